// Round 2
// baseline (1220.192 us; speedup 1.0000x reference)
//
#include <hip/hip_runtime.h>

typedef unsigned short u16;
typedef unsigned int   u32;
typedef __attribute__((ext_vector_type(8))) __bf16 bf16x8;
typedef __attribute__((ext_vector_type(4))) float  f32x4;
typedef __attribute__((ext_vector_type(4))) u16    u16x4;

#define DEV __device__ __forceinline__

DEV float bf2f(u16 u){ union { u32 i; float f; } x; x.i = ((u32)u) << 16; return x.f; }
DEV u16 f2bf(float f){ union { float f; u32 i; } x; x.f = f;
  u32 r = x.i + 0x7fffu + ((x.i >> 16) & 1u); return (u16)(r >> 16); }

// ---------------- weight transpose+convert: dst[n*R + k] = src[k*C + n] (bf16) ----------
__global__ __launch_bounds__(256)
void twt_k(const float* __restrict__ src, u16* __restrict__ dst, int R, int C){
  __shared__ float t[32][33];
  int tx = threadIdx.x & 31, ty = threadIdx.x >> 5;
  int c0 = blockIdx.x * 32, r0 = blockIdx.y * 32;
  #pragma unroll
  for (int i = 0; i < 4; i++)
    t[ty + i*8][tx] = src[(size_t)(r0 + ty + i*8) * C + c0 + tx];
  __syncthreads();
  #pragma unroll
  for (int i = 0; i < 4; i++)
    dst[(size_t)(c0 + ty + i*8) * R + r0 + tx] = f2bf(t[tx][ty + i*8]);
}

// 17 square 768x768 mats in one launch (z = matrix id)
__global__ __launch_bounds__(256)
void twt17_k(const float* __restrict__ Ws, const float* __restrict__ Wt,
             const float* __restrict__ Wtp, const float* __restrict__ Wfc,
             u16* __restrict__ dst){
  __shared__ float t[32][33];
  int z = blockIdx.z;
  const float* src = (z < 4)  ? Ws  + (size_t)z * 589824
                   : (z < 13) ? Wt  + (size_t)(z-4) * 589824
                   : (z < 16) ? Wtp + (size_t)(z-13) * 589824
                   : Wfc;
  u16* d = dst + (size_t)z * 589824;
  int tx = threadIdx.x & 31, ty = threadIdx.x >> 5;
  int c0 = blockIdx.x * 32, r0 = blockIdx.y * 32;
  #pragma unroll
  for (int i = 0; i < 4; i++)
    t[ty + i*8][tx] = src[(size_t)(r0 + ty + i*8) * 768 + c0 + tx];
  __syncthreads();
  #pragma unroll
  for (int i = 0; i < 4; i++)
    d[(size_t)(c0 + ty + i*8) * 768 + r0 + tx] = f2bf(t[tx][ty + i*8]);
}

// ---------------- zero fill (u32 granularity) ----------------
__global__ void fillz_k(u32* __restrict__ p, long n){
  long i = (long)blockIdx.x * 256 + threadIdx.x;
  long stride = (long)gridDim.x * 256;
  for (; i < n; i += stride) p[i] = 0;
}

// ---------------- LayerNorm over C=768, one wave per token, out bf16 -------------
// GM=0: temporal: token=(b,m) -> f0[b,1+m] (f32)
// GM=1: spatial: token=(s=b*16+t, j); j==0 -> f0=x[b,0] (f32); else b0_=xt2 row (bf16)
// GM=2: plain f32 (f0 + tok*768)
template<int GM>
__global__ __launch_bounds__(256)
void ln_k(const float* __restrict__ f0, const u16* __restrict__ b0_,
          const float* __restrict__ gw, const float* __restrict__ bw,
          u16* __restrict__ out){
  int lane = threadIdx.x & 63;
  int tok = blockIdx.x * 4 + (threadIdx.x >> 6);
  const float* fsrc = nullptr; const u16* bsrc = nullptr;
  bool bfp = false;
  if constexpr (GM == 0){
    int b = tok / 3136, m = tok - b * 3136;
    fsrc = f0 + ((size_t)b * 3137 + 1 + m) * 768;
  } else if constexpr (GM == 1){
    int s = tok / 197, j = tok - s * 197;
    int b = s >> 4, t = s & 15;
    if (j == 0) fsrc = f0 + (size_t)b * 3137 * 768;
    else { bfp = true; bsrc = b0_ + ((size_t)b * 3136 + (size_t)(j - 1) * 16 + t) * 768; }
  } else {
    fsrc = f0 + (size_t)tok * 768;
  }
  float v[12]; float s1 = 0.f, s2 = 0.f;
  if (!bfp){
    #pragma unroll
    for (int i = 0; i < 3; i++){
      float4 f = *(const float4*)(fsrc + i * 256 + lane * 4);
      v[i*4+0] = f.x; v[i*4+1] = f.y; v[i*4+2] = f.z; v[i*4+3] = f.w;
    }
  } else {
    #pragma unroll
    for (int i = 0; i < 3; i++){
      u16x4 p = *(const u16x4*)(bsrc + i * 256 + lane * 4);
      v[i*4+0] = bf2f(p[0]); v[i*4+1] = bf2f(p[1]); v[i*4+2] = bf2f(p[2]); v[i*4+3] = bf2f(p[3]);
    }
  }
  #pragma unroll
  for (int i = 0; i < 12; i++){ s1 += v[i]; s2 += v[i]*v[i]; }
  #pragma unroll
  for (int off = 32; off; off >>= 1){ s1 += __shfl_xor(s1, off); s2 += __shfl_xor(s2, off); }
  float mu = s1 * (1.f/768.f);
  float rstd = rsqrtf(s2 * (1.f/768.f) - mu*mu + 1e-5f);
  #pragma unroll
  for (int i = 0; i < 3; i++){
    int c = i * 256 + lane * 4;
    float4 g4 = *(const float4*)(gw + c);
    float4 b4 = *(const float4*)(bw + c);
    u16x4 pk;
    pk[0] = f2bf((v[i*4+0]-mu)*rstd*g4.x + b4.x);
    pk[1] = f2bf((v[i*4+1]-mu)*rstd*g4.y + b4.y);
    pk[2] = f2bf((v[i*4+2]-mu)*rstd*g4.z + b4.z);
    pk[3] = f2bf((v[i*4+3]-mu)*rstd*g4.w + b4.w);
    *(u16x4*)(out + (size_t)tok * 768 + c) = pk;
  }
}

// ---------------- GEMM: C = Amap @ Bw^T(+bias), 128x128 tile, bf16 MFMA ----------------
// A: (M x K) bf16 row-major with row map r -> (r/aTs)*aTf + at0 + r%aTs
// Bw: transposed weights (N x K) bf16 row-major
// MODE 0: bf16 out[R*ldo+Cg]
// MODE 1: blend: Ro=(R/oTs)*oTf+ot0+R%oTs; out[Ro*ldo+Cg] = bf16(0.5*val+0.5*old)
// MODE 2: bf16 out[R*768+Cg] = val + aux1(x,f32)[((R/3136)*3137+1+R%3136)*768+Cg]
// MODE 3: spatial: s=R/197,j=R%197; j==0 -> aux2(clsbuf,f32)[s*768+Cg]=val;
//         else xn(f32)[(b*3137+1+m)*768+Cg] = val + bf2f(aux1(xt2,bf16)[(b*3136+m)*768+Cg])
// MODE 4: bf16 out = gelu(val)
// MODE 5: f32 out[R*768+Cg] = val + aux1(xn,f32)[R*768+Cg]
// MODE 6: vT store: out[(((R/197)*12+(Cg>>6))*64 + (Cg&63))*224 + R%197] = bf16(val)
template<int MODE>
__global__ __launch_bounds__(256)
void gemm_k(const u16* __restrict__ A, const u16* __restrict__ Bw,
            const float* __restrict__ bias, void* out,
            const void* aux1, void* aux2,
            int M, int K, int lda, int ldo,
            int aTs, int aTf, int at0, int oTs, int oTf, int ot0){
  __shared__ u16 lA[128 * 32];
  __shared__ u16 lB[128 * 32];
  const int tid = threadIdx.x;
  const int m0 = blockIdx.y * 128, n0 = blockIdx.x * 128;
  const int lane = tid & 63, widx = tid >> 6;
  const int g = lane >> 4, r16 = lane & 15;
  const int wm = widx >> 1, wn = widx & 1;

  const u16* ga[2]; const u16* gb[2]; u16* la[2]; u16* lb[2];
  #pragma unroll
  for (int rnd = 0; rnd < 2; ++rnd){
    int li = tid + rnd * 256;
    int ar = m0 + (li >> 2); if (ar > M - 1) ar = M - 1;
    ar = (ar / aTs) * aTf + at0 + (ar % aTs);
    ga[rnd] = A + (size_t)ar * lda + (li & 3) * 8;
    gb[rnd] = Bw + (size_t)(n0 + (li >> 2)) * K + (li & 3) * 8;
    la[rnd] = lA + (size_t)li * 8;
    lb[rnd] = lB + (size_t)li * 8;
  }

  const f32x4 vz = {0.f, 0.f, 0.f, 0.f};
  f32x4 acc[4][4];
  #pragma unroll
  for (int i = 0; i < 4; i++)
    #pragma unroll
    for (int j = 0; j < 4; j++) acc[i][j] = vz;

  const int kiter = K >> 5;
  for (int kt = 0; kt < kiter; ++kt){
    bf16x8 ra0 = *(const bf16x8*)(ga[0] + kt * 32);
    bf16x8 ra1 = *(const bf16x8*)(ga[1] + kt * 32);
    bf16x8 rb0 = *(const bf16x8*)(gb[0] + kt * 32);
    bf16x8 rb1 = *(const bf16x8*)(gb[1] + kt * 32);
    __syncthreads();
    *(bf16x8*)la[0] = ra0;
    *(bf16x8*)la[1] = ra1;
    *(bf16x8*)lb[0] = rb0;
    *(bf16x8*)lb[1] = rb1;
    __syncthreads();
    bf16x8 af[4], bfr[4];
    #pragma unroll
    for (int i = 0; i < 4; i++){
      af[i]  = *(const bf16x8*)(lA + (wm * 64 + i * 16 + r16) * 32 + g * 8);
      bfr[i] = *(const bf16x8*)(lB + (wn * 64 + i * 16 + r16) * 32 + g * 8);
    }
    #pragma unroll
    for (int i = 0; i < 4; i++)
      #pragma unroll
      for (int j = 0; j < 4; j++)
        acc[i][j] = __builtin_amdgcn_mfma_f32_16x16x32_bf16(af[i], bfr[j], acc[i][j], 0, 0, 0);
  }

  #pragma unroll
  for (int i = 0; i < 4; i++){
    const int lrow = wm * 64 + i * 16 + g * 4;
    #pragma unroll
    for (int j = 0; j < 4; j++){
      const int Cg = n0 + wn * 64 + j * 16 + r16;
      const float b0 = bias[Cg];
      #pragma unroll
      for (int r = 0; r < 4; r++){
        const int R = m0 + lrow + r;
        if (R >= M) continue;
        float val = acc[i][j][r] + b0;
        if constexpr (MODE == 0){
          ((u16*)out)[(size_t)R * ldo + Cg] = f2bf(val);
        } else if constexpr (MODE == 1){
          int Ro = (R / oTs) * oTf + ot0 + (R % oTs);
          u16* po = (u16*)out + (size_t)Ro * ldo + Cg;
          *po = f2bf(0.5f * val + 0.5f * bf2f(*po));
        } else if constexpr (MODE == 2){
          int b_ = R / 3136, m_ = R - b_ * 3136;
          ((u16*)out)[(size_t)R * 768 + Cg] =
              f2bf(val + ((const float*)aux1)[((size_t)b_ * 3137 + 1 + m_) * 768 + Cg]);
        } else if constexpr (MODE == 3){
          int s_ = R / 197, j_ = R - s_ * 197;
          if (j_ == 0){
            ((float*)aux2)[(size_t)s_ * 768 + Cg] = val;
          } else {
            int b_ = s_ >> 4, t_ = s_ & 15, m_ = (j_ - 1) * 16 + t_;
            ((float*)out)[((size_t)b_ * 3137 + 1 + m_) * 768 + Cg] =
                val + bf2f(((const u16*)aux1)[((size_t)b_ * 3136 + m_) * 768 + Cg]);
          }
        } else if constexpr (MODE == 4){
          float gel = 0.5f * val * (1.f + erff(val * 0.70710678118f));
          ((u16*)out)[(size_t)R * ldo + Cg] = f2bf(gel);
        } else if constexpr (MODE == 5){
          ((float*)out)[(size_t)R * 768 + Cg] = val + ((const float*)aux1)[(size_t)R * 768 + Cg];
        } else if constexpr (MODE == 6){
          int s_ = R / 197, j_ = R - s_ * 197;
          int h_ = Cg >> 6, d_ = Cg & 63;
          ((u16*)out)[(((size_t)(s_ * 12 + h_) * 64 + d_) * 224) + j_] = f2bf(val);
        }
      }
    }
  }
}

// ---------------- temporal attention: one wave per (seq,head), lane = d ----------------
template<int TS>
__global__ __launch_bounds__(256)
void tattn_k(const u16* __restrict__ q, const u16* __restrict__ k,
             const u16* __restrict__ v, u16* __restrict__ o){
  int lane = threadIdx.x & 63;
  int p = blockIdx.x * 4 + (threadIdx.x >> 6);
  int seq = p / 12, h = p - seq * 12;
  size_t base = (size_t)seq * TS * 768 + h * 64 + lane;
  float qr[TS], kr[TS], vr[TS];
  #pragma unroll
  for (int t = 0; t < TS; t++){
    qr[t] = bf2f(q[base + (size_t)t * 768]);
    kr[t] = bf2f(k[base + (size_t)t * 768]);
    vr[t] = bf2f(v[base + (size_t)t * 768]);
  }
  #pragma unroll
  for (int t = 0; t < TS; t++){
    float pp[TS];
    #pragma unroll
    for (int t2 = 0; t2 < TS; t2++) pp[t2] = qr[t] * kr[t2];
    #pragma unroll
    for (int off = 32; off; off >>= 1)
      #pragma unroll
      for (int t2 = 0; t2 < TS; t2++) pp[t2] += __shfl_xor(pp[t2], off);
    float m = pp[0];
    #pragma unroll
    for (int t2 = 1; t2 < TS; t2++) m = fmaxf(m, pp[t2]);
    float sum = 0.f;
    #pragma unroll
    for (int t2 = 0; t2 < TS; t2++){ pp[t2] = __expf((pp[t2] - m) * 0.125f); sum += pp[t2]; }
    float inv = 1.f / sum;
    float ov = 0.f;
    #pragma unroll
    for (int t2 = 0; t2 < TS; t2++) ov += pp[t2] * vr[t2];
    o[base + (size_t)t * 768] = f2bf(ov * inv);
  }
}

// ---------------- spatial attention: 1 wave per (seq,head,16-row q-chunk) --------------
// qs/ks: (12608 x 768) bf16 row-major; vt: [(s*12+h)*64 + d][224] bf16 (cols j, zero-pad)
__global__ __launch_bounds__(64)
void sattn_k(const u16* __restrict__ qs, const u16* __restrict__ ks,
             const u16* __restrict__ vt, u16* __restrict__ o){
  __shared__ u16 Pl[16 * 224];
  const int lane = threadIdx.x & 63;
  const int g = lane >> 4, r16 = lane & 15;
  int bid = blockIdx.x;
  int chunk = bid % 13; int sh = bid / 13;
  int h = sh % 12, s = sh / 12;
  const float sc_l2e = 0.125f * 1.44269504089f;

  // zero P pad cols 208..223 (read by the last PV k-step)
  #pragma unroll
  for (int i = 0; i < 4; i++) Pl[(i * 4 + g) * 224 + 208 + r16] = 0;

  int q0 = chunk * 16;
  int qrow = q0 + r16; if (qrow > 196) qrow = 196;
  const u16* qp = qs + ((size_t)(s * 197 + qrow)) * 768 + h * 64 + g * 8;
  bf16x8 aq0 = *(const bf16x8*)qp;
  bf16x8 aq1 = *(const bf16x8*)(qp + 32);

  f32x4 scv[13];
  #pragma unroll
  for (int jt = 0; jt < 13; ++jt){
    int krow = jt * 16 + r16; if (krow > 196) krow = 196;
    const u16* kp = ks + ((size_t)(s * 197 + krow)) * 768 + h * 64 + g * 8;
    bf16x8 b0 = *(const bf16x8*)kp;
    bf16x8 b1 = *(const bf16x8*)(kp + 32);
    f32x4 z = {0.f, 0.f, 0.f, 0.f};
    z = __builtin_amdgcn_mfma_f32_16x16x32_bf16(aq0, b0, z, 0, 0, 0);
    z = __builtin_amdgcn_mfma_f32_16x16x32_bf16(aq1, b1, z, 0, 0, 0);
    scv[jt] = z;
  }
  float mrow[4] = {-3e38f, -3e38f, -3e38f, -3e38f};
  #pragma unroll
  for (int jt = 0; jt < 13; ++jt)
    #pragma unroll
    for (int r = 0; r < 4; r++){
      float x = (jt * 16 + r16 < 197) ? scv[jt][r] : -3e38f;
      scv[jt][r] = x;
      mrow[r] = fmaxf(mrow[r], x);
    }
  #pragma unroll
  for (int off = 1; off < 16; off <<= 1)
    #pragma unroll
    for (int r = 0; r < 4; r++) mrow[r] = fmaxf(mrow[r], __shfl_xor(mrow[r], off));
  float srow[4] = {0.f, 0.f, 0.f, 0.f};
  #pragma unroll
  for (int jt = 0; jt < 13; ++jt)
    #pragma unroll
    for (int r = 0; r < 4; r++){
      float e = exp2f((scv[jt][r] - mrow[r]) * sc_l2e);
      scv[jt][r] = e;
      srow[r] += e;
    }
  #pragma unroll
  for (int off = 1; off < 16; off <<= 1)
    #pragma unroll
    for (int r = 0; r < 4; r++) srow[r] += __shfl_xor(srow[r], off);
  float inv[4];
  #pragma unroll
  for (int r = 0; r < 4; r++) inv[r] = 1.f / srow[r];
  #pragma unroll
  for (int jt = 0; jt < 13; ++jt)
    #pragma unroll
    for (int r = 0; r < 4; r++)
      Pl[(g * 4 + r) * 224 + jt * 16 + r16] = f2bf(scv[jt][r] * inv[r]);
  __syncthreads();
  // PV: O(16x64) = P(16x224) @ Vt rows (d), b-frags straight from global (L2-resident)
  const u16* vbase = vt + ((size_t)(s * 12 + h) * 64) * 224;
  f32x4 oc[4]; const f32x4 vz = {0.f,0.f,0.f,0.f};
  #pragma unroll
  for (int dt = 0; dt < 4; dt++) oc[dt] = vz;
  #pragma unroll
  for (int ks2 = 0; ks2 < 7; ++ks2){
    bf16x8 ap = *(const bf16x8*)(Pl + r16 * 224 + ks2 * 32 + g * 8);
    #pragma unroll
    for (int dt = 0; dt < 4; ++dt){
      const u16* vp = vbase + ((size_t)(dt * 16 + r16)) * 224 + ks2 * 32 + g * 8;
      bf16x8 bv = *(const bf16x8*)vp;
      oc[dt] = __builtin_amdgcn_mfma_f32_16x16x32_bf16(ap, bv, oc[dt], 0, 0, 0);
    }
  }
  #pragma unroll
  for (int dt = 0; dt < 4; ++dt)
    #pragma unroll
    for (int r = 0; r < 4; r++){
      int qr2 = q0 + g * 4 + r;
      if (qr2 < 197)
        o[((size_t)(s * 197 + qr2)) * 768 + h * 64 + dt * 16 + r16] = f2bf(oc[dt][r]);
    }
}

// ---------------- cls row: xn[b,0] = x[b,0] + mean_t clsbuf[b*16+t] ----------------
__global__ __launch_bounds__(256)
void clsfin_k(const float* __restrict__ x, const float* __restrict__ cb, float* __restrict__ xn){
  int b = blockIdx.x;
  int c = blockIdx.y * 256 + threadIdx.x;
  float s = 0.f;
  #pragma unroll
  for (int t = 0; t < 16; t++) s += cb[((size_t)(b * 16 + t)) * 768 + c];
  xn[(size_t)b * 3137 * 768 + c] = x[(size_t)b * 3137 * 768 + c] + s * (1.f / 16.f);
}

// ======================================================================================
extern "C" void kernel_launch(void* const* d_in, const int* in_sizes, int n_in,
                              void* d_out, int out_size, void* d_ws, size_t ws_size,
                              hipStream_t stream){
  (void)in_sizes; (void)n_in; (void)out_size;
  const float* x    = (const float*)d_in[0];
  const float* ln1g = (const float*)d_in[1];
  const float* ln1b = (const float*)d_in[2];
  const float* tlng = (const float*)d_in[3];
  const float* tlnb = (const float*)d_in[4];
  const float* ln2g = (const float*)d_in[5];
  const float* ln2b = (const float*)d_in[6];
  const float* Ws   = (const float*)d_in[7];
  const float* bs   = (const float*)d_in[8];
  const float* Wt   = (const float*)d_in[9];
  const float* bt   = (const float*)d_in[10];
  const float* Wtp  = (const float*)d_in[11];
  const float* btp  = (const float*)d_in[12];
  const float* Wfc  = (const float*)d_in[13];
  const float* bfc  = (const float*)d_in[14];
  const float* W1   = (const float*)d_in[15];
  const float* b1   = (const float*)d_in[16];
  const float* W2   = (const float*)d_in[17];
  const float* b2   = (const float*)d_in[18];
  float* out = (float*)d_out;

  // ---- static workspace plan (bytes). Slots reused across disjoint lifetimes.
  constexpr size_t MiB = 1048576;
  constexpr size_t C2  = 589824;           // 768*768 elements
  constexpr size_t W_BYTES = (17 * C2 + 2 * 2359296) * 2;  // 29,491,200
  constexpr size_t NEED = W_BYTES + 139 * MiB;             // 175,243,264
  if (ws_size < NEED) return;  // diagnostic guard: zero output instead of OOB fault

  char* wsb  = (char*)d_ws;
  u16*  wbuf = (u16*)wsb;                   // 25 transposed bf16 weight mats
  u16*  W1T  = wbuf + 17 * C2;              // 3072 x 768
  u16*  W2T  = W1T + (size_t)3072 * 768;    // 768 x 3072
  char* A0   = wsb + W_BYTES;

  // slot map (MiB offsets within arena A0); lifetimes disjoint where space overlaps:
  //  [0,20)    ht | hs | os | h2
  //  [20,40)   q16 | q8 | q4 | tp | qs      ; a1 spans [20,93.6) at MLP time
  //  [40,60)   k16 | k8 | k4 | ks
  //  [60,81)   v16 | v8 | v4 | vt(21MiB)
  //  [82,100.4) o16 | xt2(bf16)
  //  [101,137.8) xn(f32)   (over dead o8@[102,111.2), o4@[112,116.6))
  //  [138,..)  clsb
  u16*  ht  = (u16*)(A0 + 0   * MiB);
  u16*  q16 = (u16*)(A0 + 20  * MiB);
  u16*  k16 = (u16*)(A0 + 40  * MiB);
  u16*  v16 = (u16*)(A0 + 60  * MiB);
  u16*  o16 = (u16*)(A0 + 82  * MiB);
  u16*  o8  = (u16*)(A0 + 102 * MiB);
  u16*  o4  = (u16*)(A0 + 112 * MiB);
  u16*  xt2 = (u16*)(A0 + 82  * MiB);
  float* xn = (float*)(A0 + 101 * MiB);
  float* clsb = (float*)(A0 + 138 * MiB);
  u16*  q8  = q16; u16* k8 = k16; u16* v8 = v16;
  u16*  q4  = q16; u16* k4 = k16; u16* v4 = v16;
  u16*  tp  = q16;
  u16*  hs  = ht;  u16* osb = ht; u16* h2 = ht;
  u16*  qsb = q16; u16* ksb = k16; u16* vts = v16;
  u16*  a1  = q16;

  // -- weights -> transposed bf16
  twt17_k<<<dim3(24, 24, 17), 256, 0, stream>>>(Ws, Wt, Wtp, Wfc, wbuf);
  twt_k<<<dim3(96, 24), 256, 0, stream>>>(W1, W1T, 768, 3072);
  twt_k<<<dim3(24, 96), 256, 0, stream>>>(W2, W2T, 3072, 768);

  // -- temporal LN
  ln_k<0><<<3136, 256, 0, stream>>>(x, nullptr, tlng, tlnb, ht);

  // -- scale 16: QKV + attn
  gemm_k<0><<<dim3(6, 98), 256, 0, stream>>>(ht, wbuf + 10*C2, bt + 6*768, q16, nullptr, nullptr, 12544, 768, 768, 768, 1,1,0, 1,1,0);
  gemm_k<0><<<dim3(6, 98), 256, 0, stream>>>(ht, wbuf + 11*C2, bt + 7*768, k16, nullptr, nullptr, 12544, 768, 768, 768, 1,1,0, 1,1,0);
  gemm_k<0><<<dim3(6, 98), 256, 0, stream>>>(ht, wbuf + 12*C2, bt + 8*768, v16, nullptr, nullptr, 12544, 768, 768, 768, 1,1,0, 1,1,0);
  tattn_k<16><<<2352, 256, 0, stream>>>(q16, k16, v16, o16);

  // -- scale 8 (reuses qkv slots)
  gemm_k<0><<<dim3(6, 49), 256, 0, stream>>>(ht, wbuf +  7*C2, bt + 3*768, q8, nullptr, nullptr, 6272, 768, 768, 768, 8,16,8, 1,1,0);
  gemm_k<0><<<dim3(6, 49), 256, 0, stream>>>(ht, wbuf +  8*C2, bt + 4*768, k8, nullptr, nullptr, 6272, 768, 768, 768, 8,16,8, 1,1,0);
  gemm_k<0><<<dim3(6, 49), 256, 0, stream>>>(ht, wbuf +  9*C2, bt + 5*768, v8, nullptr, nullptr, 6272, 768, 768, 768, 8,16,8, 1,1,0);
  tattn_k< 8><<<2352, 256, 0, stream>>>(q8, k8, v8, o8);

  // -- scale 4
  gemm_k<0><<<dim3(6, 25), 256, 0, stream>>>(ht, wbuf +  4*C2, bt + 0*768, q4, nullptr, nullptr, 3136, 768, 768, 768, 4,16,12, 1,1,0);
  gemm_k<0><<<dim3(6, 25), 256, 0, stream>>>(ht, wbuf +  5*C2, bt + 1*768, k4, nullptr, nullptr, 3136, 768, 768, 768, 4,16,12, 1,1,0);
  gemm_k<0><<<dim3(6, 25), 256, 0, stream>>>(ht, wbuf +  6*C2, bt + 2*768, v4, nullptr, nullptr, 3136, 768, 768, 768, 4,16,12, 1,1,0);
  tattn_k< 4><<<2352, 256, 0, stream>>>(q4, k4, v4, o4);

  // -- projection + blend chain; then tp, xt2
  gemm_k<1><<<dim3(6, 25), 256, 0, stream>>>(o4,  wbuf + 13*C2, btp + 0,    o8,  nullptr, nullptr, 3136, 768, 768, 768, 1,1,0, 4,8,4);
  gemm_k<1><<<dim3(6, 49), 256, 0, stream>>>(o8,  wbuf + 14*C2, btp + 768,  o16, nullptr, nullptr, 6272, 768, 768, 768, 1,1,0, 8,16,8);
  gemm_k<0><<<dim3(6, 98), 256, 0, stream>>>(o16, wbuf + 15*C2, btp + 1536, tp,  nullptr, nullptr, 12544, 768, 768, 768, 1,1,0, 1,1,0);
  gemm_k<2><<<dim3(6, 98), 256, 0, stream>>>(tp,  wbuf + 16*C2, bfc,        xt2, x, nullptr,       12544, 768, 768, 768, 1,1,0, 1,1,0);

  // -- spatial LN + QKV
  ln_k<1><<<3152, 256, 0, stream>>>(x, xt2, ln1g, ln1b, hs);
  gemm_k<0><<<dim3(6, 99), 256, 0, stream>>>(hs, wbuf + 0*C2, bs + 0,    qsb, nullptr, nullptr, 12608, 768, 768, 768, 1,1,0, 1,1,0);
  gemm_k<0><<<dim3(6, 99), 256, 0, stream>>>(hs, wbuf + 1*C2, bs + 768,  ksb, nullptr, nullptr, 12608, 768, 768, 768, 1,1,0, 1,1,0);
  fillz_k<<<2048, 256, 0, stream>>>((u32*)vts, 5505024);
  gemm_k<6><<<dim3(6, 99), 256, 0, stream>>>(hs, wbuf + 2*C2, bs + 1536, vts, nullptr, nullptr, 12608, 768, 768, 0, 1,1,0, 1,1,0);

  // -- spatial attention
  sattn_k<<<9984, 64, 0, stream>>>(qsb, ksb, vts, osb);

  // -- spatial proj + residual scatter into xn, cls rows
  gemm_k<3><<<dim3(6, 99), 256, 0, stream>>>(osb, wbuf + 3*C2, bs + 2304, xn, xt2, clsb, 12608, 768, 768, 768, 1,1,0, 1,1,0);
  clsfin_k<<<dim3(4, 3), 256, 0, stream>>>(x, clsb, xn);

  // -- final LN + MLP (a1 overlays dead spatial buffers)
  ln_k<2><<<3137, 256, 0, stream>>>(xn, nullptr, ln2g, ln2b, h2);
  gemm_k<4><<<dim3(24, 99), 256, 0, stream>>>(h2, W1T, b1, a1,  nullptr, nullptr, 12548, 768, 768, 3072, 1,1,0, 1,1,0);
  gemm_k<5><<<dim3(6, 99), 256, 0, stream>>>(a1, W2T, b2, out, xn, nullptr,       12548, 3072, 3072, 768, 1,1,0, 1,1,0);
}

// Round 3
// 1053.567 us; speedup vs baseline: 1.1582x; 1.1582x over previous
//
#include <hip/hip_runtime.h>

typedef unsigned short u16;
typedef unsigned int   u32;
typedef __attribute__((ext_vector_type(8))) __bf16 bf16x8;
typedef __attribute__((ext_vector_type(4))) float  f32x4;
typedef __attribute__((ext_vector_type(4))) u16    u16x4;

#define DEV __device__ __forceinline__

DEV float bf2f(u16 u){ union { u32 i; float f; } x; x.i = ((u32)u) << 16; return x.f; }
DEV u16 f2bf(float f){ union { float f; u32 i; } x; x.f = f;
  u32 r = x.i + 0x7fffu + ((x.i >> 16) & 1u); return (u16)(r >> 16); }

DEV void gload16(const void* g, void* l){
  __builtin_amdgcn_global_load_lds((const __attribute__((address_space(1))) void*)g,
                                   (__attribute__((address_space(3))) void*)l, 16, 0, 0);
}

// ---------------- weight transpose+convert: dst[n*R + k] = src[k*C + n] (bf16) ----------
__global__ __launch_bounds__(256)
void twt_k(const float* __restrict__ src, u16* __restrict__ dst, int R, int C){
  __shared__ float t[32][33];
  int tx = threadIdx.x & 31, ty = threadIdx.x >> 5;
  int c0 = blockIdx.x * 32, r0 = blockIdx.y * 32;
  #pragma unroll
  for (int i = 0; i < 4; i++)
    t[ty + i*8][tx] = src[(size_t)(r0 + ty + i*8) * C + c0 + tx];
  __syncthreads();
  #pragma unroll
  for (int i = 0; i < 4; i++)
    dst[(size_t)(c0 + ty + i*8) * R + r0 + tx] = f2bf(t[tx][ty + i*8]);
}

// 17 square 768x768 mats in one launch (z = matrix id)
__global__ __launch_bounds__(256)
void twt17_k(const float* __restrict__ Ws, const float* __restrict__ Wt,
             const float* __restrict__ Wtp, const float* __restrict__ Wfc,
             u16* __restrict__ dst){
  __shared__ float t[32][33];
  int z = blockIdx.z;
  const float* src = (z < 4)  ? Ws  + (size_t)z * 589824
                   : (z < 13) ? Wt  + (size_t)(z-4) * 589824
                   : (z < 16) ? Wtp + (size_t)(z-13) * 589824
                   : Wfc;
  u16* d = dst + (size_t)z * 589824;
  int tx = threadIdx.x & 31, ty = threadIdx.x >> 5;
  int c0 = blockIdx.x * 32, r0 = blockIdx.y * 32;
  #pragma unroll
  for (int i = 0; i < 4; i++)
    t[ty + i*8][tx] = src[(size_t)(r0 + ty + i*8) * 768 + c0 + tx];
  __syncthreads();
  #pragma unroll
  for (int i = 0; i < 4; i++)
    d[(size_t)(c0 + ty + i*8) * 768 + r0 + tx] = f2bf(t[tx][ty + i*8]);
}

// ---------------- zero fill (u32 granularity) ----------------
__global__ void fillz_k(u32* __restrict__ p, long n){
  long i = (long)blockIdx.x * 256 + threadIdx.x;
  long stride = (long)gridDim.x * 256;
  for (; i < n; i += stride) p[i] = 0;
}

// ---------------- LayerNorm over C=768, one wave per token, out bf16 -------------
template<int GM>
__global__ __launch_bounds__(256)
void ln_k(const float* __restrict__ f0, const u16* __restrict__ b0_,
          const float* __restrict__ gw, const float* __restrict__ bw,
          u16* __restrict__ out){
  int lane = threadIdx.x & 63;
  int tok = blockIdx.x * 4 + (threadIdx.x >> 6);
  const float* fsrc = nullptr; const u16* bsrc = nullptr;
  bool bfp = false;
  if constexpr (GM == 0){
    int b = tok / 3136, m = tok - b * 3136;
    fsrc = f0 + ((size_t)b * 3137 + 1 + m) * 768;
  } else if constexpr (GM == 1){
    int s = tok / 197, j = tok - s * 197;
    int b = s >> 4, t = s & 15;
    if (j == 0) fsrc = f0 + (size_t)b * 3137 * 768;
    else { bfp = true; bsrc = b0_ + ((size_t)b * 3136 + (size_t)(j - 1) * 16 + t) * 768; }
  } else {
    fsrc = f0 + (size_t)tok * 768;
  }
  float v[12]; float s1 = 0.f, s2 = 0.f;
  if (!bfp){
    #pragma unroll
    for (int i = 0; i < 3; i++){
      float4 f = *(const float4*)(fsrc + i * 256 + lane * 4);
      v[i*4+0] = f.x; v[i*4+1] = f.y; v[i*4+2] = f.z; v[i*4+3] = f.w;
    }
  } else {
    #pragma unroll
    for (int i = 0; i < 3; i++){
      u16x4 p = *(const u16x4*)(bsrc + i * 256 + lane * 4);
      v[i*4+0] = bf2f(p[0]); v[i*4+1] = bf2f(p[1]); v[i*4+2] = bf2f(p[2]); v[i*4+3] = bf2f(p[3]);
    }
  }
  #pragma unroll
  for (int i = 0; i < 12; i++){ s1 += v[i]; s2 += v[i]*v[i]; }
  #pragma unroll
  for (int off = 32; off; off >>= 1){ s1 += __shfl_xor(s1, off); s2 += __shfl_xor(s2, off); }
  float mu = s1 * (1.f/768.f);
  float rstd = rsqrtf(s2 * (1.f/768.f) - mu*mu + 1e-5f);
  #pragma unroll
  for (int i = 0; i < 3; i++){
    int c = i * 256 + lane * 4;
    float4 g4 = *(const float4*)(gw + c);
    float4 b4 = *(const float4*)(bw + c);
    u16x4 pk;
    pk[0] = f2bf((v[i*4+0]-mu)*rstd*g4.x + b4.x);
    pk[1] = f2bf((v[i*4+1]-mu)*rstd*g4.y + b4.y);
    pk[2] = f2bf((v[i*4+2]-mu)*rstd*g4.z + b4.z);
    pk[3] = f2bf((v[i*4+3]-mu)*rstd*g4.w + b4.w);
    *(u16x4*)(out + (size_t)tok * 768 + c) = pk;
  }
}

// ---------------- GEMM: C = Amap @ Bw^T(+bias), 128x128 tile, bf16 MFMA ----------------
// A row map r -> (r/aTs)*aTf + at0 + r%aTs ; Bw: (N x K) bf16 row-major
// MODE 0: bf16 out[R*ldo+Cg]
// MODE 1: blend: Ro=(R/oTs)*oTf+ot0+R%oTs; out[Ro*ldo+Cg] = bf16(0.5*val+0.5*old)
// MODE 2: bf16 out[R*768+Cg] = val + aux1(x,f32)[((R/3136)*3137+1+R%3136)*768+Cg]
// MODE 3: spatial scatter (+cls buffer)  MODE 4: gelu bf16
// MODE 5: f32 out = val + aux1(f32)      MODE 6: spatial vT (stride 224)
// MODE 7: temporal vT: out[(((R/oTs)*12+(Cg>>6))*64+(Cg&63))*ldo + R%oTs]
template<int MODE>
__global__ __launch_bounds__(256)
void gemm_k(const u16* __restrict__ A, const u16* __restrict__ Bw,
            const float* __restrict__ bias, void* out,
            const void* aux1, void* aux2,
            int M, int K, int lda, int ldo,
            int aTs, int aTf, int at0, int oTs, int oTf, int ot0){
  __shared__ u16 lA[128 * 32];
  __shared__ u16 lB[128 * 32];
  const int tid = threadIdx.x;
  const int m0 = blockIdx.y * 128, n0 = blockIdx.x * 128;
  const int lane = tid & 63, widx = tid >> 6;
  const int g = lane >> 4, r16 = lane & 15;
  const int wm = widx >> 1, wn = widx & 1;

  const u16* ga[2]; const u16* gb[2]; u16* la[2]; u16* lb[2];
  #pragma unroll
  for (int rnd = 0; rnd < 2; ++rnd){
    int li = tid + rnd * 256;
    int ar = m0 + (li >> 2); if (ar > M - 1) ar = M - 1;
    ar = (ar / aTs) * aTf + at0 + (ar % aTs);
    ga[rnd] = A + (size_t)ar * lda + (li & 3) * 8;
    gb[rnd] = Bw + (size_t)(n0 + (li >> 2)) * K + (li & 3) * 8;
    la[rnd] = lA + (size_t)li * 8;
    lb[rnd] = lB + (size_t)li * 8;
  }

  const f32x4 vz = {0.f, 0.f, 0.f, 0.f};
  f32x4 acc[4][4];
  #pragma unroll
  for (int i = 0; i < 4; i++)
    #pragma unroll
    for (int j = 0; j < 4; j++) acc[i][j] = vz;

  const int kiter = K >> 5;
  for (int kt = 0; kt < kiter; ++kt){
    __syncthreads();
    gload16(ga[0] + kt * 32, la[0]);
    gload16(ga[1] + kt * 32, la[1]);
    gload16(gb[0] + kt * 32, lb[0]);
    gload16(gb[1] + kt * 32, lb[1]);
    __syncthreads();
    bf16x8 af[4], bfr[4];
    #pragma unroll
    for (int i = 0; i < 4; i++){
      af[i]  = *(const bf16x8*)(lA + (wm * 64 + i * 16 + r16) * 32 + g * 8);
      bfr[i] = *(const bf16x8*)(lB + (wn * 64 + i * 16 + r16) * 32 + g * 8);
    }
    #pragma unroll
    for (int i = 0; i < 4; i++)
      #pragma unroll
      for (int j = 0; j < 4; j++)
        acc[i][j] = __builtin_amdgcn_mfma_f32_16x16x32_bf16(af[i], bfr[j], acc[i][j], 0, 0, 0);
  }

  #pragma unroll
  for (int i = 0; i < 4; i++){
    const int lrow = wm * 64 + i * 16 + g * 4;
    #pragma unroll
    for (int j = 0; j < 4; j++){
      const int Cg = n0 + wn * 64 + j * 16 + r16;
      const float b0 = bias[Cg];
      #pragma unroll
      for (int r = 0; r < 4; r++){
        const int R = m0 + lrow + r;
        if (R >= M) continue;
        float val = acc[i][j][r] + b0;
        if constexpr (MODE == 0){
          ((u16*)out)[(size_t)R * ldo + Cg] = f2bf(val);
        } else if constexpr (MODE == 1){
          int Ro = (R / oTs) * oTf + ot0 + (R % oTs);
          u16* po = (u16*)out + (size_t)Ro * ldo + Cg;
          *po = f2bf(0.5f * val + 0.5f * bf2f(*po));
        } else if constexpr (MODE == 2){
          int b_ = R / 3136, m_ = R - b_ * 3136;
          ((u16*)out)[(size_t)R * 768 + Cg] =
              f2bf(val + ((const float*)aux1)[((size_t)b_ * 3137 + 1 + m_) * 768 + Cg]);
        } else if constexpr (MODE == 3){
          int s_ = R / 197, j_ = R - s_ * 197;
          if (j_ == 0){
            ((float*)aux2)[(size_t)s_ * 768 + Cg] = val;
          } else {
            int b_ = s_ >> 4, t_ = s_ & 15, m_ = (j_ - 1) * 16 + t_;
            ((float*)out)[((size_t)b_ * 3137 + 1 + m_) * 768 + Cg] =
                val + bf2f(((const u16*)aux1)[((size_t)b_ * 3136 + m_) * 768 + Cg]);
          }
        } else if constexpr (MODE == 4){
          float gel = 0.5f * val * (1.f + erff(val * 0.70710678118f));
          ((u16*)out)[(size_t)R * ldo + Cg] = f2bf(gel);
        } else if constexpr (MODE == 5){
          ((float*)out)[(size_t)R * 768 + Cg] = val + ((const float*)aux1)[(size_t)R * 768 + Cg];
        } else if constexpr (MODE == 6){
          int s_ = R / 197, j_ = R - s_ * 197;
          int h_ = Cg >> 6, d_ = Cg & 63;
          ((u16*)out)[(((size_t)(s_ * 12 + h_) * 64 + d_) * 224) + j_] = f2bf(val);
        } else if constexpr (MODE == 7){
          int seq_ = R / oTs, t_ = R - seq_ * oTs;
          int h_ = Cg >> 6, d_ = Cg & 63;
          ((u16*)out)[((size_t)(seq_ * 12 + h_) * 64 + d_) * ldo + t_] = f2bf(val);
        }
      }
    }
  }
}

// ---------------- temporal attention via MFMA: one wave per (seq,head) ----------------
// q,k: (784*TS x 768) bf16; vt: [(seq*12+h)*64 + d][TSPAD] bf16 (cols t)
// S^T = mfma(a=K rows, b=Q rows) -> lane holds S[k=g*4+r][q=r16]; softmax over k =
// in-reg max/sum + shfl_xor(16,32); P^T via pack + 4x ds_bpermute; PV = 4 mfma.
template<int TS, int TSPAD>
__global__ __launch_bounds__(256)
void tattn_k(const u16* __restrict__ q, const u16* __restrict__ k,
             const u16* __restrict__ vt, u16* __restrict__ o){
  const int lane = threadIdx.x & 63;
  const int g = lane >> 4, r16 = lane & 15;
  int p = blockIdx.x * 4 + (threadIdx.x >> 6);
  int seq = p / 12, h = p - seq * 12;

  int trow = (TS < 16 && r16 >= TS) ? TS - 1 : r16;      // clamp for short scales
  size_t qko = (size_t)(seq * TS + trow) * 768 + h * 64 + g * 8;
  bf16x8 ak0 = *(const bf16x8*)(k + qko);
  bf16x8 ak1 = *(const bf16x8*)(k + qko + 32);
  bf16x8 bq0 = *(const bf16x8*)(q + qko);
  bf16x8 bq1 = *(const bf16x8*)(q + qko + 32);

  f32x4 s = {0.f, 0.f, 0.f, 0.f};
  s = __builtin_amdgcn_mfma_f32_16x16x32_bf16(ak0, bq0, s, 0, 0, 0);
  s = __builtin_amdgcn_mfma_f32_16x16x32_bf16(ak1, bq1, s, 0, 0, 0);

  // softmax over k (rows), per q-column r16
  const float C = 0.125f * 1.44269504089f;   // scale * log2(e)
  float pv[4]; float mx = -3e38f;
  #pragma unroll
  for (int r = 0; r < 4; r++){
    float x = (g * 4 + r < TS) ? s[r] : -3e38f;
    pv[r] = x; mx = fmaxf(mx, x);
  }
  mx = fmaxf(mx, __shfl_xor(mx, 16));
  mx = fmaxf(mx, __shfl_xor(mx, 32));
  float sum = 0.f;
  #pragma unroll
  for (int r = 0; r < 4; r++){ pv[r] = exp2f((pv[r] - mx) * C); sum += pv[r]; }
  sum += __shfl_xor(sum, 16);
  sum += __shfl_xor(sum, 32);
  float inv = 1.f / sum;
  #pragma unroll
  for (int r = 0; r < 4; r++) pv[r] *= inv;

  // transpose P into a-frag layout A[q][k] via ds_bpermute (k>=16 -> zero pad)
  u32 w0 = (u32)f2bf(pv[0]) | ((u32)f2bf(pv[1]) << 16);
  u32 w1 = (u32)f2bf(pv[2]) | ((u32)f2bf(pv[3]) << 16);
  int a0 = ((g * 2) * 16 + r16) * 4;
  int a1 = ((g * 2 + 1) * 16 + r16) * 4;
  u32 msk = (g < 2) ? 0xFFFFFFFFu : 0u;
  union { u32 w[4]; bf16x8 v; } pa;
  pa.w[0] = msk & (u32)__builtin_amdgcn_ds_bpermute(a0, (int)w0);
  pa.w[1] = msk & (u32)__builtin_amdgcn_ds_bpermute(a0, (int)w1);
  pa.w[2] = msk & (u32)__builtin_amdgcn_ds_bpermute(a1, (int)w0);
  pa.w[3] = msk & (u32)__builtin_amdgcn_ds_bpermute(a1, (int)w1);

  // PV: O[q][d] = sum_k P[q][k] * Vt[d][k]
  const u16* vb = vt + ((size_t)(seq * 12 + h) * 64) * TSPAD;
  const f32x4 vz = {0.f, 0.f, 0.f, 0.f};
  f32x4 oc[4];
  #pragma unroll
  for (int dt = 0; dt < 4; ++dt){
    bf16x8 bv = *(const bf16x8*)(vb + (size_t)(dt * 16 + r16) * TSPAD + g * 8);
    oc[dt] = __builtin_amdgcn_mfma_f32_16x16x32_bf16(pa.v, bv, vz, 0, 0, 0);
  }
  // store: lane holds O[qrow=g*4+rr][d=dt*16+r16]
  #pragma unroll
  for (int rr = 0; rr < 4; ++rr){
    int qr = g * 4 + rr;
    if (qr < TS){
      size_t ob = (size_t)(seq * TS + qr) * 768 + h * 64 + r16;
      #pragma unroll
      for (int dt = 0; dt < 4; ++dt)
        o[ob + dt * 16] = f2bf(oc[dt][rr]);
    }
  }
}

// ---------------- spatial attention: 1 wave per (seq,head,16-row q-chunk) --------------
__global__ __launch_bounds__(64)
void sattn_k(const u16* __restrict__ qs, const u16* __restrict__ ks,
             const u16* __restrict__ vt, u16* __restrict__ o){
  __shared__ u16 Pl[16 * 224];
  const int lane = threadIdx.x & 63;
  const int g = lane >> 4, r16 = lane & 15;
  int bid = blockIdx.x;
  int chunk = bid % 13; int sh = bid / 13;
  int h = sh % 12, s = sh / 12;
  const float sc_l2e = 0.125f * 1.44269504089f;

  #pragma unroll
  for (int i = 0; i < 4; i++) Pl[(i * 4 + g) * 224 + 208 + r16] = 0;

  int q0 = chunk * 16;
  int qrow = q0 + r16; if (qrow > 196) qrow = 196;
  const u16* qp = qs + ((size_t)(s * 197 + qrow)) * 768 + h * 64 + g * 8;
  bf16x8 aq0 = *(const bf16x8*)qp;
  bf16x8 aq1 = *(const bf16x8*)(qp + 32);

  f32x4 scv[13];
  #pragma unroll
  for (int jt = 0; jt < 13; ++jt){
    int krow = jt * 16 + r16; if (krow > 196) krow = 196;
    const u16* kp = ks + ((size_t)(s * 197 + krow)) * 768 + h * 64 + g * 8;
    bf16x8 b0 = *(const bf16x8*)kp;
    bf16x8 b1 = *(const bf16x8*)(kp + 32);
    f32x4 z = {0.f, 0.f, 0.f, 0.f};
    z = __builtin_amdgcn_mfma_f32_16x16x32_bf16(aq0, b0, z, 0, 0, 0);
    z = __builtin_amdgcn_mfma_f32_16x16x32_bf16(aq1, b1, z, 0, 0, 0);
    scv[jt] = z;
  }
  float mrow[4] = {-3e38f, -3e38f, -3e38f, -3e38f};
  #pragma unroll
  for (int jt = 0; jt < 13; ++jt)
    #pragma unroll
    for (int r = 0; r < 4; r++){
      float x = (jt * 16 + r16 < 197) ? scv[jt][r] : -3e38f;
      scv[jt][r] = x;
      mrow[r] = fmaxf(mrow[r], x);
    }
  #pragma unroll
  for (int off = 1; off < 16; off <<= 1)
    #pragma unroll
    for (int r = 0; r < 4; r++) mrow[r] = fmaxf(mrow[r], __shfl_xor(mrow[r], off));
  float srow[4] = {0.f, 0.f, 0.f, 0.f};
  #pragma unroll
  for (int jt = 0; jt < 13; ++jt)
    #pragma unroll
    for (int r = 0; r < 4; r++){
      float e = exp2f((scv[jt][r] - mrow[r]) * sc_l2e);
      scv[jt][r] = e;
      srow[r] += e;
    }
  #pragma unroll
  for (int off = 1; off < 16; off <<= 1)
    #pragma unroll
    for (int r = 0; r < 4; r++) srow[r] += __shfl_xor(srow[r], off);
  float inv[4];
  #pragma unroll
  for (int r = 0; r < 4; r++) inv[r] = 1.f / srow[r];
  #pragma unroll
  for (int jt = 0; jt < 13; ++jt)
    #pragma unroll
    for (int r = 0; r < 4; r++)
      Pl[(g * 4 + r) * 224 + jt * 16 + r16] = f2bf(scv[jt][r] * inv[r]);
  __syncthreads();
  const u16* vbase = vt + ((size_t)(s * 12 + h) * 64) * 224;
  f32x4 oc[4]; const f32x4 vz = {0.f,0.f,0.f,0.f};
  #pragma unroll
  for (int dt = 0; dt < 4; dt++) oc[dt] = vz;
  #pragma unroll
  for (int ks2 = 0; ks2 < 7; ++ks2){
    bf16x8 ap = *(const bf16x8*)(Pl + r16 * 224 + ks2 * 32 + g * 8);
    #pragma unroll
    for (int dt = 0; dt < 4; ++dt){
      const u16* vp = vbase + ((size_t)(dt * 16 + r16)) * 224 + ks2 * 32 + g * 8;
      bf16x8 bv = *(const bf16x8*)vp;
      oc[dt] = __builtin_amdgcn_mfma_f32_16x16x32_bf16(ap, bv, oc[dt], 0, 0, 0);
    }
  }
  #pragma unroll
  for (int dt = 0; dt < 4; ++dt)
    #pragma unroll
    for (int r = 0; r < 4; r++){
      int qr2 = q0 + g * 4 + r;
      if (qr2 < 197)
        o[((size_t)(s * 197 + qr2)) * 768 + h * 64 + dt * 16 + r16] = f2bf(oc[dt][r]);
    }
}

// ---------------- cls row: xn[b,0] = x[b,0] + mean_t clsbuf[b*16+t] ----------------
__global__ __launch_bounds__(256)
void clsfin_k(const float* __restrict__ x, const float* __restrict__ cb, float* __restrict__ xn){
  int b = blockIdx.x;
  int c = blockIdx.y * 256 + threadIdx.x;
  float s = 0.f;
  #pragma unroll
  for (int t = 0; t < 16; t++) s += cb[((size_t)(b * 16 + t)) * 768 + c];
  xn[(size_t)b * 3137 * 768 + c] = x[(size_t)b * 3137 * 768 + c] + s * (1.f / 16.f);
}

// ======================================================================================
extern "C" void kernel_launch(void* const* d_in, const int* in_sizes, int n_in,
                              void* d_out, int out_size, void* d_ws, size_t ws_size,
                              hipStream_t stream){
  (void)in_sizes; (void)n_in; (void)out_size;
  const float* x    = (const float*)d_in[0];
  const float* ln1g = (const float*)d_in[1];
  const float* ln1b = (const float*)d_in[2];
  const float* tlng = (const float*)d_in[3];
  const float* tlnb = (const float*)d_in[4];
  const float* ln2g = (const float*)d_in[5];
  const float* ln2b = (const float*)d_in[6];
  const float* Ws   = (const float*)d_in[7];
  const float* bs   = (const float*)d_in[8];
  const float* Wt   = (const float*)d_in[9];
  const float* bt   = (const float*)d_in[10];
  const float* Wtp  = (const float*)d_in[11];
  const float* btp  = (const float*)d_in[12];
  const float* Wfc  = (const float*)d_in[13];
  const float* bfc  = (const float*)d_in[14];
  const float* W1   = (const float*)d_in[15];
  const float* b1   = (const float*)d_in[16];
  const float* W2   = (const float*)d_in[17];
  const float* b2   = (const float*)d_in[18];
  float* out = (float*)d_out;

  constexpr size_t MiB = 1048576;
  constexpr size_t C2  = 589824;
  constexpr size_t W_BYTES = (17 * C2 + 2 * 2359296) * 2;  // 29,491,200
  constexpr size_t NEED = W_BYTES + 145 * MiB;
  if (ws_size < NEED) return;

  char* wsb  = (char*)d_ws;
  u16*  wbuf = (u16*)wsb;
  u16*  W1T  = wbuf + 17 * C2;
  u16*  W2T  = W1T + (size_t)3072 * 768;
  char* A0   = wsb + W_BYTES;

  // slot map (MiB offsets in A0):
  //  [0,20)   ht | hs | os | h2        [20,40)  q16/q8/q4 | tp | qs  (a1 spans [20,93.6))
  //  [40,60)  k16/k8/k4 | ks           [60,88)  vt (temporal, 27.6MiB) | vts (spatial, 21MiB)
  //  [88,107) o16 | xt2(bf16)          [107,144) o8@107 o4@117 -> xn(f32)
  //  [144,..) clsb
  u16*  ht  = (u16*)(A0 + 0   * MiB);
  u16*  q16 = (u16*)(A0 + 20  * MiB);
  u16*  k16 = (u16*)(A0 + 40  * MiB);
  u16*  vtb = (u16*)(A0 + 60  * MiB);
  u16*  o16 = (u16*)(A0 + 88  * MiB);
  u16*  o8  = (u16*)(A0 + 107 * MiB);
  u16*  o4  = (u16*)(A0 + 117 * MiB);
  u16*  xt2 = (u16*)(A0 + 88  * MiB);
  float* xn = (float*)(A0 + 107 * MiB);
  float* clsb = (float*)(A0 + 144 * MiB);
  u16*  q8  = q16; u16* k8 = k16;
  u16*  q4  = q16; u16* k4 = k16;
  u16*  tp  = q16;
  u16*  hs  = ht;  u16* osb = ht; u16* h2 = ht;
  u16*  qsb = q16; u16* ksb = k16; u16* vts = vtb;
  u16*  a1  = q16;

  // -- weights -> transposed bf16
  twt17_k<<<dim3(24, 24, 17), 256, 0, stream>>>(Ws, Wt, Wtp, Wfc, wbuf);
  twt_k<<<dim3(96, 24), 256, 0, stream>>>(W1, W1T, 768, 3072);
  twt_k<<<dim3(24, 96), 256, 0, stream>>>(W2, W2T, 3072, 768);

  // -- temporal LN
  ln_k<0><<<3136, 256, 0, stream>>>(x, nullptr, tlng, tlnb, ht);

  // -- scale 16: QKV (V -> transposed layout) + attn
  gemm_k<0><<<dim3(6, 98), 256, 0, stream>>>(ht, wbuf + 10*C2, bt + 6*768, q16, nullptr, nullptr, 12544, 768, 768, 768, 1,1,0, 1,1,0);
  gemm_k<0><<<dim3(6, 98), 256, 0, stream>>>(ht, wbuf + 11*C2, bt + 7*768, k16, nullptr, nullptr, 12544, 768, 768, 768, 1,1,0, 1,1,0);
  gemm_k<7><<<dim3(6, 98), 256, 0, stream>>>(ht, wbuf + 12*C2, bt + 8*768, vtb, nullptr, nullptr, 12544, 768, 768, 24, 1,1,0, 16,1,0);
  tattn_k<16,24><<<2352, 256, 0, stream>>>(q16, k16, vtb, o16);

  // -- scale 8
  gemm_k<0><<<dim3(6, 49), 256, 0, stream>>>(ht, wbuf +  7*C2, bt + 3*768, q8, nullptr, nullptr, 6272, 768, 768, 768, 8,16,8, 1,1,0);
  gemm_k<0><<<dim3(6, 49), 256, 0, stream>>>(ht, wbuf +  8*C2, bt + 4*768, k8, nullptr, nullptr, 6272, 768, 768, 768, 8,16,8, 1,1,0);
  gemm_k<7><<<dim3(6, 49), 256, 0, stream>>>(ht, wbuf +  9*C2, bt + 5*768, vtb, nullptr, nullptr, 6272, 768, 768, 16, 8,16,8, 8,1,0);
  tattn_k< 8,16><<<2352, 256, 0, stream>>>(q8, k8, vtb, o8);

  // -- scale 4
  gemm_k<0><<<dim3(6, 25), 256, 0, stream>>>(ht, wbuf +  4*C2, bt + 0*768, q4, nullptr, nullptr, 3136, 768, 768, 768, 4,16,12, 1,1,0);
  gemm_k<0><<<dim3(6, 25), 256, 0, stream>>>(ht, wbuf +  5*C2, bt + 1*768, k4, nullptr, nullptr, 3136, 768, 768, 768, 4,16,12, 1,1,0);
  gemm_k<7><<<dim3(6, 25), 256, 0, stream>>>(ht, wbuf +  6*C2, bt + 2*768, vtb, nullptr, nullptr, 3136, 768, 768, 16, 4,16,12, 4,1,0);
  tattn_k< 4,16><<<2352, 256, 0, stream>>>(q4, k4, vtb, o4);

  // -- projection + blend chain; then tp, xt2
  gemm_k<1><<<dim3(6, 25), 256, 0, stream>>>(o4,  wbuf + 13*C2, btp + 0,    o8,  nullptr, nullptr, 3136, 768, 768, 768, 1,1,0, 4,8,4);
  gemm_k<1><<<dim3(6, 49), 256, 0, stream>>>(o8,  wbuf + 14*C2, btp + 768,  o16, nullptr, nullptr, 6272, 768, 768, 768, 1,1,0, 8,16,8);
  gemm_k<0><<<dim3(6, 98), 256, 0, stream>>>(o16, wbuf + 15*C2, btp + 1536, tp,  nullptr, nullptr, 12544, 768, 768, 768, 1,1,0, 1,1,0);
  gemm_k<2><<<dim3(6, 98), 256, 0, stream>>>(tp,  wbuf + 16*C2, bfc,        xt2, x, nullptr,       12544, 768, 768, 768, 1,1,0, 1,1,0);

  // -- spatial LN + QKV
  ln_k<1><<<3152, 256, 0, stream>>>(x, xt2, ln1g, ln1b, hs);
  gemm_k<0><<<dim3(6, 99), 256, 0, stream>>>(hs, wbuf + 0*C2, bs + 0,    qsb, nullptr, nullptr, 12608, 768, 768, 768, 1,1,0, 1,1,0);
  gemm_k<0><<<dim3(6, 99), 256, 0, stream>>>(hs, wbuf + 1*C2, bs + 768,  ksb, nullptr, nullptr, 12608, 768, 768, 768, 1,1,0, 1,1,0);
  fillz_k<<<2048, 256, 0, stream>>>((u32*)vts, 5505024);
  gemm_k<6><<<dim3(6, 99), 256, 0, stream>>>(hs, wbuf + 2*C2, bs + 1536, vts, nullptr, nullptr, 12608, 768, 768, 0, 1,1,0, 1,1,0);

  // -- spatial attention
  sattn_k<<<9984, 64, 0, stream>>>(qsb, ksb, vts, osb);

  // -- spatial proj + residual scatter into xn, cls rows
  gemm_k<3><<<dim3(6, 99), 256, 0, stream>>>(osb, wbuf + 3*C2, bs + 2304, xn, xt2, clsb, 12608, 768, 768, 768, 1,1,0, 1,1,0);
  clsfin_k<<<dim3(4, 3), 256, 0, stream>>>(x, clsb, xn);

  // -- final LN + MLP
  ln_k<2><<<3137, 256, 0, stream>>>(xn, nullptr, ln2g, ln2b, h2);
  gemm_k<4><<<dim3(24, 99), 256, 0, stream>>>(h2, W1T, b1, a1,  nullptr, nullptr, 12548, 768, 768, 3072, 1,1,0, 1,1,0);
  gemm_k<5><<<dim3(6, 99), 256, 0, stream>>>(a1, W2T, b2, out, xn, nullptr,       12548, 3072, 3072, 768, 1,1,0, 1,1,0);
}

// Round 4
// 949.951 us; speedup vs baseline: 1.2845x; 1.1091x over previous
//
#include <hip/hip_runtime.h>

typedef unsigned short u16;
typedef unsigned int   u32;
typedef __attribute__((ext_vector_type(8))) __bf16 bf16x8;
typedef __attribute__((ext_vector_type(4))) float  f32x4;
typedef __attribute__((ext_vector_type(4))) u16    u16x4;

#define DEV __device__ __forceinline__

DEV float bf2f(u16 u){ union { u32 i; float f; } x; x.i = ((u32)u) << 16; return x.f; }
DEV u16 f2bf(float f){ union { float f; u32 i; } x; x.f = f;
  u32 r = x.i + 0x7fffu + ((x.i >> 16) & 1u); return (u16)(r >> 16); }

DEV void gload16(const void* g, void* l){
  __builtin_amdgcn_global_load_lds((const __attribute__((address_space(1))) void*)g,
                                   (__attribute__((address_space(3))) void*)l, 16, 0, 0);
}

// ---------------- weight transpose+convert: dst[n*R + k] = src[k*C + n] (bf16) ----------
__global__ __launch_bounds__(256)
void twt_k(const float* __restrict__ src, u16* __restrict__ dst, int R, int C){
  __shared__ float t[32][33];
  int tx = threadIdx.x & 31, ty = threadIdx.x >> 5;
  int c0 = blockIdx.x * 32, r0 = blockIdx.y * 32;
  #pragma unroll
  for (int i = 0; i < 4; i++)
    t[ty + i*8][tx] = src[(size_t)(r0 + ty + i*8) * C + c0 + tx];
  __syncthreads();
  #pragma unroll
  for (int i = 0; i < 4; i++)
    dst[(size_t)(c0 + ty + i*8) * R + r0 + tx] = f2bf(t[tx][ty + i*8]);
}

// 17 square 768x768 mats in one launch (z = matrix id)
__global__ __launch_bounds__(256)
void twt17_k(const float* __restrict__ Ws, const float* __restrict__ Wt,
             const float* __restrict__ Wtp, const float* __restrict__ Wfc,
             u16* __restrict__ dst){
  __shared__ float t[32][33];
  int z = blockIdx.z;
  const float* src = (z < 4)  ? Ws  + (size_t)z * 589824
                   : (z < 13) ? Wt  + (size_t)(z-4) * 589824
                   : (z < 16) ? Wtp + (size_t)(z-13) * 589824
                   : Wfc;
  u16* d = dst + (size_t)z * 589824;
  int tx = threadIdx.x & 31, ty = threadIdx.x >> 5;
  int c0 = blockIdx.x * 32, r0 = blockIdx.y * 32;
  #pragma unroll
  for (int i = 0; i < 4; i++)
    t[ty + i*8][tx] = src[(size_t)(r0 + ty + i*8) * 768 + c0 + tx];
  __syncthreads();
  #pragma unroll
  for (int i = 0; i < 4; i++)
    d[(size_t)(c0 + ty + i*8) * 768 + r0 + tx] = f2bf(t[tx][ty + i*8]);
}

// ---------------- zero fill (u32 granularity) ----------------
__global__ void fillz_k(u32* __restrict__ p, long n){
  long i = (long)blockIdx.x * 256 + threadIdx.x;
  long stride = (long)gridDim.x * 256;
  for (; i < n; i += stride) p[i] = 0;
}

// ---------------- LayerNorm over C=768, one wave per token, out bf16 -------------
template<int GM>
__global__ __launch_bounds__(256)
void ln_k(const float* __restrict__ f0, const u16* __restrict__ b0_,
          const float* __restrict__ gw, const float* __restrict__ bw,
          u16* __restrict__ out){
  int lane = threadIdx.x & 63;
  int tok = blockIdx.x * 4 + (threadIdx.x >> 6);
  const float* fsrc = nullptr; const u16* bsrc = nullptr;
  bool bfp = false;
  if constexpr (GM == 0){
    int b = tok / 3136, m = tok - b * 3136;
    fsrc = f0 + ((size_t)b * 3137 + 1 + m) * 768;
  } else if constexpr (GM == 1){
    int s = tok / 197, j = tok - s * 197;
    int b = s >> 4, t = s & 15;
    if (j == 0) fsrc = f0 + (size_t)b * 3137 * 768;
    else { bfp = true; bsrc = b0_ + ((size_t)b * 3136 + (size_t)(j - 1) * 16 + t) * 768; }
  } else {
    fsrc = f0 + (size_t)tok * 768;
  }
  float v[12]; float s1 = 0.f, s2 = 0.f;
  if (!bfp){
    #pragma unroll
    for (int i = 0; i < 3; i++){
      float4 f = *(const float4*)(fsrc + i * 256 + lane * 4);
      v[i*4+0] = f.x; v[i*4+1] = f.y; v[i*4+2] = f.z; v[i*4+3] = f.w;
    }
  } else {
    #pragma unroll
    for (int i = 0; i < 3; i++){
      u16x4 p = *(const u16x4*)(bsrc + i * 256 + lane * 4);
      v[i*4+0] = bf2f(p[0]); v[i*4+1] = bf2f(p[1]); v[i*4+2] = bf2f(p[2]); v[i*4+3] = bf2f(p[3]);
    }
  }
  #pragma unroll
  for (int i = 0; i < 12; i++){ s1 += v[i]; s2 += v[i]*v[i]; }
  #pragma unroll
  for (int off = 32; off; off >>= 1){ s1 += __shfl_xor(s1, off); s2 += __shfl_xor(s2, off); }
  float mu = s1 * (1.f/768.f);
  float rstd = rsqrtf(s2 * (1.f/768.f) - mu*mu + 1e-5f);
  #pragma unroll
  for (int i = 0; i < 3; i++){
    int c = i * 256 + lane * 4;
    float4 g4 = *(const float4*)(gw + c);
    float4 b4 = *(const float4*)(bw + c);
    u16x4 pk;
    pk[0] = f2bf((v[i*4+0]-mu)*rstd*g4.x + b4.x);
    pk[1] = f2bf((v[i*4+1]-mu)*rstd*g4.y + b4.y);
    pk[2] = f2bf((v[i*4+2]-mu)*rstd*g4.z + b4.z);
    pk[3] = f2bf((v[i*4+3]-mu)*rstd*g4.w + b4.w);
    *(u16x4*)(out + (size_t)tok * 768 + c) = pk;
  }
}

// ---------------- GEMM: C = Amap @ Bw^T(+bias), 128x128 tile, bf16 MFMA ----------------
// 2-phase pipeline: double-buffered LDS, STAGE(next) issued BEFORE compute(cur),
// single barrier per K-step (its implicit vmcnt(0) lands after the MFMA block).
// A row map r -> (r/aTs)*aTf + at0 + r%aTs ; Bw: (N x K) bf16 row-major
// MODE 0: bf16 out[R*ldo+Cg]
// MODE 1: blend: Ro=(R/oTs)*oTf+ot0+R%oTs; out[Ro*ldo+Cg] = bf16(0.5*val+0.5*old)
// MODE 2: bf16 out[R*768+Cg] = val + aux1(x,f32)[((R/3136)*3137+1+R%3136)*768+Cg]
// MODE 3: spatial scatter (+cls buffer)  MODE 4: gelu bf16 (tanh form)
// MODE 5: f32 out = val + aux1(f32)      MODE 6: spatial vT (stride 224)
// MODE 7: temporal vT: out[(((R/oTs)*12+(Cg>>6))*64+(Cg&63))*ldo + R%oTs]
template<int MODE>
__global__ __launch_bounds__(256)
void gemm_k(const u16* __restrict__ A, const u16* __restrict__ Bw,
            const float* __restrict__ bias, void* out,
            const void* aux1, void* aux2,
            int M, int K, int lda, int ldo,
            int aTs, int aTf, int at0, int oTs, int oTf, int ot0){
  __shared__ u16 lA[2][128 * 32];
  __shared__ u16 lB[2][128 * 32];
  const int tid = threadIdx.x;
  const int m0 = blockIdx.y * 128, n0 = blockIdx.x * 128;
  const int lane = tid & 63, widx = tid >> 6;
  const int g = lane >> 4, r16 = lane & 15;
  const int wm = widx >> 1, wn = widx & 1;

  const u16* ga[2]; const u16* gb[2]; int lo[2];
  #pragma unroll
  for (int rnd = 0; rnd < 2; ++rnd){
    int li = tid + rnd * 256;
    int ar = m0 + (li >> 2); if (ar > M - 1) ar = M - 1;
    ar = (ar / aTs) * aTf + at0 + (ar % aTs);
    ga[rnd] = A + (size_t)ar * lda + (li & 3) * 8;
    gb[rnd] = Bw + (size_t)(n0 + (li >> 2)) * K + (li & 3) * 8;
    lo[rnd] = li * 8;
  }

  const f32x4 vz = {0.f, 0.f, 0.f, 0.f};
  f32x4 acc[4][4];
  #pragma unroll
  for (int i = 0; i < 4; i++)
    #pragma unroll
    for (int j = 0; j < 4; j++) acc[i][j] = vz;

  const int kiter = K >> 5;

  // prologue: stage k-tile 0 into buf 0
  gload16(ga[0], &lA[0][lo[0]]);
  gload16(ga[1], &lA[0][lo[1]]);
  gload16(gb[0], &lB[0][lo[0]]);
  gload16(gb[1], &lB[0][lo[1]]);
  __syncthreads();

  for (int kt = 0; kt < kiter; ++kt){
    const int cur = kt & 1;
    if (kt + 1 < kiter){           // issue next-tile loads BEFORE compute
      const int nxt = cur ^ 1;
      gload16(ga[0] + (kt + 1) * 32, &lA[nxt][lo[0]]);
      gload16(ga[1] + (kt + 1) * 32, &lA[nxt][lo[1]]);
      gload16(gb[0] + (kt + 1) * 32, &lB[nxt][lo[0]]);
      gload16(gb[1] + (kt + 1) * 32, &lB[nxt][lo[1]]);
    }
    bf16x8 af[4], bfr[4];
    #pragma unroll
    for (int i = 0; i < 4; i++){
      af[i]  = *(const bf16x8*)(&lA[cur][(wm * 64 + i * 16 + r16) * 32 + g * 8]);
      bfr[i] = *(const bf16x8*)(&lB[cur][(wn * 64 + i * 16 + r16) * 32 + g * 8]);
    }
    #pragma unroll
    for (int i = 0; i < 4; i++)
      #pragma unroll
      for (int j = 0; j < 4; j++)
        acc[i][j] = __builtin_amdgcn_mfma_f32_16x16x32_bf16(af[i], bfr[j], acc[i][j], 0, 0, 0);
    __syncthreads();               // implicit vmcnt(0)+lgkmcnt(0) after compute
  }

  #pragma unroll
  for (int i = 0; i < 4; i++){
    const int lrow = wm * 64 + i * 16 + g * 4;
    #pragma unroll
    for (int j = 0; j < 4; j++){
      const int Cg = n0 + wn * 64 + j * 16 + r16;
      const float b0 = bias[Cg];
      #pragma unroll
      for (int r = 0; r < 4; r++){
        const int R = m0 + lrow + r;
        if (R >= M) continue;
        float val = acc[i][j][r] + b0;
        if constexpr (MODE == 0){
          ((u16*)out)[(size_t)R * ldo + Cg] = f2bf(val);
        } else if constexpr (MODE == 1){
          int Ro = (R / oTs) * oTf + ot0 + (R % oTs);
          u16* po = (u16*)out + (size_t)Ro * ldo + Cg;
          *po = f2bf(0.5f * val + 0.5f * bf2f(*po));
        } else if constexpr (MODE == 2){
          int b_ = R / 3136, m_ = R - b_ * 3136;
          ((u16*)out)[(size_t)R * 768 + Cg] =
              f2bf(val + ((const float*)aux1)[((size_t)b_ * 3137 + 1 + m_) * 768 + Cg]);
        } else if constexpr (MODE == 3){
          int s_ = R / 197, j_ = R - s_ * 197;
          if (j_ == 0){
            ((float*)aux2)[(size_t)s_ * 768 + Cg] = val;
          } else {
            int b_ = s_ >> 4, t_ = s_ & 15, m_ = (j_ - 1) * 16 + t_;
            ((float*)out)[((size_t)b_ * 3137 + 1 + m_) * 768 + Cg] =
                val + bf2f(((const u16*)aux1)[((size_t)b_ * 3136 + m_) * 768 + Cg]);
          }
        } else if constexpr (MODE == 4){
          // gelu, tanh form: err vs exact erf ~3e-4, negligible after W2
          float c = val * (0.7978845608f + 0.0356774081f * val * val);
          float e2 = __expf(2.f * fabsf(c));          // >= 1, inf-safe
          float th = __builtin_copysignf(1.f - 2.f / (e2 + 1.f), c);
          ((u16*)out)[(size_t)R * ldo + Cg] = f2bf(0.5f * val * (1.f + th));
        } else if constexpr (MODE == 5){
          ((float*)out)[(size_t)R * 768 + Cg] = val + ((const float*)aux1)[(size_t)R * 768 + Cg];
        } else if constexpr (MODE == 6){
          int s_ = R / 197, j_ = R - s_ * 197;
          int h_ = Cg >> 6, d_ = Cg & 63;
          ((u16*)out)[(((size_t)(s_ * 12 + h_) * 64 + d_) * 224) + j_] = f2bf(val);
        } else if constexpr (MODE == 7){
          int seq_ = R / oTs, t_ = R - seq_ * oTs;
          int h_ = Cg >> 6, d_ = Cg & 63;
          ((u16*)out)[((size_t)(seq_ * 12 + h_) * 64 + d_) * ldo + t_] = f2bf(val);
        }
      }
    }
  }
}

// ---------------- temporal attention via MFMA: one wave per (seq,head) ----------------
template<int TS, int TSPAD>
__global__ __launch_bounds__(256)
void tattn_k(const u16* __restrict__ q, const u16* __restrict__ k,
             const u16* __restrict__ vt, u16* __restrict__ o){
  const int lane = threadIdx.x & 63;
  const int g = lane >> 4, r16 = lane & 15;
  int p = blockIdx.x * 4 + (threadIdx.x >> 6);
  int seq = p / 12, h = p - seq * 12;

  int trow = (TS < 16 && r16 >= TS) ? TS - 1 : r16;
  size_t qko = (size_t)(seq * TS + trow) * 768 + h * 64 + g * 8;
  bf16x8 ak0 = *(const bf16x8*)(k + qko);
  bf16x8 ak1 = *(const bf16x8*)(k + qko + 32);
  bf16x8 bq0 = *(const bf16x8*)(q + qko);
  bf16x8 bq1 = *(const bf16x8*)(q + qko + 32);

  f32x4 s = {0.f, 0.f, 0.f, 0.f};
  s = __builtin_amdgcn_mfma_f32_16x16x32_bf16(ak0, bq0, s, 0, 0, 0);
  s = __builtin_amdgcn_mfma_f32_16x16x32_bf16(ak1, bq1, s, 0, 0, 0);

  const float C = 0.125f * 1.44269504089f;
  float pv[4]; float mx = -3e38f;
  #pragma unroll
  for (int r = 0; r < 4; r++){
    float x = (g * 4 + r < TS) ? s[r] : -3e38f;
    pv[r] = x; mx = fmaxf(mx, x);
  }
  mx = fmaxf(mx, __shfl_xor(mx, 16));
  mx = fmaxf(mx, __shfl_xor(mx, 32));
  float sum = 0.f;
  #pragma unroll
  for (int r = 0; r < 4; r++){ pv[r] = exp2f((pv[r] - mx) * C); sum += pv[r]; }
  sum += __shfl_xor(sum, 16);
  sum += __shfl_xor(sum, 32);
  float inv = 1.f / sum;
  #pragma unroll
  for (int r = 0; r < 4; r++) pv[r] *= inv;

  u32 w0 = (u32)f2bf(pv[0]) | ((u32)f2bf(pv[1]) << 16);
  u32 w1 = (u32)f2bf(pv[2]) | ((u32)f2bf(pv[3]) << 16);
  int a0 = ((g * 2) * 16 + r16) * 4;
  int a1 = ((g * 2 + 1) * 16 + r16) * 4;
  u32 msk = (g < 2) ? 0xFFFFFFFFu : 0u;
  union { u32 w[4]; bf16x8 v; } pa;
  pa.w[0] = msk & (u32)__builtin_amdgcn_ds_bpermute(a0, (int)w0);
  pa.w[1] = msk & (u32)__builtin_amdgcn_ds_bpermute(a0, (int)w1);
  pa.w[2] = msk & (u32)__builtin_amdgcn_ds_bpermute(a1, (int)w0);
  pa.w[3] = msk & (u32)__builtin_amdgcn_ds_bpermute(a1, (int)w1);

  const u16* vb = vt + ((size_t)(seq * 12 + h) * 64) * TSPAD;
  const f32x4 vz = {0.f, 0.f, 0.f, 0.f};
  f32x4 oc[4];
  #pragma unroll
  for (int dt = 0; dt < 4; ++dt){
    bf16x8 bv = *(const bf16x8*)(vb + (size_t)(dt * 16 + r16) * TSPAD + g * 8);
    oc[dt] = __builtin_amdgcn_mfma_f32_16x16x32_bf16(pa.v, bv, vz, 0, 0, 0);
  }
  #pragma unroll
  for (int rr = 0; rr < 4; ++rr){
    int qr = g * 4 + rr;
    if (qr < TS){
      size_t ob = (size_t)(seq * TS + qr) * 768 + h * 64 + r16;
      #pragma unroll
      for (int dt = 0; dt < 4; ++dt)
        o[ob + dt * 16] = f2bf(oc[dt][rr]);
    }
  }
}

// ---------------- spatial attention: 1 wave per (seq,head,16-row q-chunk) --------------
__global__ __launch_bounds__(64)
void sattn_k(const u16* __restrict__ qs, const u16* __restrict__ ks,
             const u16* __restrict__ vt, u16* __restrict__ o){
  __shared__ u16 Pl[16 * 224];
  const int lane = threadIdx.x & 63;
  const int g = lane >> 4, r16 = lane & 15;
  int bid = blockIdx.x;
  int chunk = bid % 13; int sh = bid / 13;
  int h = sh % 12, s = sh / 12;
  const float sc_l2e = 0.125f * 1.44269504089f;

  #pragma unroll
  for (int i = 0; i < 4; i++) Pl[(i * 4 + g) * 224 + 208 + r16] = 0;

  int q0 = chunk * 16;
  int qrow = q0 + r16; if (qrow > 196) qrow = 196;
  const u16* qp = qs + ((size_t)(s * 197 + qrow)) * 768 + h * 64 + g * 8;
  bf16x8 aq0 = *(const bf16x8*)qp;
  bf16x8 aq1 = *(const bf16x8*)(qp + 32);

  f32x4 scv[13];
  #pragma unroll
  for (int jt = 0; jt < 13; ++jt){
    int krow = jt * 16 + r16; if (krow > 196) krow = 196;
    const u16* kp = ks + ((size_t)(s * 197 + krow)) * 768 + h * 64 + g * 8;
    bf16x8 b0 = *(const bf16x8*)kp;
    bf16x8 b1 = *(const bf16x8*)(kp + 32);
    f32x4 z = {0.f, 0.f, 0.f, 0.f};
    z = __builtin_amdgcn_mfma_f32_16x16x32_bf16(aq0, b0, z, 0, 0, 0);
    z = __builtin_amdgcn_mfma_f32_16x16x32_bf16(aq1, b1, z, 0, 0, 0);
    scv[jt] = z;
  }
  float mrow[4] = {-3e38f, -3e38f, -3e38f, -3e38f};
  #pragma unroll
  for (int jt = 0; jt < 13; ++jt)
    #pragma unroll
    for (int r = 0; r < 4; r++){
      float x = (jt * 16 + r16 < 197) ? scv[jt][r] : -3e38f;
      scv[jt][r] = x;
      mrow[r] = fmaxf(mrow[r], x);
    }
  #pragma unroll
  for (int off = 1; off < 16; off <<= 1)
    #pragma unroll
    for (int r = 0; r < 4; r++) mrow[r] = fmaxf(mrow[r], __shfl_xor(mrow[r], off));
  float srow[4] = {0.f, 0.f, 0.f, 0.f};
  #pragma unroll
  for (int jt = 0; jt < 13; ++jt)
    #pragma unroll
    for (int r = 0; r < 4; r++){
      float e = exp2f((scv[jt][r] - mrow[r]) * sc_l2e);
      scv[jt][r] = e;
      srow[r] += e;
    }
  #pragma unroll
  for (int off = 1; off < 16; off <<= 1)
    #pragma unroll
    for (int r = 0; r < 4; r++) srow[r] += __shfl_xor(srow[r], off);
  float inv[4];
  #pragma unroll
  for (int r = 0; r < 4; r++) inv[r] = 1.f / srow[r];
  #pragma unroll
  for (int jt = 0; jt < 13; ++jt)
    #pragma unroll
    for (int r = 0; r < 4; r++)
      Pl[(g * 4 + r) * 224 + jt * 16 + r16] = f2bf(scv[jt][r] * inv[r]);
  __syncthreads();
  const u16* vbase = vt + ((size_t)(s * 12 + h) * 64) * 224;
  f32x4 oc[4]; const f32x4 vz = {0.f,0.f,0.f,0.f};
  #pragma unroll
  for (int dt = 0; dt < 4; dt++) oc[dt] = vz;
  #pragma unroll
  for (int ks2 = 0; ks2 < 7; ++ks2){
    bf16x8 ap = *(const bf16x8*)(Pl + r16 * 224 + ks2 * 32 + g * 8);
    #pragma unroll
    for (int dt = 0; dt < 4; ++dt){
      const u16* vp = vbase + ((size_t)(dt * 16 + r16)) * 224 + ks2 * 32 + g * 8;
      bf16x8 bv = *(const bf16x8*)vp;
      oc[dt] = __builtin_amdgcn_mfma_f32_16x16x32_bf16(ap, bv, oc[dt], 0, 0, 0);
    }
  }
  #pragma unroll
  for (int dt = 0; dt < 4; ++dt)
    #pragma unroll
    for (int r = 0; r < 4; r++){
      int qr2 = q0 + g * 4 + r;
      if (qr2 < 197)
        o[((size_t)(s * 197 + qr2)) * 768 + h * 64 + dt * 16 + r16] = f2bf(oc[dt][r]);
    }
}

// ---------------- cls row: xn[b,0] = x[b,0] + mean_t clsbuf[b*16+t] ----------------
__global__ __launch_bounds__(256)
void clsfin_k(const float* __restrict__ x, const float* __restrict__ cb, float* __restrict__ xn){
  int b = blockIdx.x;
  int c = blockIdx.y * 256 + threadIdx.x;
  float s = 0.f;
  #pragma unroll
  for (int t = 0; t < 16; t++) s += cb[((size_t)(b * 16 + t)) * 768 + c];
  xn[(size_t)b * 3137 * 768 + c] = x[(size_t)b * 3137 * 768 + c] + s * (1.f / 16.f);
}

// ======================================================================================
extern "C" void kernel_launch(void* const* d_in, const int* in_sizes, int n_in,
                              void* d_out, int out_size, void* d_ws, size_t ws_size,
                              hipStream_t stream){
  (void)in_sizes; (void)n_in; (void)out_size;
  const float* x    = (const float*)d_in[0];
  const float* ln1g = (const float*)d_in[1];
  const float* ln1b = (const float*)d_in[2];
  const float* tlng = (const float*)d_in[3];
  const float* tlnb = (const float*)d_in[4];
  const float* ln2g = (const float*)d_in[5];
  const float* ln2b = (const float*)d_in[6];
  const float* Ws   = (const float*)d_in[7];
  const float* bs   = (const float*)d_in[8];
  const float* Wt   = (const float*)d_in[9];
  const float* bt   = (const float*)d_in[10];
  const float* Wtp  = (const float*)d_in[11];
  const float* btp  = (const float*)d_in[12];
  const float* Wfc  = (const float*)d_in[13];
  const float* bfc  = (const float*)d_in[14];
  const float* W1   = (const float*)d_in[15];
  const float* b1   = (const float*)d_in[16];
  const float* W2   = (const float*)d_in[17];
  const float* b2   = (const float*)d_in[18];
  float* out = (float*)d_out;

  constexpr size_t MiB = 1048576;
  constexpr size_t C2  = 589824;
  constexpr size_t W_BYTES = (17 * C2 + 2 * 2359296) * 2;  // 29,491,200
  constexpr size_t NEED = W_BYTES + 145 * MiB;
  if (ws_size < NEED) return;

  char* wsb  = (char*)d_ws;
  u16*  wbuf = (u16*)wsb;
  u16*  W1T  = wbuf + 17 * C2;
  u16*  W2T  = W1T + (size_t)3072 * 768;
  char* A0   = wsb + W_BYTES;

  u16*  ht  = (u16*)(A0 + 0   * MiB);
  u16*  q16 = (u16*)(A0 + 20  * MiB);
  u16*  k16 = (u16*)(A0 + 40  * MiB);
  u16*  vtb = (u16*)(A0 + 60  * MiB);
  u16*  o16 = (u16*)(A0 + 88  * MiB);
  u16*  o8  = (u16*)(A0 + 107 * MiB);
  u16*  o4  = (u16*)(A0 + 117 * MiB);
  u16*  xt2 = (u16*)(A0 + 88  * MiB);
  float* xn = (float*)(A0 + 107 * MiB);
  float* clsb = (float*)(A0 + 144 * MiB);
  u16*  q8  = q16; u16* k8 = k16;
  u16*  q4  = q16; u16* k4 = k16;
  u16*  tp  = q16;
  u16*  hs  = ht;  u16* osb = ht; u16* h2 = ht;
  u16*  qsb = q16; u16* ksb = k16; u16* vts = vtb;
  u16*  a1  = q16;

  // -- weights -> transposed bf16
  twt17_k<<<dim3(24, 24, 17), 256, 0, stream>>>(Ws, Wt, Wtp, Wfc, wbuf);
  twt_k<<<dim3(96, 24), 256, 0, stream>>>(W1, W1T, 768, 3072);
  twt_k<<<dim3(24, 96), 256, 0, stream>>>(W2, W2T, 3072, 768);

  // -- temporal LN
  ln_k<0><<<3136, 256, 0, stream>>>(x, nullptr, tlng, tlnb, ht);

  // -- scale 16: QKV (V -> transposed layout) + attn
  gemm_k<0><<<dim3(6, 98), 256, 0, stream>>>(ht, wbuf + 10*C2, bt + 6*768, q16, nullptr, nullptr, 12544, 768, 768, 768, 1,1,0, 1,1,0);
  gemm_k<0><<<dim3(6, 98), 256, 0, stream>>>(ht, wbuf + 11*C2, bt + 7*768, k16, nullptr, nullptr, 12544, 768, 768, 768, 1,1,0, 1,1,0);
  gemm_k<7><<<dim3(6, 98), 256, 0, stream>>>(ht, wbuf + 12*C2, bt + 8*768, vtb, nullptr, nullptr, 12544, 768, 768, 24, 1,1,0, 16,1,0);
  tattn_k<16,24><<<2352, 256, 0, stream>>>(q16, k16, vtb, o16);

  // -- scale 8
  gemm_k<0><<<dim3(6, 49), 256, 0, stream>>>(ht, wbuf +  7*C2, bt + 3*768, q8, nullptr, nullptr, 6272, 768, 768, 768, 8,16,8, 1,1,0);
  gemm_k<0><<<dim3(6, 49), 256, 0, stream>>>(ht, wbuf +  8*C2, bt + 4*768, k8, nullptr, nullptr, 6272, 768, 768, 768, 8,16,8, 1,1,0);
  gemm_k<7><<<dim3(6, 49), 256, 0, stream>>>(ht, wbuf +  9*C2, bt + 5*768, vtb, nullptr, nullptr, 6272, 768, 768, 16, 8,16,8, 8,1,0);
  tattn_k< 8,16><<<2352, 256, 0, stream>>>(q8, k8, vtb, o8);

  // -- scale 4
  gemm_k<0><<<dim3(6, 25), 256, 0, stream>>>(ht, wbuf +  4*C2, bt + 0*768, q4, nullptr, nullptr, 3136, 768, 768, 768, 4,16,12, 1,1,0);
  gemm_k<0><<<dim3(6, 25), 256, 0, stream>>>(ht, wbuf +  5*C2, bt + 1*768, k4, nullptr, nullptr, 3136, 768, 768, 768, 4,16,12, 1,1,0);
  gemm_k<7><<<dim3(6, 25), 256, 0, stream>>>(ht, wbuf +  6*C2, bt + 2*768, vtb, nullptr, nullptr, 3136, 768, 768, 16, 4,16,12, 4,1,0);
  tattn_k< 4,16><<<2352, 256, 0, stream>>>(q4, k4, vtb, o4);

  // -- projection + blend chain; then tp, xt2
  gemm_k<1><<<dim3(6, 25), 256, 0, stream>>>(o4,  wbuf + 13*C2, btp + 0,    o8,  nullptr, nullptr, 3136, 768, 768, 768, 1,1,0, 4,8,4);
  gemm_k<1><<<dim3(6, 49), 256, 0, stream>>>(o8,  wbuf + 14*C2, btp + 768,  o16, nullptr, nullptr, 6272, 768, 768, 768, 1,1,0, 8,16,8);
  gemm_k<0><<<dim3(6, 98), 256, 0, stream>>>(o16, wbuf + 15*C2, btp + 1536, tp,  nullptr, nullptr, 12544, 768, 768, 768, 1,1,0, 1,1,0);
  gemm_k<2><<<dim3(6, 98), 256, 0, stream>>>(tp,  wbuf + 16*C2, bfc,        xt2, x, nullptr,       12544, 768, 768, 768, 1,1,0, 1,1,0);

  // -- spatial LN + QKV
  ln_k<1><<<3152, 256, 0, stream>>>(x, xt2, ln1g, ln1b, hs);
  gemm_k<0><<<dim3(6, 99), 256, 0, stream>>>(hs, wbuf + 0*C2, bs + 0,    qsb, nullptr, nullptr, 12608, 768, 768, 768, 1,1,0, 1,1,0);
  gemm_k<0><<<dim3(6, 99), 256, 0, stream>>>(hs, wbuf + 1*C2, bs + 768,  ksb, nullptr, nullptr, 12608, 768, 768, 768, 1,1,0, 1,1,0);
  fillz_k<<<2048, 256, 0, stream>>>((u32*)vts, 5505024);
  gemm_k<6><<<dim3(6, 99), 256, 0, stream>>>(hs, wbuf + 2*C2, bs + 1536, vts, nullptr, nullptr, 12608, 768, 768, 0, 1,1,0, 1,1,0);

  // -- spatial attention
  sattn_k<<<9984, 64, 0, stream>>>(qsb, ksb, vts, osb);

  // -- spatial proj + residual scatter into xn, cls rows
  gemm_k<3><<<dim3(6, 99), 256, 0, stream>>>(osb, wbuf + 3*C2, bs + 2304, xn, xt2, clsb, 12608, 768, 768, 768, 1,1,0, 1,1,0);
  clsfin_k<<<dim3(4, 3), 256, 0, stream>>>(x, clsb, xn);

  // -- final LN + MLP
  ln_k<2><<<3137, 256, 0, stream>>>(xn, nullptr, ln2g, ln2b, h2);
  gemm_k<4><<<dim3(24, 99), 256, 0, stream>>>(h2, W1T, b1, a1,  nullptr, nullptr, 12548, 768, 768, 3072, 1,1,0, 1,1,0);
  gemm_k<5><<<dim3(6, 99), 256, 0, stream>>>(a1, W2T, b2, out, xn, nullptr,       12548, 3072, 3072, 768, 1,1,0, 1,1,0);
}

// Round 5
// 933.778 us; speedup vs baseline: 1.3067x; 1.0173x over previous
//
#include <hip/hip_runtime.h>

typedef unsigned short u16;
typedef unsigned int   u32;
typedef __attribute__((ext_vector_type(8))) __bf16 bf16x8;
typedef __attribute__((ext_vector_type(4))) float  f32x4;
typedef __attribute__((ext_vector_type(4))) u16    u16x4;

#define DEV __device__ __forceinline__

DEV float bf2f(u16 u){ union { u32 i; float f; } x; x.i = ((u32)u) << 16; return x.f; }
DEV u16 f2bf(float f){ union { float f; u32 i; } x; x.f = f;
  u32 r = x.i + 0x7fffu + ((x.i >> 16) & 1u); return (u16)(r >> 16); }

DEV void gload16(const void* g, void* l){
  __builtin_amdgcn_global_load_lds((const __attribute__((address_space(1))) void*)g,
                                   (__attribute__((address_space(3))) void*)l, 16, 0, 0);
}

// ---------------- weight transpose+convert: dst[n*R + k] = src[k*C + n] (bf16) ----------
__global__ __launch_bounds__(256)
void twt_k(const float* __restrict__ src, u16* __restrict__ dst, int R, int C){
  __shared__ float t[32][33];
  int tx = threadIdx.x & 31, ty = threadIdx.x >> 5;
  int c0 = blockIdx.x * 32, r0 = blockIdx.y * 32;
  #pragma unroll
  for (int i = 0; i < 4; i++)
    t[ty + i*8][tx] = src[(size_t)(r0 + ty + i*8) * C + c0 + tx];
  __syncthreads();
  #pragma unroll
  for (int i = 0; i < 4; i++)
    dst[(size_t)(c0 + ty + i*8) * R + r0 + tx] = f2bf(t[tx][ty + i*8]);
}

// 17 square 768x768 mats in one launch (z = matrix id)
__global__ __launch_bounds__(256)
void twt17_k(const float* __restrict__ Ws, const float* __restrict__ Wt,
             const float* __restrict__ Wtp, const float* __restrict__ Wfc,
             u16* __restrict__ dst){
  __shared__ float t[32][33];
  int z = blockIdx.z;
  const float* src = (z < 4)  ? Ws  + (size_t)z * 589824
                   : (z < 13) ? Wt  + (size_t)(z-4) * 589824
                   : (z < 16) ? Wtp + (size_t)(z-13) * 589824
                   : Wfc;
  u16* d = dst + (size_t)z * 589824;
  int tx = threadIdx.x & 31, ty = threadIdx.x >> 5;
  int c0 = blockIdx.x * 32, r0 = blockIdx.y * 32;
  #pragma unroll
  for (int i = 0; i < 4; i++)
    t[ty + i*8][tx] = src[(size_t)(r0 + ty + i*8) * 768 + c0 + tx];
  __syncthreads();
  #pragma unroll
  for (int i = 0; i < 4; i++)
    d[(size_t)(c0 + ty + i*8) * 768 + r0 + tx] = f2bf(t[tx][ty + i*8]);
}

// ---------------- zero fill (u32 granularity) ----------------
__global__ void fillz_k(u32* __restrict__ p, long n){
  long i = (long)blockIdx.x * 256 + threadIdx.x;
  long stride = (long)gridDim.x * 256;
  for (; i < n; i += stride) p[i] = 0;
}

// ---------------- LayerNorm over C=768, one wave per token, out bf16 -------------
template<int GM>
__global__ __launch_bounds__(256)
void ln_k(const float* __restrict__ f0, const u16* __restrict__ b0_,
          const float* __restrict__ gw, const float* __restrict__ bw,
          u16* __restrict__ out){
  int lane = threadIdx.x & 63;
  int tok = blockIdx.x * 4 + (threadIdx.x >> 6);
  const float* fsrc = nullptr; const u16* bsrc = nullptr;
  bool bfp = false;
  if constexpr (GM == 0){
    int b = tok / 3136, m = tok - b * 3136;
    fsrc = f0 + ((size_t)b * 3137 + 1 + m) * 768;
  } else if constexpr (GM == 1){
    int s = tok / 197, j = tok - s * 197;
    int b = s >> 4, t = s & 15;
    if (j == 0) fsrc = f0 + (size_t)b * 3137 * 768;
    else { bfp = true; bsrc = b0_ + ((size_t)b * 3136 + (size_t)(j - 1) * 16 + t) * 768; }
  } else {
    fsrc = f0 + (size_t)tok * 768;
  }
  float v[12]; float s1 = 0.f, s2 = 0.f;
  if (!bfp){
    #pragma unroll
    for (int i = 0; i < 3; i++){
      float4 f = *(const float4*)(fsrc + i * 256 + lane * 4);
      v[i*4+0] = f.x; v[i*4+1] = f.y; v[i*4+2] = f.z; v[i*4+3] = f.w;
    }
  } else {
    #pragma unroll
    for (int i = 0; i < 3; i++){
      u16x4 p = *(const u16x4*)(bsrc + i * 256 + lane * 4);
      v[i*4+0] = bf2f(p[0]); v[i*4+1] = bf2f(p[1]); v[i*4+2] = bf2f(p[2]); v[i*4+3] = bf2f(p[3]);
    }
  }
  #pragma unroll
  for (int i = 0; i < 12; i++){ s1 += v[i]; s2 += v[i]*v[i]; }
  #pragma unroll
  for (int off = 32; off; off >>= 1){ s1 += __shfl_xor(s1, off); s2 += __shfl_xor(s2, off); }
  float mu = s1 * (1.f/768.f);
  float rstd = rsqrtf(s2 * (1.f/768.f) - mu*mu + 1e-5f);
  #pragma unroll
  for (int i = 0; i < 3; i++){
    int c = i * 256 + lane * 4;
    float4 g4 = *(const float4*)(gw + c);
    float4 b4 = *(const float4*)(bw + c);
    u16x4 pk;
    pk[0] = f2bf((v[i*4+0]-mu)*rstd*g4.x + b4.x);
    pk[1] = f2bf((v[i*4+1]-mu)*rstd*g4.y + b4.y);
    pk[2] = f2bf((v[i*4+2]-mu)*rstd*g4.z + b4.z);
    pk[3] = f2bf((v[i*4+3]-mu)*rstd*g4.w + b4.w);
    *(u16x4*)(out + (size_t)tok * 768 + c) = pk;
  }
}

// ---------------- GEMM: C = Amap @ Bw^T(+bias), 128x128 tile, bf16 MFMA ----------------
// Counted-vmcnt double-buffer pipeline (T4): stage(next) issued, vmcnt(4) keeps it in
// flight across the barrier; second barrier protects the restaged buffer.
// LDS k-chunk XOR swizzle (chunk ^= row&3) applied on BOTH sides: pre-swizzled global
// source (global_load_lds writes linearly) + swizzled ds_read column.
// A row map r -> (r/aTs)*aTf + at0 + r%aTs ; Bw: (N x K) bf16 row-major
// MODE 0: bf16 out[R*ldo+Cg]
// MODE 1: blend: Ro=(R/oTs)*oTf+ot0+R%oTs; out[Ro*ldo+Cg] = bf16(0.5*val+0.5*old)
// MODE 2: bf16 out[R*768+Cg] = val + aux1(x,f32)[((R/3136)*3137+1+R%3136)*768+Cg]
// MODE 3: spatial scatter (+cls buffer)  MODE 4: gelu bf16 (tanh form)
// MODE 5: f32 out = val + aux1(f32)
// MODE 8: fused temporal QKV: mat=Cg/768; mat<2 -> out[mat*ot0*768 + R*768 + c0];
//         mat==2 -> aux2 vT: [((R/oTs)*12+(c0>>6))*64+(c0&63)]*ldo + R%oTs
// MODE 9: fused spatial QKV: mat<2 -> out[mat*ot0*768 + R*768 + c0];
//         mat==2 -> aux2 vT: [((R/197)*12+(c0>>6))*64+(c0&63)]*224 + R%197
template<int MODE>
__global__ __launch_bounds__(256)
void gemm_k(const u16* __restrict__ A, const u16* __restrict__ Bw,
            const float* __restrict__ bias, void* out,
            const void* aux1, void* aux2,
            int M, int K, int lda, int ldo,
            int aTs, int aTf, int at0, int oTs, int oTf, int ot0){
  __shared__ u16 lA[2][128 * 32];
  __shared__ u16 lB[2][128 * 32];
  const int tid = threadIdx.x;
  const int m0 = blockIdx.y * 128, n0 = blockIdx.x * 128;
  const int lane = tid & 63, widx = tid >> 6;
  const int g = lane >> 4, r16 = lane & 15;
  const int wm = widx >> 1, wn = widx & 1;

  const u16* ga[2]; const u16* gb[2]; int lo[2];
  #pragma unroll
  for (int rnd = 0; rnd < 2; ++rnd){
    int li = tid + rnd * 256;
    int ar = m0 + (li >> 2); if (ar > M - 1) ar = M - 1;
    ar = (ar / aTs) * aTf + at0 + (ar % aTs);
    int csw = (li & 3) ^ ((li >> 2) & 3);      // chunk swizzle (both-sides)
    ga[rnd] = A + (size_t)ar * lda + csw * 8;
    gb[rnd] = Bw + (size_t)(n0 + (li >> 2)) * K + csw * 8;
    lo[rnd] = li * 8;
  }
  const int rda = (g ^ (r16 & 3)) * 8;         // swizzled read column

  const f32x4 vz = {0.f, 0.f, 0.f, 0.f};
  f32x4 acc[4][4];
  #pragma unroll
  for (int i = 0; i < 4; i++)
    #pragma unroll
    for (int j = 0; j < 4; j++) acc[i][j] = vz;

  const int kiter = K >> 5;

  // prologue: stage k-tile 0 into buf 0 (4 vmem instrs per wave)
  gload16(ga[0], &lA[0][lo[0]]);
  gload16(ga[1], &lA[0][lo[1]]);
  gload16(gb[0], &lB[0][lo[0]]);
  gload16(gb[1], &lB[0][lo[1]]);

  for (int kt = 0; kt < kiter; ++kt){
    const int cur = kt & 1;
    if (kt + 1 < kiter){                        // prefetch next tile
      const int nxt = cur ^ 1;
      gload16(ga[0] + (kt + 1) * 32, &lA[nxt][lo[0]]);
      gload16(ga[1] + (kt + 1) * 32, &lA[nxt][lo[1]]);
      gload16(gb[0] + (kt + 1) * 32, &lB[nxt][lo[0]]);
      gload16(gb[1] + (kt + 1) * 32, &lB[nxt][lo[1]]);
      asm volatile("s_waitcnt vmcnt(4)" ::: "memory");  // cur-tile loads done; prefetch flies
    } else {
      asm volatile("s_waitcnt vmcnt(0)" ::: "memory");
    }
    __builtin_amdgcn_s_barrier();               // all waves' cur-tile staged
    bf16x8 af[4], bfr[4];
    #pragma unroll
    for (int i = 0; i < 4; i++){
      af[i]  = *(const bf16x8*)(&lA[cur][(wm * 64 + i * 16 + r16) * 32 + rda]);
      bfr[i] = *(const bf16x8*)(&lB[cur][(wn * 64 + i * 16 + r16) * 32 + rda]);
    }
    #pragma unroll
    for (int i = 0; i < 4; i++)
      #pragma unroll
      for (int j = 0; j < 4; j++)
        acc[i][j] = __builtin_amdgcn_mfma_f32_16x16x32_bf16(af[i], bfr[j], acc[i][j], 0, 0, 0);
    asm volatile("s_waitcnt lgkmcnt(0)" ::: "memory");
    __builtin_amdgcn_s_barrier();               // done reading cur; next iter restages it
  }

  #pragma unroll
  for (int i = 0; i < 4; i++){
    const int lrow = wm * 64 + i * 16 + g * 4;
    #pragma unroll
    for (int j = 0; j < 4; j++){
      const int Cg = n0 + wn * 64 + j * 16 + r16;
      const float b0 = bias[Cg];
      #pragma unroll
      for (int r = 0; r < 4; r++){
        const int R = m0 + lrow + r;
        if (R >= M) continue;
        float val = acc[i][j][r] + b0;
        if constexpr (MODE == 0){
          ((u16*)out)[(size_t)R * ldo + Cg] = f2bf(val);
        } else if constexpr (MODE == 1){
          int Ro = (R / oTs) * oTf + ot0 + (R % oTs);
          u16* po = (u16*)out + (size_t)Ro * ldo + Cg;
          *po = f2bf(0.5f * val + 0.5f * bf2f(*po));
        } else if constexpr (MODE == 2){
          int b_ = R / 3136, m_ = R - b_ * 3136;
          ((u16*)out)[(size_t)R * 768 + Cg] =
              f2bf(val + ((const float*)aux1)[((size_t)b_ * 3137 + 1 + m_) * 768 + Cg]);
        } else if constexpr (MODE == 3){
          int s_ = R / 197, j_ = R - s_ * 197;
          if (j_ == 0){
            ((float*)aux2)[(size_t)s_ * 768 + Cg] = val;
          } else {
            int b_ = s_ >> 4, t_ = s_ & 15, m_ = (j_ - 1) * 16 + t_;
            ((float*)out)[((size_t)b_ * 3137 + 1 + m_) * 768 + Cg] =
                val + bf2f(((const u16*)aux1)[((size_t)b_ * 3136 + m_) * 768 + Cg]);
          }
        } else if constexpr (MODE == 4){
          float c = val * (0.7978845608f + 0.0356774081f * val * val);
          float e2 = __expf(2.f * fabsf(c));
          float th = __builtin_copysignf(1.f - 2.f / (e2 + 1.f), c);
          ((u16*)out)[(size_t)R * ldo + Cg] = f2bf(0.5f * val * (1.f + th));
        } else if constexpr (MODE == 5){
          ((float*)out)[(size_t)R * 768 + Cg] = val + ((const float*)aux1)[(size_t)R * 768 + Cg];
        } else if constexpr (MODE == 8){
          int mat = Cg / 768, c0 = Cg - mat * 768;
          if (mat < 2){
            ((u16*)out)[(size_t)mat * ot0 * 768 + (size_t)R * 768 + c0] = f2bf(val);
          } else {
            int seq_ = R / oTs, t_ = R - seq_ * oTs;
            ((u16*)aux2)[((size_t)(seq_ * 12 + (c0 >> 6)) * 64 + (c0 & 63)) * ldo + t_] = f2bf(val);
          }
        } else if constexpr (MODE == 9){
          int mat = Cg / 768, c0 = Cg - mat * 768;
          if (mat < 2){
            ((u16*)out)[(size_t)mat * ot0 * 768 + (size_t)R * 768 + c0] = f2bf(val);
          } else {
            int s_ = R / 197, j_ = R - s_ * 197;
            ((u16*)aux2)[(((size_t)(s_ * 12 + (c0 >> 6)) * 64 + (c0 & 63)) * 224) + j_] = f2bf(val);
          }
        }
      }
    }
  }
}

// ---------------- temporal attention via MFMA: one wave per (seq,head) ----------------
template<int TS, int TSPAD>
__global__ __launch_bounds__(256)
void tattn_k(const u16* __restrict__ q, const u16* __restrict__ k,
             const u16* __restrict__ vt, u16* __restrict__ o){
  const int lane = threadIdx.x & 63;
  const int g = lane >> 4, r16 = lane & 15;
  int p = blockIdx.x * 4 + (threadIdx.x >> 6);
  int seq = p / 12, h = p - seq * 12;

  int trow = (TS < 16 && r16 >= TS) ? TS - 1 : r16;
  size_t qko = (size_t)(seq * TS + trow) * 768 + h * 64 + g * 8;
  bf16x8 ak0 = *(const bf16x8*)(k + qko);
  bf16x8 ak1 = *(const bf16x8*)(k + qko + 32);
  bf16x8 bq0 = *(const bf16x8*)(q + qko);
  bf16x8 bq1 = *(const bf16x8*)(q + qko + 32);

  f32x4 s = {0.f, 0.f, 0.f, 0.f};
  s = __builtin_amdgcn_mfma_f32_16x16x32_bf16(ak0, bq0, s, 0, 0, 0);
  s = __builtin_amdgcn_mfma_f32_16x16x32_bf16(ak1, bq1, s, 0, 0, 0);

  const float C = 0.125f * 1.44269504089f;
  float pv[4]; float mx = -3e38f;
  #pragma unroll
  for (int r = 0; r < 4; r++){
    float x = (g * 4 + r < TS) ? s[r] : -3e38f;
    pv[r] = x; mx = fmaxf(mx, x);
  }
  mx = fmaxf(mx, __shfl_xor(mx, 16));
  mx = fmaxf(mx, __shfl_xor(mx, 32));
  float sum = 0.f;
  #pragma unroll
  for (int r = 0; r < 4; r++){ pv[r] = exp2f((pv[r] - mx) * C); sum += pv[r]; }
  sum += __shfl_xor(sum, 16);
  sum += __shfl_xor(sum, 32);
  float inv = 1.f / sum;
  #pragma unroll
  for (int r = 0; r < 4; r++) pv[r] *= inv;

  u32 w0 = (u32)f2bf(pv[0]) | ((u32)f2bf(pv[1]) << 16);
  u32 w1 = (u32)f2bf(pv[2]) | ((u32)f2bf(pv[3]) << 16);
  int a0 = ((g * 2) * 16 + r16) * 4;
  int a1 = ((g * 2 + 1) * 16 + r16) * 4;
  u32 msk = (g < 2) ? 0xFFFFFFFFu : 0u;
  union { u32 w[4]; bf16x8 v; } pa;
  pa.w[0] = msk & (u32)__builtin_amdgcn_ds_bpermute(a0, (int)w0);
  pa.w[1] = msk & (u32)__builtin_amdgcn_ds_bpermute(a0, (int)w1);
  pa.w[2] = msk & (u32)__builtin_amdgcn_ds_bpermute(a1, (int)w0);
  pa.w[3] = msk & (u32)__builtin_amdgcn_ds_bpermute(a1, (int)w1);

  const u16* vb = vt + ((size_t)(seq * 12 + h) * 64) * TSPAD;
  const f32x4 vz = {0.f, 0.f, 0.f, 0.f};
  f32x4 oc[4];
  #pragma unroll
  for (int dt = 0; dt < 4; ++dt){
    bf16x8 bv = *(const bf16x8*)(vb + (size_t)(dt * 16 + r16) * TSPAD + g * 8);
    oc[dt] = __builtin_amdgcn_mfma_f32_16x16x32_bf16(pa.v, bv, vz, 0, 0, 0);
  }
  #pragma unroll
  for (int rr = 0; rr < 4; ++rr){
    int qr = g * 4 + rr;
    if (qr < TS){
      size_t ob = (size_t)(seq * TS + qr) * 768 + h * 64 + r16;
      #pragma unroll
      for (int dt = 0; dt < 4; ++dt)
        o[ob + dt * 16] = f2bf(oc[dt][rr]);
    }
  }
}

// ---------------- spatial attention: 1 wave per (seq,head,16-row q-chunk) --------------
__global__ __launch_bounds__(64)
void sattn_k(const u16* __restrict__ qs, const u16* __restrict__ ks,
             const u16* __restrict__ vt, u16* __restrict__ o){
  __shared__ u16 Pl[16 * 224];
  const int lane = threadIdx.x & 63;
  const int g = lane >> 4, r16 = lane & 15;
  int bid = blockIdx.x;
  int chunk = bid % 13; int sh = bid / 13;
  int h = sh % 12, s = sh / 12;
  const float sc_l2e = 0.125f * 1.44269504089f;

  #pragma unroll
  for (int i = 0; i < 4; i++) Pl[(i * 4 + g) * 224 + 208 + r16] = 0;

  int q0 = chunk * 16;
  int qrow = q0 + r16; if (qrow > 196) qrow = 196;
  const u16* qp = qs + ((size_t)(s * 197 + qrow)) * 768 + h * 64 + g * 8;
  bf16x8 aq0 = *(const bf16x8*)qp;
  bf16x8 aq1 = *(const bf16x8*)(qp + 32);

  f32x4 scv[13];
  #pragma unroll
  for (int jt = 0; jt < 13; ++jt){
    int krow = jt * 16 + r16; if (krow > 196) krow = 196;
    const u16* kp = ks + ((size_t)(s * 197 + krow)) * 768 + h * 64 + g * 8;
    bf16x8 b0 = *(const bf16x8*)kp;
    bf16x8 b1 = *(const bf16x8*)(kp + 32);
    f32x4 z = {0.f, 0.f, 0.f, 0.f};
    z = __builtin_amdgcn_mfma_f32_16x16x32_bf16(aq0, b0, z, 0, 0, 0);
    z = __builtin_amdgcn_mfma_f32_16x16x32_bf16(aq1, b1, z, 0, 0, 0);
    scv[jt] = z;
  }
  float mrow[4] = {-3e38f, -3e38f, -3e38f, -3e38f};
  #pragma unroll
  for (int jt = 0; jt < 13; ++jt)
    #pragma unroll
    for (int r = 0; r < 4; r++){
      float x = (jt * 16 + r16 < 197) ? scv[jt][r] : -3e38f;
      scv[jt][r] = x;
      mrow[r] = fmaxf(mrow[r], x);
    }
  #pragma unroll
  for (int off = 1; off < 16; off <<= 1)
    #pragma unroll
    for (int r = 0; r < 4; r++) mrow[r] = fmaxf(mrow[r], __shfl_xor(mrow[r], off));
  float srow[4] = {0.f, 0.f, 0.f, 0.f};
  #pragma unroll
  for (int jt = 0; jt < 13; ++jt)
    #pragma unroll
    for (int r = 0; r < 4; r++){
      float e = exp2f((scv[jt][r] - mrow[r]) * sc_l2e);
      scv[jt][r] = e;
      srow[r] += e;
    }
  #pragma unroll
  for (int off = 1; off < 16; off <<= 1)
    #pragma unroll
    for (int r = 0; r < 4; r++) srow[r] += __shfl_xor(srow[r], off);
  float inv[4];
  #pragma unroll
  for (int r = 0; r < 4; r++) inv[r] = 1.f / srow[r];
  #pragma unroll
  for (int jt = 0; jt < 13; ++jt)
    #pragma unroll
    for (int r = 0; r < 4; r++)
      Pl[(g * 4 + r) * 224 + jt * 16 + r16] = f2bf(scv[jt][r] * inv[r]);
  __syncthreads();
  const u16* vbase = vt + ((size_t)(s * 12 + h) * 64) * 224;
  f32x4 oc[4]; const f32x4 vz = {0.f,0.f,0.f,0.f};
  #pragma unroll
  for (int dt = 0; dt < 4; dt++) oc[dt] = vz;
  #pragma unroll
  for (int ks2 = 0; ks2 < 7; ++ks2){
    bf16x8 ap = *(const bf16x8*)(Pl + r16 * 224 + ks2 * 32 + g * 8);
    #pragma unroll
    for (int dt = 0; dt < 4; ++dt){
      const u16* vp = vbase + ((size_t)(dt * 16 + r16)) * 224 + ks2 * 32 + g * 8;
      bf16x8 bv = *(const bf16x8*)vp;
      oc[dt] = __builtin_amdgcn_mfma_f32_16x16x32_bf16(ap, bv, oc[dt], 0, 0, 0);
    }
  }
  #pragma unroll
  for (int dt = 0; dt < 4; ++dt)
    #pragma unroll
    for (int r = 0; r < 4; r++){
      int qr2 = q0 + g * 4 + r;
      if (qr2 < 197)
        o[((size_t)(s * 197 + qr2)) * 768 + h * 64 + dt * 16 + r16] = f2bf(oc[dt][r]);
    }
}

// ---------------- cls row: xn[b,0] = x[b,0] + mean_t clsbuf[b*16+t] ----------------
__global__ __launch_bounds__(256)
void clsfin_k(const float* __restrict__ x, const float* __restrict__ cb, float* __restrict__ xn){
  int b = blockIdx.x;
  int c = blockIdx.y * 256 + threadIdx.x;
  float s = 0.f;
  #pragma unroll
  for (int t = 0; t < 16; t++) s += cb[((size_t)(b * 16 + t)) * 768 + c];
  xn[(size_t)b * 3137 * 768 + c] = x[(size_t)b * 3137 * 768 + c] + s * (1.f / 16.f);
}

// ======================================================================================
extern "C" void kernel_launch(void* const* d_in, const int* in_sizes, int n_in,
                              void* d_out, int out_size, void* d_ws, size_t ws_size,
                              hipStream_t stream){
  (void)in_sizes; (void)n_in; (void)out_size;
  const float* x    = (const float*)d_in[0];
  const float* ln1g = (const float*)d_in[1];
  const float* ln1b = (const float*)d_in[2];
  const float* tlng = (const float*)d_in[3];
  const float* tlnb = (const float*)d_in[4];
  const float* ln2g = (const float*)d_in[5];
  const float* ln2b = (const float*)d_in[6];
  const float* Ws   = (const float*)d_in[7];
  const float* bs   = (const float*)d_in[8];
  const float* Wt   = (const float*)d_in[9];
  const float* bt   = (const float*)d_in[10];
  const float* Wtp  = (const float*)d_in[11];
  const float* btp  = (const float*)d_in[12];
  const float* Wfc  = (const float*)d_in[13];
  const float* bfc  = (const float*)d_in[14];
  const float* W1   = (const float*)d_in[15];
  const float* b1   = (const float*)d_in[16];
  const float* W2   = (const float*)d_in[17];
  const float* b2   = (const float*)d_in[18];
  float* out = (float*)d_out;

  constexpr size_t MiB = 1048576;
  constexpr size_t C2  = 589824;
  constexpr size_t W_BYTES = (17 * C2 + 2 * 2359296) * 2;  // 29,491,200
  constexpr size_t NEED = W_BYTES + 143 * MiB;
  if (ws_size < NEED) return;

  char* wsb  = (char*)d_ws;
  u16*  wbuf = (u16*)wsb;
  u16*  W1T  = wbuf + 17 * C2;
  u16*  W2T  = W1T + (size_t)3072 * 768;
  char* A0   = wsb + W_BYTES;

  // slot map (MiB offsets in A0):
  //  [0,20)    ht | hs | osb | h2
  //  [20,58)   q+k slab (contiguous; spatial worst 36.94) ; a1 spans [20,93.5) at MLP time
  //  [58,86)   vt (temporal 27.6) | vts (spatial 22.0)
  //  [86,105)  o16 | xt2(bf16)
  //  [105,142) o8@105, o4@115 -> xn(f32) spans [105,141.8)
  //  [142,..)  clsb
  u16*  ht  = (u16*)(A0 + 0   * MiB);
  u16*  qk  = (u16*)(A0 + 20  * MiB);
  u16*  vtb = (u16*)(A0 + 58  * MiB);
  u16*  o16 = (u16*)(A0 + 86  * MiB);
  u16*  o8  = (u16*)(A0 + 105 * MiB);
  u16*  o4  = (u16*)(A0 + 115 * MiB);
  u16*  xt2 = (u16*)(A0 + 86  * MiB);
  float* xn = (float*)(A0 + 105 * MiB);
  float* clsb = (float*)(A0 + 142 * MiB);
  u16*  tp  = qk;
  u16*  hs  = ht;  u16* osb = ht; u16* h2 = ht;
  u16*  a1  = qk;

  // -- weights -> transposed bf16 (QKV triplets contiguous for fused GEMMs)
  twt17_k<<<dim3(24, 24, 17), 256, 0, stream>>>(Ws, Wt, Wtp, Wfc, wbuf);
  twt_k<<<dim3(96, 24), 256, 0, stream>>>(W1, W1T, 768, 3072);
  twt_k<<<dim3(24, 96), 256, 0, stream>>>(W2, W2T, 3072, 768);

  // -- temporal LN
  ln_k<0><<<3136, 256, 0, stream>>>(x, nullptr, tlng, tlnb, ht);

  // -- scale 16: fused QKV (N=2304; V -> transposed layout) + attn
  gemm_k<8><<<dim3(18, 98), 256, 0, stream>>>(ht, wbuf + 10*C2, bt + 6*768, qk, nullptr, vtb, 12544, 768, 768, 24, 1,1,0, 16,1,12544);
  tattn_k<16,24><<<2352, 256, 0, stream>>>(qk, qk + (size_t)12544*768, vtb, o16);

  // -- scale 8
  gemm_k<8><<<dim3(18, 49), 256, 0, stream>>>(ht, wbuf +  7*C2, bt + 3*768, qk, nullptr, vtb, 6272, 768, 768, 16, 8,16,8, 8,1,6272);
  tattn_k< 8,16><<<2352, 256, 0, stream>>>(qk, qk + (size_t)6272*768, vtb, o8);

  // -- scale 4
  gemm_k<8><<<dim3(18, 25), 256, 0, stream>>>(ht, wbuf +  4*C2, bt + 0*768, qk, nullptr, vtb, 3136, 768, 768, 16, 4,16,12, 4,1,3136);
  tattn_k< 4,16><<<2352, 256, 0, stream>>>(qk, qk + (size_t)3136*768, vtb, o4);

  // -- projection + blend chain; then tp, xt2
  gemm_k<1><<<dim3(6, 25), 256, 0, stream>>>(o4,  wbuf + 13*C2, btp + 0,    o8,  nullptr, nullptr, 3136, 768, 768, 768, 1,1,0, 4,8,4);
  gemm_k<1><<<dim3(6, 49), 256, 0, stream>>>(o8,  wbuf + 14*C2, btp + 768,  o16, nullptr, nullptr, 6272, 768, 768, 768, 1,1,0, 8,16,8);
  gemm_k<0><<<dim3(6, 98), 256, 0, stream>>>(o16, wbuf + 15*C2, btp + 1536, tp,  nullptr, nullptr, 12544, 768, 768, 768, 1,1,0, 1,1,0);
  gemm_k<2><<<dim3(6, 98), 256, 0, stream>>>(tp,  wbuf + 16*C2, bfc,        xt2, x, nullptr,       12544, 768, 768, 768, 1,1,0, 1,1,0);

  // -- spatial LN + fused QKV
  ln_k<1><<<3152, 256, 0, stream>>>(x, xt2, ln1g, ln1b, hs);
  fillz_k<<<2048, 256, 0, stream>>>((u32*)vtb, 5505024);
  gemm_k<9><<<dim3(18, 99), 256, 0, stream>>>(hs, wbuf + 0*C2, bs + 0, qk, nullptr, vtb, 12608, 768, 768, 224, 1,1,0, 1,1,12608);

  // -- spatial attention
  sattn_k<<<9984, 64, 0, stream>>>(qk, qk + (size_t)12608*768, vtb, osb);

  // -- spatial proj + residual scatter into xn, cls rows
  gemm_k<3><<<dim3(6, 99), 256, 0, stream>>>(osb, wbuf + 3*C2, bs + 2304, xn, xt2, clsb, 12608, 768, 768, 768, 1,1,0, 1,1,0);
  clsfin_k<<<dim3(4, 3), 256, 0, stream>>>(x, clsb, xn);

  // -- final LN + MLP
  ln_k<2><<<3137, 256, 0, stream>>>(xn, nullptr, ln2g, ln2b, h2);
  gemm_k<4><<<dim3(24, 99), 256, 0, stream>>>(h2, W1T, b1, a1,  nullptr, nullptr, 12548, 768, 768, 3072, 1,1,0, 1,1,0);
  gemm_k<5><<<dim3(6, 99), 256, 0, stream>>>(a1, W2T, b2, out, xn, nullptr,       12548, 3072, 3072, 768, 1,1,0, 1,1,0);
}

// Round 6
// 824.944 us; speedup vs baseline: 1.4791x; 1.1319x over previous
//
#include <hip/hip_runtime.h>

typedef unsigned short u16;
typedef unsigned int   u32;
typedef __attribute__((ext_vector_type(8))) __bf16 bf16x8;
typedef __attribute__((ext_vector_type(4))) float  f32x4;
typedef __attribute__((ext_vector_type(4))) u16    u16x4;

#define DEV __device__ __forceinline__

DEV float bf2f(u16 u){ union { u32 i; float f; } x; x.i = ((u32)u) << 16; return x.f; }
DEV u16 f2bf(float f){ union { float f; u32 i; } x; x.f = f;
  u32 r = x.i + 0x7fffu + ((x.i >> 16) & 1u); return (u16)(r >> 16); }

DEV void gload16(const void* g, void* l){
  __builtin_amdgcn_global_load_lds((const __attribute__((address_space(1))) void*)g,
                                   (__attribute__((address_space(3))) void*)l, 16, 0, 0);
}

// ---------------- weight transpose+convert: dst[n*R + k] = src[k*C + n] (bf16) ----------
__global__ __launch_bounds__(256)
void twt_k(const float* __restrict__ src, u16* __restrict__ dst, int R, int C){
  __shared__ float t[32][33];
  int tx = threadIdx.x & 31, ty = threadIdx.x >> 5;
  int c0 = blockIdx.x * 32, r0 = blockIdx.y * 32;
  #pragma unroll
  for (int i = 0; i < 4; i++)
    t[ty + i*8][tx] = src[(size_t)(r0 + ty + i*8) * C + c0 + tx];
  __syncthreads();
  #pragma unroll
  for (int i = 0; i < 4; i++)
    dst[(size_t)(c0 + ty + i*8) * R + r0 + tx] = f2bf(t[tx][ty + i*8]);
}

// 17 square 768x768 mats in one launch (z = matrix id)
__global__ __launch_bounds__(256)
void twt17_k(const float* __restrict__ Ws, const float* __restrict__ Wt,
             const float* __restrict__ Wtp, const float* __restrict__ Wfc,
             u16* __restrict__ dst){
  __shared__ float t[32][33];
  int z = blockIdx.z;
  const float* src = (z < 4)  ? Ws  + (size_t)z * 589824
                   : (z < 13) ? Wt  + (size_t)(z-4) * 589824
                   : (z < 16) ? Wtp + (size_t)(z-13) * 589824
                   : Wfc;
  u16* d = dst + (size_t)z * 589824;
  int tx = threadIdx.x & 31, ty = threadIdx.x >> 5;
  int c0 = blockIdx.x * 32, r0 = blockIdx.y * 32;
  #pragma unroll
  for (int i = 0; i < 4; i++)
    t[ty + i*8][tx] = src[(size_t)(r0 + ty + i*8) * 768 + c0 + tx];
  __syncthreads();
  #pragma unroll
  for (int i = 0; i < 4; i++)
    d[(size_t)(c0 + ty + i*8) * 768 + r0 + tx] = f2bf(t[tx][ty + i*8]);
}

// ---------------- zero fill (u32 granularity) ----------------
__global__ void fillz_k(u32* __restrict__ p, long n){
  long i = (long)blockIdx.x * 256 + threadIdx.x;
  long stride = (long)gridDim.x * 256;
  for (; i < n; i += stride) p[i] = 0;
}

// ---------------- LayerNorm over C=768, one wave per token, out bf16 -------------
template<int GM>
__global__ __launch_bounds__(256)
void ln_k(const float* __restrict__ f0, const u16* __restrict__ b0_,
          const float* __restrict__ gw, const float* __restrict__ bw,
          u16* __restrict__ out){
  int lane = threadIdx.x & 63;
  int tok = blockIdx.x * 4 + (threadIdx.x >> 6);
  const float* fsrc = nullptr; const u16* bsrc = nullptr;
  bool bfp = false;
  if constexpr (GM == 0){
    int b = tok / 3136, m = tok - b * 3136;
    fsrc = f0 + ((size_t)b * 3137 + 1 + m) * 768;
  } else if constexpr (GM == 1){
    int s = tok / 197, j = tok - s * 197;
    int b = s >> 4, t = s & 15;
    if (j == 0) fsrc = f0 + (size_t)b * 3137 * 768;
    else { bfp = true; bsrc = b0_ + ((size_t)b * 3136 + (size_t)(j - 1) * 16 + t) * 768; }
  } else {
    fsrc = f0 + (size_t)tok * 768;
  }
  float v[12]; float s1 = 0.f, s2 = 0.f;
  if (!bfp){
    #pragma unroll
    for (int i = 0; i < 3; i++){
      float4 f = *(const float4*)(fsrc + i * 256 + lane * 4);
      v[i*4+0] = f.x; v[i*4+1] = f.y; v[i*4+2] = f.z; v[i*4+3] = f.w;
    }
  } else {
    #pragma unroll
    for (int i = 0; i < 3; i++){
      u16x4 p = *(const u16x4*)(bsrc + i * 256 + lane * 4);
      v[i*4+0] = bf2f(p[0]); v[i*4+1] = bf2f(p[1]); v[i*4+2] = bf2f(p[2]); v[i*4+3] = bf2f(p[3]);
    }
  }
  #pragma unroll
  for (int i = 0; i < 12; i++){ s1 += v[i]; s2 += v[i]*v[i]; }
  #pragma unroll
  for (int off = 32; off; off >>= 1){ s1 += __shfl_xor(s1, off); s2 += __shfl_xor(s2, off); }
  float mu = s1 * (1.f/768.f);
  float rstd = rsqrtf(s2 * (1.f/768.f) - mu*mu + 1e-5f);
  #pragma unroll
  for (int i = 0; i < 3; i++){
    int c = i * 256 + lane * 4;
    float4 g4 = *(const float4*)(gw + c);
    float4 b4 = *(const float4*)(bw + c);
    u16x4 pk;
    pk[0] = f2bf((v[i*4+0]-mu)*rstd*g4.x + b4.x);
    pk[1] = f2bf((v[i*4+1]-mu)*rstd*g4.y + b4.y);
    pk[2] = f2bf((v[i*4+2]-mu)*rstd*g4.z + b4.z);
    pk[3] = f2bf((v[i*4+3]-mu)*rstd*g4.w + b4.w);
    *(u16x4*)(out + (size_t)tok * 768 + c) = pk;
  }
}

// ---------------- GEMM: C = Amap @ Bw^T(+bias), 128x128 tile, bf16 MFMA ----------------
// R4-verified inner loop: double-buffered LDS, prefetch issued BEFORE compute, single
// __syncthreads per K-step. 1-D grid + m204 bijective XCD-chunked remap (x-fastest ->
// blocks in one XCD chunk share the A panel; cuts A L2 re-fetch across XCDs).
// A row map r -> (r/aTs)*aTf + at0 + r%aTs ; Bw: (N x K) bf16 row-major
// MODE 0: bf16 out[R*ldo+Cg]
// MODE 1: blend: Ro=(R/oTs)*oTf+ot0+R%oTs; out[Ro*ldo+Cg] = bf16(0.5*val+0.5*old)
// MODE 2: bf16 out[R*768+Cg] = val + aux1(x,f32)[((R/3136)*3137+1+R%3136)*768+Cg]
// MODE 3: spatial scatter (+cls buffer)  MODE 4: gelu bf16 (tanh form)
// MODE 5: f32 out = val + aux1(f32)
// MODE 8: fused temporal QKV: mat=Cg/768; mat<2 -> out[mat*ot0*768 + R*768 + c0];
//         mat==2 -> aux2 vT: [((R/oTs)*12+(c0>>6))*64+(c0&63)]*ldo + R%oTs
// MODE 9: fused spatial QKV: mat<2 -> out[mat*ot0*768 + R*768 + c0];
//         mat==2 -> aux2 vT: [((R/197)*12+(c0>>6))*64+(c0&63)]*224 + R%197
template<int MODE>
__global__ __launch_bounds__(256)
void gemm_k(const u16* __restrict__ A, const u16* __restrict__ Bw,
            const float* __restrict__ bias, void* out,
            const void* aux1, void* aux2, int nbx,
            int M, int K, int lda, int ldo,
            int aTs, int aTf, int at0, int oTs, int oTf, int ot0){
  __shared__ u16 lA[2][128 * 32];
  __shared__ u16 lB[2][128 * 32];
  const int tid = threadIdx.x;

  // m204 bijective XCD-chunked remap (nwg need not be %8)
  const int nwg = (int)gridDim.x;
  {
  }
  int id = (int)blockIdx.x;
  int qc = nwg >> 3, rc = nwg & 7;
  int xcd = id & 7, off = id >> 3;
  int wg = (xcd < rc ? xcd * (qc + 1) : rc * (qc + 1) + (xcd - rc) * qc) + off;
  int by = wg / nbx;
  int bx = wg - by * nbx;
  const int m0 = by * 128, n0 = bx * 128;

  const int lane = tid & 63, widx = tid >> 6;
  const int g = lane >> 4, r16 = lane & 15;
  const int wm = widx >> 1, wn = widx & 1;

  const u16* ga[2]; const u16* gb[2]; int lo[2];
  #pragma unroll
  for (int rnd = 0; rnd < 2; ++rnd){
    int li = tid + rnd * 256;
    int ar = m0 + (li >> 2); if (ar > M - 1) ar = M - 1;
    ar = (ar / aTs) * aTf + at0 + (ar % aTs);
    ga[rnd] = A + (size_t)ar * lda + (li & 3) * 8;
    gb[rnd] = Bw + (size_t)(n0 + (li >> 2)) * K + (li & 3) * 8;
    lo[rnd] = li * 8;
  }

  const f32x4 vz = {0.f, 0.f, 0.f, 0.f};
  f32x4 acc[4][4];
  #pragma unroll
  for (int i = 0; i < 4; i++)
    #pragma unroll
    for (int j = 0; j < 4; j++) acc[i][j] = vz;

  const int kiter = K >> 5;

  // prologue: stage k-tile 0 into buf 0
  gload16(ga[0], &lA[0][lo[0]]);
  gload16(ga[1], &lA[0][lo[1]]);
  gload16(gb[0], &lB[0][lo[0]]);
  gload16(gb[1], &lB[0][lo[1]]);
  __syncthreads();

  for (int kt = 0; kt < kiter; ++kt){
    const int cur = kt & 1;
    if (kt + 1 < kiter){           // issue next-tile loads BEFORE compute
      const int nxt = cur ^ 1;
      gload16(ga[0] + (kt + 1) * 32, &lA[nxt][lo[0]]);
      gload16(ga[1] + (kt + 1) * 32, &lA[nxt][lo[1]]);
      gload16(gb[0] + (kt + 1) * 32, &lB[nxt][lo[0]]);
      gload16(gb[1] + (kt + 1) * 32, &lB[nxt][lo[1]]);
    }
    bf16x8 af[4], bfr[4];
    #pragma unroll
    for (int i = 0; i < 4; i++){
      af[i]  = *(const bf16x8*)(&lA[cur][(wm * 64 + i * 16 + r16) * 32 + g * 8]);
      bfr[i] = *(const bf16x8*)(&lB[cur][(wn * 64 + i * 16 + r16) * 32 + g * 8]);
    }
    #pragma unroll
    for (int i = 0; i < 4; i++)
      #pragma unroll
      for (int j = 0; j < 4; j++)
        acc[i][j] = __builtin_amdgcn_mfma_f32_16x16x32_bf16(af[i], bfr[j], acc[i][j], 0, 0, 0);
    __syncthreads();               // implicit vmcnt(0)+lgkmcnt(0) after compute
  }

  #pragma unroll
  for (int i = 0; i < 4; i++){
    const int lrow = wm * 64 + i * 16 + g * 4;
    #pragma unroll
    for (int j = 0; j < 4; j++){
      const int Cg = n0 + wn * 64 + j * 16 + r16;
      const float b0 = bias[Cg];
      #pragma unroll
      for (int r = 0; r < 4; r++){
        const int R = m0 + lrow + r;
        if (R >= M) continue;
        float val = acc[i][j][r] + b0;
        if constexpr (MODE == 0){
          ((u16*)out)[(size_t)R * ldo + Cg] = f2bf(val);
        } else if constexpr (MODE == 1){
          int Ro = (R / oTs) * oTf + ot0 + (R % oTs);
          u16* po = (u16*)out + (size_t)Ro * ldo + Cg;
          *po = f2bf(0.5f * val + 0.5f * bf2f(*po));
        } else if constexpr (MODE == 2){
          int b_ = R / 3136, m_ = R - b_ * 3136;
          ((u16*)out)[(size_t)R * 768 + Cg] =
              f2bf(val + ((const float*)aux1)[((size_t)b_ * 3137 + 1 + m_) * 768 + Cg]);
        } else if constexpr (MODE == 3){
          int s_ = R / 197, j_ = R - s_ * 197;
          if (j_ == 0){
            ((float*)aux2)[(size_t)s_ * 768 + Cg] = val;
          } else {
            int b_ = s_ >> 4, t_ = s_ & 15, m_ = (j_ - 1) * 16 + t_;
            ((float*)out)[((size_t)b_ * 3137 + 1 + m_) * 768 + Cg] =
                val + bf2f(((const u16*)aux1)[((size_t)b_ * 3136 + m_) * 768 + Cg]);
          }
        } else if constexpr (MODE == 4){
          float c = val * (0.7978845608f + 0.0356774081f * val * val);
          float e2 = __expf(2.f * fabsf(c));
          float th = __builtin_copysignf(1.f - 2.f / (e2 + 1.f), c);
          ((u16*)out)[(size_t)R * ldo + Cg] = f2bf(0.5f * val * (1.f + th));
        } else if constexpr (MODE == 5){
          ((float*)out)[(size_t)R * 768 + Cg] = val + ((const float*)aux1)[(size_t)R * 768 + Cg];
        } else if constexpr (MODE == 8){
          int mat = Cg / 768, c0 = Cg - mat * 768;
          if (mat < 2){
            ((u16*)out)[(size_t)mat * ot0 * 768 + (size_t)R * 768 + c0] = f2bf(val);
          } else {
            int seq_ = R / oTs, t_ = R - seq_ * oTs;
            ((u16*)aux2)[((size_t)(seq_ * 12 + (c0 >> 6)) * 64 + (c0 & 63)) * ldo + t_] = f2bf(val);
          }
        } else if constexpr (MODE == 9){
          int mat = Cg / 768, c0 = Cg - mat * 768;
          if (mat < 2){
            ((u16*)out)[(size_t)mat * ot0 * 768 + (size_t)R * 768 + c0] = f2bf(val);
          } else {
            int s_ = R / 197, j_ = R - s_ * 197;
            ((u16*)aux2)[(((size_t)(s_ * 12 + (c0 >> 6)) * 64 + (c0 & 63)) * 224) + j_] = f2bf(val);
          }
        }
      }
    }
  }
}

// ---------------- temporal attention via MFMA: one wave per (seq,head) ----------------
template<int TS, int TSPAD>
__global__ __launch_bounds__(256)
void tattn_k(const u16* __restrict__ q, const u16* __restrict__ k,
             const u16* __restrict__ vt, u16* __restrict__ o){
  const int lane = threadIdx.x & 63;
  const int g = lane >> 4, r16 = lane & 15;
  int p = blockIdx.x * 4 + (threadIdx.x >> 6);
  int seq = p / 12, h = p - seq * 12;

  int trow = (TS < 16 && r16 >= TS) ? TS - 1 : r16;
  size_t qko = (size_t)(seq * TS + trow) * 768 + h * 64 + g * 8;
  bf16x8 ak0 = *(const bf16x8*)(k + qko);
  bf16x8 ak1 = *(const bf16x8*)(k + qko + 32);
  bf16x8 bq0 = *(const bf16x8*)(q + qko);
  bf16x8 bq1 = *(const bf16x8*)(q + qko + 32);

  f32x4 s = {0.f, 0.f, 0.f, 0.f};
  s = __builtin_amdgcn_mfma_f32_16x16x32_bf16(ak0, bq0, s, 0, 0, 0);
  s = __builtin_amdgcn_mfma_f32_16x16x32_bf16(ak1, bq1, s, 0, 0, 0);

  const float C = 0.125f * 1.44269504089f;
  float pv[4]; float mx = -3e38f;
  #pragma unroll
  for (int r = 0; r < 4; r++){
    float x = (g * 4 + r < TS) ? s[r] : -3e38f;
    pv[r] = x; mx = fmaxf(mx, x);
  }
  mx = fmaxf(mx, __shfl_xor(mx, 16));
  mx = fmaxf(mx, __shfl_xor(mx, 32));
  float sum = 0.f;
  #pragma unroll
  for (int r = 0; r < 4; r++){ pv[r] = exp2f((pv[r] - mx) * C); sum += pv[r]; }
  sum += __shfl_xor(sum, 16);
  sum += __shfl_xor(sum, 32);
  float inv = 1.f / sum;
  #pragma unroll
  for (int r = 0; r < 4; r++) pv[r] *= inv;

  u32 w0 = (u32)f2bf(pv[0]) | ((u32)f2bf(pv[1]) << 16);
  u32 w1 = (u32)f2bf(pv[2]) | ((u32)f2bf(pv[3]) << 16);
  int a0 = ((g * 2) * 16 + r16) * 4;
  int a1 = ((g * 2 + 1) * 16 + r16) * 4;
  u32 msk = (g < 2) ? 0xFFFFFFFFu : 0u;
  union { u32 w[4]; bf16x8 v; } pa;
  pa.w[0] = msk & (u32)__builtin_amdgcn_ds_bpermute(a0, (int)w0);
  pa.w[1] = msk & (u32)__builtin_amdgcn_ds_bpermute(a0, (int)w1);
  pa.w[2] = msk & (u32)__builtin_amdgcn_ds_bpermute(a1, (int)w0);
  pa.w[3] = msk & (u32)__builtin_amdgcn_ds_bpermute(a1, (int)w1);

  const u16* vb = vt + ((size_t)(seq * 12 + h) * 64) * TSPAD;
  const f32x4 vz = {0.f, 0.f, 0.f, 0.f};
  f32x4 oc[4];
  #pragma unroll
  for (int dt = 0; dt < 4; ++dt){
    bf16x8 bv = *(const bf16x8*)(vb + (size_t)(dt * 16 + r16) * TSPAD + g * 8);
    oc[dt] = __builtin_amdgcn_mfma_f32_16x16x32_bf16(pa.v, bv, vz, 0, 0, 0);
  }
  #pragma unroll
  for (int rr = 0; rr < 4; ++rr){
    int qr = g * 4 + rr;
    if (qr < TS){
      size_t ob = (size_t)(seq * TS + qr) * 768 + h * 64 + r16;
      #pragma unroll
      for (int dt = 0; dt < 4; ++dt)
        o[ob + dt * 16] = f2bf(oc[dt][rr]);
    }
  }
}

// ---------------- spatial attention: 1 wave per (seq,head,16-row q-chunk) --------------
__global__ __launch_bounds__(64)
void sattn_k(const u16* __restrict__ qs, const u16* __restrict__ ks,
             const u16* __restrict__ vt, u16* __restrict__ o){
  __shared__ u16 Pl[16 * 224];
  const int lane = threadIdx.x & 63;
  const int g = lane >> 4, r16 = lane & 15;
  int bid = blockIdx.x;
  int chunk = bid % 13; int sh = bid / 13;
  int h = sh % 12, s = sh / 12;
  const float sc_l2e = 0.125f * 1.44269504089f;

  #pragma unroll
  for (int i = 0; i < 4; i++) Pl[(i * 4 + g) * 224 + 208 + r16] = 0;

  int q0 = chunk * 16;
  int qrow = q0 + r16; if (qrow > 196) qrow = 196;
  const u16* qp = qs + ((size_t)(s * 197 + qrow)) * 768 + h * 64 + g * 8;
  bf16x8 aq0 = *(const bf16x8*)qp;
  bf16x8 aq1 = *(const bf16x8*)(qp + 32);

  f32x4 scv[13];
  #pragma unroll
  for (int jt = 0; jt < 13; ++jt){
    int krow = jt * 16 + r16; if (krow > 196) krow = 196;
    const u16* kp = ks + ((size_t)(s * 197 + krow)) * 768 + h * 64 + g * 8;
    bf16x8 b0 = *(const bf16x8*)kp;
    bf16x8 b1 = *(const bf16x8*)(kp + 32);
    f32x4 z = {0.f, 0.f, 0.f, 0.f};
    z = __builtin_amdgcn_mfma_f32_16x16x32_bf16(aq0, b0, z, 0, 0, 0);
    z = __builtin_amdgcn_mfma_f32_16x16x32_bf16(aq1, b1, z, 0, 0, 0);
    scv[jt] = z;
  }
  float mrow[4] = {-3e38f, -3e38f, -3e38f, -3e38f};
  #pragma unroll
  for (int jt = 0; jt < 13; ++jt)
    #pragma unroll
    for (int r = 0; r < 4; r++){
      float x = (jt * 16 + r16 < 197) ? scv[jt][r] : -3e38f;
      scv[jt][r] = x;
      mrow[r] = fmaxf(mrow[r], x);
    }
  #pragma unroll
  for (int off = 1; off < 16; off <<= 1)
    #pragma unroll
    for (int r = 0; r < 4; r++) mrow[r] = fmaxf(mrow[r], __shfl_xor(mrow[r], off));
  float srow[4] = {0.f, 0.f, 0.f, 0.f};
  #pragma unroll
  for (int jt = 0; jt < 13; ++jt)
    #pragma unroll
    for (int r = 0; r < 4; r++){
      float e = exp2f((scv[jt][r] - mrow[r]) * sc_l2e);
      scv[jt][r] = e;
      srow[r] += e;
    }
  #pragma unroll
  for (int off = 1; off < 16; off <<= 1)
    #pragma unroll
    for (int r = 0; r < 4; r++) srow[r] += __shfl_xor(srow[r], off);
  float inv[4];
  #pragma unroll
  for (int r = 0; r < 4; r++) inv[r] = 1.f / srow[r];
  #pragma unroll
  for (int jt = 0; jt < 13; ++jt)
    #pragma unroll
    for (int r = 0; r < 4; r++)
      Pl[(g * 4 + r) * 224 + jt * 16 + r16] = f2bf(scv[jt][r] * inv[r]);
  __syncthreads();
  const u16* vbase = vt + ((size_t)(s * 12 + h) * 64) * 224;
  f32x4 oc[4]; const f32x4 vz = {0.f,0.f,0.f,0.f};
  #pragma unroll
  for (int dt = 0; dt < 4; dt++) oc[dt] = vz;
  #pragma unroll
  for (int ks2 = 0; ks2 < 7; ++ks2){
    bf16x8 ap = *(const bf16x8*)(Pl + r16 * 224 + ks2 * 32 + g * 8);
    #pragma unroll
    for (int dt = 0; dt < 4; ++dt){
      const u16* vp = vbase + ((size_t)(dt * 16 + r16)) * 224 + ks2 * 32 + g * 8;
      bf16x8 bv = *(const bf16x8*)vp;
      oc[dt] = __builtin_amdgcn_mfma_f32_16x16x32_bf16(ap, bv, oc[dt], 0, 0, 0);
    }
  }
  #pragma unroll
  for (int dt = 0; dt < 4; ++dt)
    #pragma unroll
    for (int r = 0; r < 4; r++){
      int qr2 = q0 + g * 4 + r;
      if (qr2 < 197)
        o[((size_t)(s * 197 + qr2)) * 768 + h * 64 + dt * 16 + r16] = f2bf(oc[dt][r]);
    }
}

// ---------------- cls row: xn[b,0] = x[b,0] + mean_t clsbuf[b*16+t] ----------------
__global__ __launch_bounds__(256)
void clsfin_k(const float* __restrict__ x, const float* __restrict__ cb, float* __restrict__ xn){
  int b = blockIdx.x;
  int c = blockIdx.y * 256 + threadIdx.x;
  float s = 0.f;
  #pragma unroll
  for (int t = 0; t < 16; t++) s += cb[((size_t)(b * 16 + t)) * 768 + c];
  xn[(size_t)b * 3137 * 768 + c] = x[(size_t)b * 3137 * 768 + c] + s * (1.f / 16.f);
}

// ======================================================================================
extern "C" void kernel_launch(void* const* d_in, const int* in_sizes, int n_in,
                              void* d_out, int out_size, void* d_ws, size_t ws_size,
                              hipStream_t stream){
  (void)in_sizes; (void)n_in; (void)out_size;
  const float* x    = (const float*)d_in[0];
  const float* ln1g = (const float*)d_in[1];
  const float* ln1b = (const float*)d_in[2];
  const float* tlng = (const float*)d_in[3];
  const float* tlnb = (const float*)d_in[4];
  const float* ln2g = (const float*)d_in[5];
  const float* ln2b = (const float*)d_in[6];
  const float* Ws   = (const float*)d_in[7];
  const float* bs   = (const float*)d_in[8];
  const float* Wt   = (const float*)d_in[9];
  const float* bt   = (const float*)d_in[10];
  const float* Wtp  = (const float*)d_in[11];
  const float* btp  = (const float*)d_in[12];
  const float* Wfc  = (const float*)d_in[13];
  const float* bfc  = (const float*)d_in[14];
  const float* W1   = (const float*)d_in[15];
  const float* b1   = (const float*)d_in[16];
  const float* W2   = (const float*)d_in[17];
  const float* b2   = (const float*)d_in[18];
  float* out = (float*)d_out;

  constexpr size_t MiB = 1048576;
  constexpr size_t C2  = 589824;
  constexpr size_t W_BYTES = (17 * C2 + 2 * 2359296) * 2;  // 29,491,200
  constexpr size_t NEED = W_BYTES + 143 * MiB;
  if (ws_size < NEED) return;

  char* wsb  = (char*)d_ws;
  u16*  wbuf = (u16*)wsb;
  u16*  W1T  = wbuf + 17 * C2;
  u16*  W2T  = W1T + (size_t)3072 * 768;
  char* A0   = wsb + W_BYTES;

  // slot map (MiB offsets in A0):
  //  [0,20)    ht | hs | osb | h2
  //  [20,58)   q+k slab ; a1 spans [20,93.5) at MLP time
  //  [58,86)   vt (temporal 27.6) | vts (spatial 22.0)
  //  [86,105)  o16 | xt2(bf16)
  //  [105,142) o8@105, o4@115 -> xn(f32)
  //  [142,..)  clsb
  u16*  ht  = (u16*)(A0 + 0   * MiB);
  u16*  qk  = (u16*)(A0 + 20  * MiB);
  u16*  vtb = (u16*)(A0 + 58  * MiB);
  u16*  o16 = (u16*)(A0 + 86  * MiB);
  u16*  o8  = (u16*)(A0 + 105 * MiB);
  u16*  o4  = (u16*)(A0 + 115 * MiB);
  u16*  xt2 = (u16*)(A0 + 86  * MiB);
  float* xn = (float*)(A0 + 105 * MiB);
  float* clsb = (float*)(A0 + 142 * MiB);
  u16*  tp  = qk;
  u16*  hs  = ht;  u16* osb = ht; u16* h2 = ht;
  u16*  a1  = qk;

  // -- weights -> transposed bf16 (QKV triplets contiguous for fused GEMMs)
  twt17_k<<<dim3(24, 24, 17), 256, 0, stream>>>(Ws, Wt, Wtp, Wfc, wbuf);
  twt_k<<<dim3(96, 24), 256, 0, stream>>>(W1, W1T, 768, 3072);
  twt_k<<<dim3(24, 96), 256, 0, stream>>>(W2, W2T, 3072, 768);

  // -- temporal LN
  ln_k<0><<<3136, 256, 0, stream>>>(x, nullptr, tlng, tlnb, ht);

  // -- scale 16: fused QKV (N=2304; V -> transposed layout) + attn
  gemm_k<8><<<18*98, 256, 0, stream>>>(ht, wbuf + 10*C2, bt + 6*768, qk, nullptr, vtb, 18, 12544, 768, 768, 24, 1,1,0, 16,1,12544);
  tattn_k<16,24><<<2352, 256, 0, stream>>>(qk, qk + (size_t)12544*768, vtb, o16);

  // -- scale 8
  gemm_k<8><<<18*49, 256, 0, stream>>>(ht, wbuf +  7*C2, bt + 3*768, qk, nullptr, vtb, 18, 6272, 768, 768, 16, 8,16,8, 8,1,6272);
  tattn_k< 8,16><<<2352, 256, 0, stream>>>(qk, qk + (size_t)6272*768, vtb, o8);

  // -- scale 4
  gemm_k<8><<<18*25, 256, 0, stream>>>(ht, wbuf +  4*C2, bt + 0*768, qk, nullptr, vtb, 18, 3136, 768, 768, 16, 4,16,12, 4,1,3136);
  tattn_k< 4,16><<<2352, 256, 0, stream>>>(qk, qk + (size_t)3136*768, vtb, o4);

  // -- projection + blend chain; then tp, xt2
  gemm_k<1><<<6*25, 256, 0, stream>>>(o4,  wbuf + 13*C2, btp + 0,    o8,  nullptr, nullptr, 6, 3136, 768, 768, 768, 1,1,0, 4,8,4);
  gemm_k<1><<<6*49, 256, 0, stream>>>(o8,  wbuf + 14*C2, btp + 768,  o16, nullptr, nullptr, 6, 6272, 768, 768, 768, 1,1,0, 8,16,8);
  gemm_k<0><<<6*98, 256, 0, stream>>>(o16, wbuf + 15*C2, btp + 1536, tp,  nullptr, nullptr, 6, 12544, 768, 768, 768, 1,1,0, 1,1,0);
  gemm_k<2><<<6*98, 256, 0, stream>>>(tp,  wbuf + 16*C2, bfc,        xt2, x, nullptr,       6, 12544, 768, 768, 768, 1,1,0, 1,1,0);

  // -- spatial LN + fused QKV
  ln_k<1><<<3152, 256, 0, stream>>>(x, xt2, ln1g, ln1b, hs);
  fillz_k<<<2048, 256, 0, stream>>>((u32*)vtb, 5505024);
  gemm_k<9><<<18*99, 256, 0, stream>>>(hs, wbuf + 0*C2, bs + 0, qk, nullptr, vtb, 18, 12608, 768, 768, 224, 1,1,0, 1,1,12608);

  // -- spatial attention
  sattn_k<<<9984, 64, 0, stream>>>(qk, qk + (size_t)12608*768, vtb, osb);

  // -- spatial proj + residual scatter into xn, cls rows
  gemm_k<3><<<6*99, 256, 0, stream>>>(osb, wbuf + 3*C2, bs + 2304, xn, xt2, clsb, 6, 12608, 768, 768, 768, 1,1,0, 1,1,0);
  clsfin_k<<<dim3(4, 3), 256, 0, stream>>>(x, clsb, xn);

  // -- final LN + MLP
  ln_k<2><<<3137, 256, 0, stream>>>(xn, nullptr, ln2g, ln2b, h2);
  gemm_k<4><<<24*99, 256, 0, stream>>>(h2, W1T, b1, a1,  nullptr, nullptr, 24, 12548, 768, 768, 3072, 1,1,0, 1,1,0);
  gemm_k<5><<<6*99, 256, 0, stream>>>(a1, W2T, b2, out, xn, nullptr,       6, 12548, 3072, 3072, 768, 1,1,0, 1,1,0);
}

// Round 7
// 782.867 us; speedup vs baseline: 1.5586x; 1.0537x over previous
//
#include <hip/hip_runtime.h>

typedef unsigned short u16;
typedef unsigned int   u32;
typedef __attribute__((ext_vector_type(8))) __bf16 bf16x8;
typedef __attribute__((ext_vector_type(4))) float  f32x4;
typedef __attribute__((ext_vector_type(4))) u16    u16x4;

#define DEV __device__ __forceinline__

DEV float bf2f(u16 u){ union { u32 i; float f; } x; x.i = ((u32)u) << 16; return x.f; }
DEV u16 f2bf(float f){ union { float f; u32 i; } x; x.f = f;
  u32 r = x.i + 0x7fffu + ((x.i >> 16) & 1u); return (u16)(r >> 16); }

DEV void gload16(const void* g, void* l){
  __builtin_amdgcn_global_load_lds((const __attribute__((address_space(1))) void*)g,
                                   (__attribute__((address_space(3))) void*)l, 16, 0, 0);
}

// ---------------- weight transpose+convert: dst[n*R + k] = src[k*C + n] (bf16) ----------
__global__ __launch_bounds__(256)
void twt_k(const float* __restrict__ src, u16* __restrict__ dst, int R, int C){
  __shared__ float t[32][33];
  int tx = threadIdx.x & 31, ty = threadIdx.x >> 5;
  int c0 = blockIdx.x * 32, r0 = blockIdx.y * 32;
  #pragma unroll
  for (int i = 0; i < 4; i++)
    t[ty + i*8][tx] = src[(size_t)(r0 + ty + i*8) * C + c0 + tx];
  __syncthreads();
  #pragma unroll
  for (int i = 0; i < 4; i++)
    dst[(size_t)(c0 + ty + i*8) * R + r0 + tx] = f2bf(t[tx][ty + i*8]);
}

// 17 square 768x768 mats in one launch (z = matrix id)
__global__ __launch_bounds__(256)
void twt17_k(const float* __restrict__ Ws, const float* __restrict__ Wt,
             const float* __restrict__ Wtp, const float* __restrict__ Wfc,
             u16* __restrict__ dst){
  __shared__ float t[32][33];
  int z = blockIdx.z;
  const float* src = (z < 4)  ? Ws  + (size_t)z * 589824
                   : (z < 13) ? Wt  + (size_t)(z-4) * 589824
                   : (z < 16) ? Wtp + (size_t)(z-13) * 589824
                   : Wfc;
  u16* d = dst + (size_t)z * 589824;
  int tx = threadIdx.x & 31, ty = threadIdx.x >> 5;
  int c0 = blockIdx.x * 32, r0 = blockIdx.y * 32;
  #pragma unroll
  for (int i = 0; i < 4; i++)
    t[ty + i*8][tx] = src[(size_t)(r0 + ty + i*8) * 768 + c0 + tx];
  __syncthreads();
  #pragma unroll
  for (int i = 0; i < 4; i++)
    d[(size_t)(c0 + ty + i*8) * 768 + r0 + tx] = f2bf(t[tx][ty + i*8]);
}

// ---------------- zero fill (u32 granularity) ----------------
__global__ void fillz_k(u32* __restrict__ p, long n){
  long i = (long)blockIdx.x * 256 + threadIdx.x;
  long stride = (long)gridDim.x * 256;
  for (; i < n; i += stride) p[i] = 0;
}

// ---------------- LayerNorm over C=768, one wave per token, out bf16 -------------
template<int GM>
__global__ __launch_bounds__(256)
void ln_k(const float* __restrict__ f0, const u16* __restrict__ b0_,
          const float* __restrict__ gw, const float* __restrict__ bw,
          u16* __restrict__ out){
  int lane = threadIdx.x & 63;
  int tok = blockIdx.x * 4 + (threadIdx.x >> 6);
  const float* fsrc = nullptr; const u16* bsrc = nullptr;
  bool bfp = false;
  if constexpr (GM == 0){
    int b = tok / 3136, m = tok - b * 3136;
    fsrc = f0 + ((size_t)b * 3137 + 1 + m) * 768;
  } else if constexpr (GM == 1){
    int s = tok / 197, j = tok - s * 197;
    int b = s >> 4, t = s & 15;
    if (j == 0) fsrc = f0 + (size_t)b * 3137 * 768;
    else { bfp = true; bsrc = b0_ + ((size_t)b * 3136 + (size_t)(j - 1) * 16 + t) * 768; }
  } else {
    fsrc = f0 + (size_t)tok * 768;
  }
  float v[12]; float s1 = 0.f, s2 = 0.f;
  if (!bfp){
    #pragma unroll
    for (int i = 0; i < 3; i++){
      float4 f = *(const float4*)(fsrc + i * 256 + lane * 4);
      v[i*4+0] = f.x; v[i*4+1] = f.y; v[i*4+2] = f.z; v[i*4+3] = f.w;
    }
  } else {
    #pragma unroll
    for (int i = 0; i < 3; i++){
      u16x4 p = *(const u16x4*)(bsrc + i * 256 + lane * 4);
      v[i*4+0] = bf2f(p[0]); v[i*4+1] = bf2f(p[1]); v[i*4+2] = bf2f(p[2]); v[i*4+3] = bf2f(p[3]);
    }
  }
  #pragma unroll
  for (int i = 0; i < 12; i++){ s1 += v[i]; s2 += v[i]*v[i]; }
  #pragma unroll
  for (int off = 32; off; off >>= 1){ s1 += __shfl_xor(s1, off); s2 += __shfl_xor(s2, off); }
  float mu = s1 * (1.f/768.f);
  float rstd = rsqrtf(s2 * (1.f/768.f) - mu*mu + 1e-5f);
  #pragma unroll
  for (int i = 0; i < 3; i++){
    int c = i * 256 + lane * 4;
    float4 g4 = *(const float4*)(gw + c);
    float4 b4 = *(const float4*)(bw + c);
    u16x4 pk;
    pk[0] = f2bf((v[i*4+0]-mu)*rstd*g4.x + b4.x);
    pk[1] = f2bf((v[i*4+1]-mu)*rstd*g4.y + b4.y);
    pk[2] = f2bf((v[i*4+2]-mu)*rstd*g4.z + b4.z);
    pk[3] = f2bf((v[i*4+3]-mu)*rstd*g4.w + b4.w);
    *(u16x4*)(out + (size_t)tok * 768 + c) = pk;
  }
}

// ---------------- GEMM: C = Amap @ Bw^T(+bias), 128x128 tile, bf16 MFMA ----------------
// R4-verified loop (dbuf, prefetch-before-compute, single __syncthreads) + XCD remap.
// NEW: __launch_bounds__(256,4) — unified regs must fit 128 (acc=64 AGPR + <=64 VGPR)
// to double occupancy (m69: waves/CU halve at 128 regs; R6 was 136 -> 8 waves/CU).
// A row map r -> (r/aTs)*aTf + at0 + r%aTs ; Bw: (N x K) bf16 row-major
// MODE 0: bf16 out[R*ldo+Cg]
// MODE 1: blend: Ro=(R/oTs)*oTf+ot0+R%oTs; out[Ro*ldo+Cg] = bf16(0.5*val+0.5*old)
// MODE 2: bf16 out[R*768+Cg] = val + aux1(x,f32)[((R/3136)*3137+1+R%3136)*768+Cg]
// MODE 3: spatial scatter (+cls buffer)  MODE 4: gelu bf16 (tanh form)
// MODE 5: f32 out = val + aux1(f32)
// MODE 8: fused temporal QKV  MODE 9: fused spatial QKV
template<int MODE>
__global__ __launch_bounds__(256, 4)
void gemm_k(const u16* __restrict__ A, const u16* __restrict__ Bw,
            const float* __restrict__ bias, void* out,
            const void* aux1, void* aux2, int nbx,
            int M, int K, int lda, int ldo,
            int aTs, int aTf, int at0, int oTs, int oTf, int ot0){
  __shared__ u16 lA[2][128 * 32];
  __shared__ u16 lB[2][128 * 32];
  const int tid = threadIdx.x;

  // m204 bijective XCD-chunked remap
  const int nwg = (int)gridDim.x;
  int id = (int)blockIdx.x;
  int qc = nwg >> 3, rc = nwg & 7;
  int xcd = id & 7, off = id >> 3;
  int wg = (xcd < rc ? xcd * (qc + 1) : rc * (qc + 1) + (xcd - rc) * qc) + off;
  int by = wg / nbx;
  int bx = wg - by * nbx;
  const int m0 = by * 128, n0 = bx * 128;

  const int lane = tid & 63, widx = tid >> 6;
  const int g = lane >> 4, r16 = lane & 15;
  const int wm = widx >> 1, wn = widx & 1;

  const u16* ga0; const u16* ga1; const u16* gb0; const u16* gb1;
  u32 lo0, lo1;
  {
    int li = tid;
    int ar = m0 + (li >> 2); if (ar > M - 1) ar = M - 1;
    ar = (ar / aTs) * aTf + at0 + (ar % aTs);
    ga0 = A + (size_t)ar * lda + (li & 3) * 8;
    gb0 = Bw + (size_t)(n0 + (li >> 2)) * K + (li & 3) * 8;
    lo0 = li * 8;
    li = tid + 256;
    ar = m0 + (li >> 2); if (ar > M - 1) ar = M - 1;
    ar = (ar / aTs) * aTf + at0 + (ar % aTs);
    ga1 = A + (size_t)ar * lda + (li & 3) * 8;
    gb1 = Bw + (size_t)(n0 + (li >> 2)) * K + (li & 3) * 8;
    lo1 = li * 8;
  }

  const f32x4 vz = {0.f, 0.f, 0.f, 0.f};
  f32x4 acc[4][4];
  #pragma unroll
  for (int i = 0; i < 4; i++)
    #pragma unroll
    for (int j = 0; j < 4; j++) acc[i][j] = vz;

  const int kiter = K >> 5;

  // prologue: stage k-tile 0 into buf 0, advance pointers in place
  gload16(ga0, &lA[0][lo0]);
  gload16(ga1, &lA[0][lo1]);
  gload16(gb0, &lB[0][lo0]);
  gload16(gb1, &lB[0][lo1]);
  ga0 += 32; ga1 += 32; gb0 += 32; gb1 += 32;
  __syncthreads();

  for (int kt = 0; kt < kiter; ++kt){
    const int cur = kt & 1;
    if (kt + 1 < kiter){           // issue next-tile loads BEFORE compute
      const int nxt = cur ^ 1;
      gload16(ga0, &lA[nxt][lo0]);
      gload16(ga1, &lA[nxt][lo1]);
      gload16(gb0, &lB[nxt][lo0]);
      gload16(gb1, &lB[nxt][lo1]);
      ga0 += 32; ga1 += 32; gb0 += 32; gb1 += 32;
    }
    bf16x8 af[4], bfr[4];
    #pragma unroll
    for (int i = 0; i < 4; i++){
      af[i]  = *(const bf16x8*)(&lA[cur][(wm * 64 + i * 16 + r16) * 32 + g * 8]);
      bfr[i] = *(const bf16x8*)(&lB[cur][(wn * 64 + i * 16 + r16) * 32 + g * 8]);
    }
    #pragma unroll
    for (int i = 0; i < 4; i++)
      #pragma unroll
      for (int j = 0; j < 4; j++)
        acc[i][j] = __builtin_amdgcn_mfma_f32_16x16x32_bf16(af[i], bfr[j], acc[i][j], 0, 0, 0);
    __syncthreads();               // implicit vmcnt(0)+lgkmcnt(0) after compute
  }

  #pragma unroll
  for (int i = 0; i < 4; i++){
    const int lrow = wm * 64 + i * 16 + g * 4;
    #pragma unroll
    for (int j = 0; j < 4; j++){
      const int Cg = n0 + wn * 64 + j * 16 + r16;
      const float b0 = bias[Cg];
      #pragma unroll
      for (int r = 0; r < 4; r++){
        const int R = m0 + lrow + r;
        if (R >= M) continue;
        float val = acc[i][j][r] + b0;
        if constexpr (MODE == 0){
          ((u16*)out)[(size_t)R * ldo + Cg] = f2bf(val);
        } else if constexpr (MODE == 1){
          int Ro = (R / oTs) * oTf + ot0 + (R % oTs);
          u16* po = (u16*)out + (size_t)Ro * ldo + Cg;
          *po = f2bf(0.5f * val + 0.5f * bf2f(*po));
        } else if constexpr (MODE == 2){
          int b_ = R / 3136, m_ = R - b_ * 3136;
          ((u16*)out)[(size_t)R * 768 + Cg] =
              f2bf(val + ((const float*)aux1)[((size_t)b_ * 3137 + 1 + m_) * 768 + Cg]);
        } else if constexpr (MODE == 3){
          int s_ = R / 197, j_ = R - s_ * 197;
          if (j_ == 0){
            ((float*)aux2)[(size_t)s_ * 768 + Cg] = val;
          } else {
            int b_ = s_ >> 4, t_ = s_ & 15, m_ = (j_ - 1) * 16 + t_;
            ((float*)out)[((size_t)b_ * 3137 + 1 + m_) * 768 + Cg] =
                val + bf2f(((const u16*)aux1)[((size_t)b_ * 3136 + m_) * 768 + Cg]);
          }
        } else if constexpr (MODE == 4){
          float c = val * (0.7978845608f + 0.0356774081f * val * val);
          float e2 = __expf(2.f * fabsf(c));
          float th = __builtin_copysignf(1.f - 2.f / (e2 + 1.f), c);
          ((u16*)out)[(size_t)R * ldo + Cg] = f2bf(0.5f * val * (1.f + th));
        } else if constexpr (MODE == 5){
          ((float*)out)[(size_t)R * 768 + Cg] = val + ((const float*)aux1)[(size_t)R * 768 + Cg];
        } else if constexpr (MODE == 8){
          int mat = Cg / 768, c0 = Cg - mat * 768;
          if (mat < 2){
            ((u16*)out)[(size_t)mat * ot0 * 768 + (size_t)R * 768 + c0] = f2bf(val);
          } else {
            int seq_ = R / oTs, t_ = R - seq_ * oTs;
            ((u16*)aux2)[((size_t)(seq_ * 12 + (c0 >> 6)) * 64 + (c0 & 63)) * ldo + t_] = f2bf(val);
          }
        } else if constexpr (MODE == 9){
          int mat = Cg / 768, c0 = Cg - mat * 768;
          if (mat < 2){
            ((u16*)out)[(size_t)mat * ot0 * 768 + (size_t)R * 768 + c0] = f2bf(val);
          } else {
            int s_ = R / 197, j_ = R - s_ * 197;
            ((u16*)aux2)[(((size_t)(s_ * 12 + (c0 >> 6)) * 64 + (c0 & 63)) * 224) + j_] = f2bf(val);
          }
        }
      }
    }
  }
}

// ---------------- temporal attention via MFMA: one wave per (seq,head) ----------------
template<int TS, int TSPAD>
__global__ __launch_bounds__(256)
void tattn_k(const u16* __restrict__ q, const u16* __restrict__ k,
             const u16* __restrict__ vt, u16* __restrict__ o){
  const int lane = threadIdx.x & 63;
  const int g = lane >> 4, r16 = lane & 15;
  int p = blockIdx.x * 4 + (threadIdx.x >> 6);
  int seq = p / 12, h = p - seq * 12;

  int trow = (TS < 16 && r16 >= TS) ? TS - 1 : r16;
  size_t qko = (size_t)(seq * TS + trow) * 768 + h * 64 + g * 8;
  bf16x8 ak0 = *(const bf16x8*)(k + qko);
  bf16x8 ak1 = *(const bf16x8*)(k + qko + 32);
  bf16x8 bq0 = *(const bf16x8*)(q + qko);
  bf16x8 bq1 = *(const bf16x8*)(q + qko + 32);

  f32x4 s = {0.f, 0.f, 0.f, 0.f};
  s = __builtin_amdgcn_mfma_f32_16x16x32_bf16(ak0, bq0, s, 0, 0, 0);
  s = __builtin_amdgcn_mfma_f32_16x16x32_bf16(ak1, bq1, s, 0, 0, 0);

  const float C = 0.125f * 1.44269504089f;
  float pv[4]; float mx = -3e38f;
  #pragma unroll
  for (int r = 0; r < 4; r++){
    float x = (g * 4 + r < TS) ? s[r] : -3e38f;
    pv[r] = x; mx = fmaxf(mx, x);
  }
  mx = fmaxf(mx, __shfl_xor(mx, 16));
  mx = fmaxf(mx, __shfl_xor(mx, 32));
  float sum = 0.f;
  #pragma unroll
  for (int r = 0; r < 4; r++){ pv[r] = exp2f((pv[r] - mx) * C); sum += pv[r]; }
  sum += __shfl_xor(sum, 16);
  sum += __shfl_xor(sum, 32);
  float inv = 1.f / sum;
  #pragma unroll
  for (int r = 0; r < 4; r++) pv[r] *= inv;

  u32 w0 = (u32)f2bf(pv[0]) | ((u32)f2bf(pv[1]) << 16);
  u32 w1 = (u32)f2bf(pv[2]) | ((u32)f2bf(pv[3]) << 16);
  int a0 = ((g * 2) * 16 + r16) * 4;
  int a1 = ((g * 2 + 1) * 16 + r16) * 4;
  u32 msk = (g < 2) ? 0xFFFFFFFFu : 0u;
  union { u32 w[4]; bf16x8 v; } pa;
  pa.w[0] = msk & (u32)__builtin_amdgcn_ds_bpermute(a0, (int)w0);
  pa.w[1] = msk & (u32)__builtin_amdgcn_ds_bpermute(a0, (int)w1);
  pa.w[2] = msk & (u32)__builtin_amdgcn_ds_bpermute(a1, (int)w0);
  pa.w[3] = msk & (u32)__builtin_amdgcn_ds_bpermute(a1, (int)w1);

  const u16* vb = vt + ((size_t)(seq * 12 + h) * 64) * TSPAD;
  const f32x4 vz = {0.f, 0.f, 0.f, 0.f};
  f32x4 oc[4];
  #pragma unroll
  for (int dt = 0; dt < 4; ++dt){
    bf16x8 bv = *(const bf16x8*)(vb + (size_t)(dt * 16 + r16) * TSPAD + g * 8);
    oc[dt] = __builtin_amdgcn_mfma_f32_16x16x32_bf16(pa.v, bv, vz, 0, 0, 0);
  }
  #pragma unroll
  for (int rr = 0; rr < 4; ++rr){
    int qr = g * 4 + rr;
    if (qr < TS){
      size_t ob = (size_t)(seq * TS + qr) * 768 + h * 64 + r16;
      #pragma unroll
      for (int dt = 0; dt < 4; ++dt)
        o[ob + dt * 16] = f2bf(oc[dt][rr]);
    }
  }
}

// ---------------- spatial attention: 1 wave per (seq,head,16-row q-chunk) --------------
__global__ __launch_bounds__(64)
void sattn_k(const u16* __restrict__ qs, const u16* __restrict__ ks,
             const u16* __restrict__ vt, u16* __restrict__ o){
  __shared__ u16 Pl[16 * 224];
  const int lane = threadIdx.x & 63;
  const int g = lane >> 4, r16 = lane & 15;
  int bid = blockIdx.x;
  int chunk = bid % 13; int sh = bid / 13;
  int h = sh % 12, s = sh / 12;
  const float sc_l2e = 0.125f * 1.44269504089f;

  #pragma unroll
  for (int i = 0; i < 4; i++) Pl[(i * 4 + g) * 224 + 208 + r16] = 0;

  int q0 = chunk * 16;
  int qrow = q0 + r16; if (qrow > 196) qrow = 196;
  const u16* qp = qs + ((size_t)(s * 197 + qrow)) * 768 + h * 64 + g * 8;
  bf16x8 aq0 = *(const bf16x8*)qp;
  bf16x8 aq1 = *(const bf16x8*)(qp + 32);

  f32x4 scv[13];
  #pragma unroll
  for (int jt = 0; jt < 13; ++jt){
    int krow = jt * 16 + r16; if (krow > 196) krow = 196;
    const u16* kp = ks + ((size_t)(s * 197 + krow)) * 768 + h * 64 + g * 8;
    bf16x8 b0 = *(const bf16x8*)kp;
    bf16x8 b1 = *(const bf16x8*)(kp + 32);
    f32x4 z = {0.f, 0.f, 0.f, 0.f};
    z = __builtin_amdgcn_mfma_f32_16x16x32_bf16(aq0, b0, z, 0, 0, 0);
    z = __builtin_amdgcn_mfma_f32_16x16x32_bf16(aq1, b1, z, 0, 0, 0);
    scv[jt] = z;
  }
  float mrow[4] = {-3e38f, -3e38f, -3e38f, -3e38f};
  #pragma unroll
  for (int jt = 0; jt < 13; ++jt)
    #pragma unroll
    for (int r = 0; r < 4; r++){
      float x = (jt * 16 + r16 < 197) ? scv[jt][r] : -3e38f;
      scv[jt][r] = x;
      mrow[r] = fmaxf(mrow[r], x);
    }
  #pragma unroll
  for (int off = 1; off < 16; off <<= 1)
    #pragma unroll
    for (int r = 0; r < 4; r++) mrow[r] = fmaxf(mrow[r], __shfl_xor(mrow[r], off));
  float srow[4] = {0.f, 0.f, 0.f, 0.f};
  #pragma unroll
  for (int jt = 0; jt < 13; ++jt)
    #pragma unroll
    for (int r = 0; r < 4; r++){
      float e = exp2f((scv[jt][r] - mrow[r]) * sc_l2e);
      scv[jt][r] = e;
      srow[r] += e;
    }
  #pragma unroll
  for (int off = 1; off < 16; off <<= 1)
    #pragma unroll
    for (int r = 0; r < 4; r++) srow[r] += __shfl_xor(srow[r], off);
  float inv[4];
  #pragma unroll
  for (int r = 0; r < 4; r++) inv[r] = 1.f / srow[r];
  #pragma unroll
  for (int jt = 0; jt < 13; ++jt)
    #pragma unroll
    for (int r = 0; r < 4; r++)
      Pl[(g * 4 + r) * 224 + jt * 16 + r16] = f2bf(scv[jt][r] * inv[r]);
  __syncthreads();
  const u16* vbase = vt + ((size_t)(s * 12 + h) * 64) * 224;
  f32x4 oc[4]; const f32x4 vz = {0.f,0.f,0.f,0.f};
  #pragma unroll
  for (int dt = 0; dt < 4; dt++) oc[dt] = vz;
  #pragma unroll
  for (int ks2 = 0; ks2 < 7; ++ks2){
    bf16x8 ap = *(const bf16x8*)(Pl + r16 * 224 + ks2 * 32 + g * 8);
    #pragma unroll
    for (int dt = 0; dt < 4; ++dt){
      const u16* vp = vbase + ((size_t)(dt * 16 + r16)) * 224 + ks2 * 32 + g * 8;
      bf16x8 bv = *(const bf16x8*)vp;
      oc[dt] = __builtin_amdgcn_mfma_f32_16x16x32_bf16(ap, bv, oc[dt], 0, 0, 0);
    }
  }
  #pragma unroll
  for (int dt = 0; dt < 4; ++dt)
    #pragma unroll
    for (int r = 0; r < 4; r++){
      int qr2 = q0 + g * 4 + r;
      if (qr2 < 197)
        o[((size_t)(s * 197 + qr2)) * 768 + h * 64 + dt * 16 + r16] = f2bf(oc[dt][r]);
    }
}

// ---------------- cls row: xn[b,0] = x[b,0] + mean_t clsbuf[b*16+t] ----------------
__global__ __launch_bounds__(256)
void clsfin_k(const float* __restrict__ x, const float* __restrict__ cb, float* __restrict__ xn){
  int b = blockIdx.x;
  int c = blockIdx.y * 256 + threadIdx.x;
  float s = 0.f;
  #pragma unroll
  for (int t = 0; t < 16; t++) s += cb[((size_t)(b * 16 + t)) * 768 + c];
  xn[(size_t)b * 3137 * 768 + c] = x[(size_t)b * 3137 * 768 + c] + s * (1.f / 16.f);
}

// ======================================================================================
extern "C" void kernel_launch(void* const* d_in, const int* in_sizes, int n_in,
                              void* d_out, int out_size, void* d_ws, size_t ws_size,
                              hipStream_t stream){
  (void)in_sizes; (void)n_in; (void)out_size;
  const float* x    = (const float*)d_in[0];
  const float* ln1g = (const float*)d_in[1];
  const float* ln1b = (const float*)d_in[2];
  const float* tlng = (const float*)d_in[3];
  const float* tlnb = (const float*)d_in[4];
  const float* ln2g = (const float*)d_in[5];
  const float* ln2b = (const float*)d_in[6];
  const float* Ws   = (const float*)d_in[7];
  const float* bs   = (const float*)d_in[8];
  const float* Wt   = (const float*)d_in[9];
  const float* bt   = (const float*)d_in[10];
  const float* Wtp  = (const float*)d_in[11];
  const float* btp  = (const float*)d_in[12];
  const float* Wfc  = (const float*)d_in[13];
  const float* bfc  = (const float*)d_in[14];
  const float* W1   = (const float*)d_in[15];
  const float* b1   = (const float*)d_in[16];
  const float* W2   = (const float*)d_in[17];
  const float* b2   = (const float*)d_in[18];
  float* out = (float*)d_out;

  constexpr size_t MiB = 1048576;
  constexpr size_t C2  = 589824;
  constexpr size_t W_BYTES = (17 * C2 + 2 * 2359296) * 2;  // 29,491,200
  constexpr size_t NEED = W_BYTES + 143 * MiB;
  if (ws_size < NEED) return;

  char* wsb  = (char*)d_ws;
  u16*  wbuf = (u16*)wsb;
  u16*  W1T  = wbuf + 17 * C2;
  u16*  W2T  = W1T + (size_t)3072 * 768;
  char* A0   = wsb + W_BYTES;

  u16*  ht  = (u16*)(A0 + 0   * MiB);
  u16*  qk  = (u16*)(A0 + 20  * MiB);
  u16*  vtb = (u16*)(A0 + 58  * MiB);
  u16*  o16 = (u16*)(A0 + 86  * MiB);
  u16*  o8  = (u16*)(A0 + 105 * MiB);
  u16*  o4  = (u16*)(A0 + 115 * MiB);
  u16*  xt2 = (u16*)(A0 + 86  * MiB);
  float* xn = (float*)(A0 + 105 * MiB);
  float* clsb = (float*)(A0 + 142 * MiB);
  u16*  tp  = qk;
  u16*  hs  = ht;  u16* osb = ht; u16* h2 = ht;
  u16*  a1  = qk;

  // -- weights -> transposed bf16 (QKV triplets contiguous for fused GEMMs)
  twt17_k<<<dim3(24, 24, 17), 256, 0, stream>>>(Ws, Wt, Wtp, Wfc, wbuf);
  twt_k<<<dim3(96, 24), 256, 0, stream>>>(W1, W1T, 768, 3072);
  twt_k<<<dim3(24, 96), 256, 0, stream>>>(W2, W2T, 3072, 768);

  // -- temporal LN
  ln_k<0><<<3136, 256, 0, stream>>>(x, nullptr, tlng, tlnb, ht);

  // -- scale 16: fused QKV (N=2304; V -> transposed layout) + attn
  gemm_k<8><<<18*98, 256, 0, stream>>>(ht, wbuf + 10*C2, bt + 6*768, qk, nullptr, vtb, 18, 12544, 768, 768, 24, 1,1,0, 16,1,12544);
  tattn_k<16,24><<<2352, 256, 0, stream>>>(qk, qk + (size_t)12544*768, vtb, o16);

  // -- scale 8
  gemm_k<8><<<18*49, 256, 0, stream>>>(ht, wbuf +  7*C2, bt + 3*768, qk, nullptr, vtb, 18, 6272, 768, 768, 16, 8,16,8, 8,1,6272);
  tattn_k< 8,16><<<2352, 256, 0, stream>>>(qk, qk + (size_t)6272*768, vtb, o8);

  // -- scale 4
  gemm_k<8><<<18*25, 256, 0, stream>>>(ht, wbuf +  4*C2, bt + 0*768, qk, nullptr, vtb, 18, 3136, 768, 768, 16, 4,16,12, 4,1,3136);
  tattn_k< 4,16><<<2352, 256, 0, stream>>>(qk, qk + (size_t)3136*768, vtb, o4);

  // -- projection + blend chain; then tp, xt2
  gemm_k<1><<<6*25, 256, 0, stream>>>(o4,  wbuf + 13*C2, btp + 0,    o8,  nullptr, nullptr, 6, 3136, 768, 768, 768, 1,1,0, 4,8,4);
  gemm_k<1><<<6*49, 256, 0, stream>>>(o8,  wbuf + 14*C2, btp + 768,  o16, nullptr, nullptr, 6, 6272, 768, 768, 768, 1,1,0, 8,16,8);
  gemm_k<0><<<6*98, 256, 0, stream>>>(o16, wbuf + 15*C2, btp + 1536, tp,  nullptr, nullptr, 6, 12544, 768, 768, 768, 1,1,0, 1,1,0);
  gemm_k<2><<<6*98, 256, 0, stream>>>(tp,  wbuf + 16*C2, bfc,        xt2, x, nullptr,       6, 12544, 768, 768, 768, 1,1,0, 1,1,0);

  // -- spatial LN + fused QKV
  ln_k<1><<<3152, 256, 0, stream>>>(x, xt2, ln1g, ln1b, hs);
  fillz_k<<<2048, 256, 0, stream>>>((u32*)vtb, 5505024);
  gemm_k<9><<<18*99, 256, 0, stream>>>(hs, wbuf + 0*C2, bs + 0, qk, nullptr, vtb, 18, 12608, 768, 768, 224, 1,1,0, 1,1,12608);

  // -- spatial attention
  sattn_k<<<9984, 64, 0, stream>>>(qk, qk + (size_t)12608*768, vtb, osb);

  // -- spatial proj + residual scatter into xn, cls rows
  gemm_k<3><<<6*99, 256, 0, stream>>>(osb, wbuf + 3*C2, bs + 2304, xn, xt2, clsb, 6, 12608, 768, 768, 768, 1,1,0, 1,1,0);
  clsfin_k<<<dim3(4, 3), 256, 0, stream>>>(x, clsb, xn);

  // -- final LN + MLP
  ln_k<2><<<3137, 256, 0, stream>>>(xn, nullptr, ln2g, ln2b, h2);
  gemm_k<4><<<24*99, 256, 0, stream>>>(h2, W1T, b1, a1,  nullptr, nullptr, 24, 12548, 768, 768, 3072, 1,1,0, 1,1,0);
  gemm_k<5><<<6*99, 256, 0, stream>>>(a1, W2T, b2, out, xn, nullptr,       6, 12548, 3072, 3072, 768, 1,1,0, 1,1,0);
}

// Round 8
// 723.025 us; speedup vs baseline: 1.6876x; 1.0828x over previous
//
#include <hip/hip_runtime.h>

typedef unsigned short u16;
typedef unsigned int   u32;
typedef __attribute__((ext_vector_type(8))) __bf16 bf16x8;
typedef __attribute__((ext_vector_type(4))) float  f32x4;
typedef __attribute__((ext_vector_type(4))) u16    u16x4;

#define DEV __device__ __forceinline__

DEV float bf2f(u16 u){ union { u32 i; float f; } x; x.i = ((u32)u) << 16; return x.f; }
DEV u16 f2bf(float f){ union { float f; u32 i; } x; x.f = f;
  u32 r = x.i + 0x7fffu + ((x.i >> 16) & 1u); return (u16)(r >> 16); }

DEV void gload16(const void* g, void* l){
  __builtin_amdgcn_global_load_lds((const __attribute__((address_space(1))) void*)g,
                                   (__attribute__((address_space(3))) void*)l, 16, 0, 0);
}

// ---------------- weight transpose+convert: dst[n*R + k] = src[k*C + n] (bf16) ----------
__global__ __launch_bounds__(256)
void twt_k(const float* __restrict__ src, u16* __restrict__ dst, int R, int C){
  __shared__ float t[32][33];
  int tx = threadIdx.x & 31, ty = threadIdx.x >> 5;
  int c0 = blockIdx.x * 32, r0 = blockIdx.y * 32;
  #pragma unroll
  for (int i = 0; i < 4; i++)
    t[ty + i*8][tx] = src[(size_t)(r0 + ty + i*8) * C + c0 + tx];
  __syncthreads();
  #pragma unroll
  for (int i = 0; i < 4; i++)
    dst[(size_t)(c0 + ty + i*8) * R + r0 + tx] = f2bf(t[tx][ty + i*8]);
}

// 17 square 768x768 mats in one launch (z = matrix id)
__global__ __launch_bounds__(256)
void twt17_k(const float* __restrict__ Ws, const float* __restrict__ Wt,
             const float* __restrict__ Wtp, const float* __restrict__ Wfc,
             u16* __restrict__ dst){
  __shared__ float t[32][33];
  int z = blockIdx.z;
  const float* src = (z < 4)  ? Ws  + (size_t)z * 589824
                   : (z < 13) ? Wt  + (size_t)(z-4) * 589824
                   : (z < 16) ? Wtp + (size_t)(z-13) * 589824
                   : Wfc;
  u16* d = dst + (size_t)z * 589824;
  int tx = threadIdx.x & 31, ty = threadIdx.x >> 5;
  int c0 = blockIdx.x * 32, r0 = blockIdx.y * 32;
  #pragma unroll
  for (int i = 0; i < 4; i++)
    t[ty + i*8][tx] = src[(size_t)(r0 + ty + i*8) * 768 + c0 + tx];
  __syncthreads();
  #pragma unroll
  for (int i = 0; i < 4; i++)
    d[(size_t)(c0 + ty + i*8) * 768 + r0 + tx] = f2bf(t[tx][ty + i*8]);
}

// ---------------- zero fill (u32 granularity) ----------------
__global__ void fillz_k(u32* __restrict__ p, long n){
  long i = (long)blockIdx.x * 256 + threadIdx.x;
  long stride = (long)gridDim.x * 256;
  for (; i < n; i += stride) p[i] = 0;
}

// ---------------- LayerNorm over C=768, one wave per token, out bf16 -------------
template<int GM>
__global__ __launch_bounds__(256)
void ln_k(const float* __restrict__ f0, const u16* __restrict__ b0_,
          const float* __restrict__ gw, const float* __restrict__ bw,
          u16* __restrict__ out){
  int lane = threadIdx.x & 63;
  int tok = blockIdx.x * 4 + (threadIdx.x >> 6);
  const float* fsrc = nullptr; const u16* bsrc = nullptr;
  bool bfp = false;
  if constexpr (GM == 0){
    int b = tok / 3136, m = tok - b * 3136;
    fsrc = f0 + ((size_t)b * 3137 + 1 + m) * 768;
  } else if constexpr (GM == 1){
    int s = tok / 197, j = tok - s * 197;
    int b = s >> 4, t = s & 15;
    if (j == 0) fsrc = f0 + (size_t)b * 3137 * 768;
    else { bfp = true; bsrc = b0_ + ((size_t)b * 3136 + (size_t)(j - 1) * 16 + t) * 768; }
  } else {
    fsrc = f0 + (size_t)tok * 768;
  }
  float v[12]; float s1 = 0.f, s2 = 0.f;
  if (!bfp){
    #pragma unroll
    for (int i = 0; i < 3; i++){
      float4 f = *(const float4*)(fsrc + i * 256 + lane * 4);
      v[i*4+0] = f.x; v[i*4+1] = f.y; v[i*4+2] = f.z; v[i*4+3] = f.w;
    }
  } else {
    #pragma unroll
    for (int i = 0; i < 3; i++){
      u16x4 p = *(const u16x4*)(bsrc + i * 256 + lane * 4);
      v[i*4+0] = bf2f(p[0]); v[i*4+1] = bf2f(p[1]); v[i*4+2] = bf2f(p[2]); v[i*4+3] = bf2f(p[3]);
    }
  }
  #pragma unroll
  for (int i = 0; i < 12; i++){ s1 += v[i]; s2 += v[i]*v[i]; }
  #pragma unroll
  for (int off = 32; off; off >>= 1){ s1 += __shfl_xor(s1, off); s2 += __shfl_xor(s2, off); }
  float mu = s1 * (1.f/768.f);
  float rstd = rsqrtf(s2 * (1.f/768.f) - mu*mu + 1e-5f);
  #pragma unroll
  for (int i = 0; i < 3; i++){
    int c = i * 256 + lane * 4;
    float4 g4 = *(const float4*)(gw + c);
    float4 b4 = *(const float4*)(bw + c);
    u16x4 pk;
    pk[0] = f2bf((v[i*4+0]-mu)*rstd*g4.x + b4.x);
    pk[1] = f2bf((v[i*4+1]-mu)*rstd*g4.y + b4.y);
    pk[2] = f2bf((v[i*4+2]-mu)*rstd*g4.z + b4.z);
    pk[3] = f2bf((v[i*4+3]-mu)*rstd*g4.w + b4.w);
    *(u16x4*)(out + (size_t)tok * 768 + c) = pk;
  }
}

// ---------------- GEMM: C = Amap @ Bw^T(+bias), 128x128 tile, bf16 MFMA ----------------
// R4-verified loop (dbuf, prefetch-before-compute, single __syncthreads) + XCD remap +
// __launch_bounds__(256,4). NEW R8: vT epilogues write packed u16x4 (4 consecutive
// t/j rows live in one lane's acc quad); spatial vT uses per-seq column shift s&3 so
// packed stores stay 8B-aligned despite 197 % 4 != 0 (sattn shifts P identically).
// MODE 0: bf16 out[R*ldo+Cg]
// MODE 1: blend: Ro=(R/oTs)*oTf+ot0+R%oTs; out[Ro*ldo+Cg] = bf16(0.5*val+0.5*old)
// MODE 2: bf16 out[R*768+Cg] = val + aux1(x,f32)[((R/3136)*3137+1+R%3136)*768+Cg]
// MODE 3: spatial scatter (+cls buffer)  MODE 4: gelu bf16 (tanh form)
// MODE 5: f32 out = val + aux1(f32)
// MODE 8: fused temporal QKV  MODE 9: fused spatial QKV (shifted vT)
template<int MODE>
__global__ __launch_bounds__(256, 4)
void gemm_k(const u16* __restrict__ A, const u16* __restrict__ Bw,
            const float* __restrict__ bias, void* out,
            const void* aux1, void* aux2, int nbx,
            int M, int K, int lda, int ldo,
            int aTs, int aTf, int at0, int oTs, int oTf, int ot0){
  __shared__ u16 lA[2][128 * 32];
  __shared__ u16 lB[2][128 * 32];
  const int tid = threadIdx.x;

  // m204 bijective XCD-chunked remap
  const int nwg = (int)gridDim.x;
  int id = (int)blockIdx.x;
  int qc = nwg >> 3, rc = nwg & 7;
  int xcd = id & 7, off = id >> 3;
  int wg = (xcd < rc ? xcd * (qc + 1) : rc * (qc + 1) + (xcd - rc) * qc) + off;
  int by = wg / nbx;
  int bx = wg - by * nbx;
  const int m0 = by * 128, n0 = bx * 128;

  const int lane = tid & 63, widx = tid >> 6;
  const int g = lane >> 4, r16 = lane & 15;
  const int wm = widx >> 1, wn = widx & 1;

  const u16* ga0; const u16* ga1; const u16* gb0; const u16* gb1;
  u32 lo0, lo1;
  {
    int li = tid;
    int ar = m0 + (li >> 2); if (ar > M - 1) ar = M - 1;
    ar = (ar / aTs) * aTf + at0 + (ar % aTs);
    ga0 = A + (size_t)ar * lda + (li & 3) * 8;
    gb0 = Bw + (size_t)(n0 + (li >> 2)) * K + (li & 3) * 8;
    lo0 = li * 8;
    li = tid + 256;
    ar = m0 + (li >> 2); if (ar > M - 1) ar = M - 1;
    ar = (ar / aTs) * aTf + at0 + (ar % aTs);
    ga1 = A + (size_t)ar * lda + (li & 3) * 8;
    gb1 = Bw + (size_t)(n0 + (li >> 2)) * K + (li & 3) * 8;
    lo1 = li * 8;
  }

  const f32x4 vz = {0.f, 0.f, 0.f, 0.f};
  f32x4 acc[4][4];
  #pragma unroll
  for (int i = 0; i < 4; i++)
    #pragma unroll
    for (int j = 0; j < 4; j++) acc[i][j] = vz;

  const int kiter = K >> 5;

  // prologue: stage k-tile 0 into buf 0, advance pointers in place
  gload16(ga0, &lA[0][lo0]);
  gload16(ga1, &lA[0][lo1]);
  gload16(gb0, &lB[0][lo0]);
  gload16(gb1, &lB[0][lo1]);
  ga0 += 32; ga1 += 32; gb0 += 32; gb1 += 32;
  __syncthreads();

  for (int kt = 0; kt < kiter; ++kt){
    const int cur = kt & 1;
    if (kt + 1 < kiter){           // issue next-tile loads BEFORE compute
      const int nxt = cur ^ 1;
      gload16(ga0, &lA[nxt][lo0]);
      gload16(ga1, &lA[nxt][lo1]);
      gload16(gb0, &lB[nxt][lo0]);
      gload16(gb1, &lB[nxt][lo1]);
      ga0 += 32; ga1 += 32; gb0 += 32; gb1 += 32;
    }
    bf16x8 af[4], bfr[4];
    #pragma unroll
    for (int i = 0; i < 4; i++){
      af[i]  = *(const bf16x8*)(&lA[cur][(wm * 64 + i * 16 + r16) * 32 + g * 8]);
      bfr[i] = *(const bf16x8*)(&lB[cur][(wn * 64 + i * 16 + r16) * 32 + g * 8]);
    }
    #pragma unroll
    for (int i = 0; i < 4; i++)
      #pragma unroll
      for (int j = 0; j < 4; j++)
        acc[i][j] = __builtin_amdgcn_mfma_f32_16x16x32_bf16(af[i], bfr[j], acc[i][j], 0, 0, 0);
    __syncthreads();               // implicit vmcnt(0)+lgkmcnt(0) after compute
  }

  #pragma unroll
  for (int i = 0; i < 4; i++){
    const int lrow = wm * 64 + i * 16 + g * 4;
    #pragma unroll
    for (int j = 0; j < 4; j++){
      const int Cg = n0 + wn * 64 + j * 16 + r16;
      const float b0 = bias[Cg];
      float vv[4];
      #pragma unroll
      for (int r = 0; r < 4; r++) vv[r] = acc[i][j][r] + b0;

      if constexpr (MODE == 8){
        int mat = Cg / 768, c0 = Cg - mat * 768;
        if (mat < 2){
          #pragma unroll
          for (int r = 0; r < 4; r++){
            int R = m0 + lrow + r;
            if (R < M)
              ((u16*)out)[(size_t)mat * ot0 * 768 + (size_t)R * 768 + c0] = f2bf(vv[r]);
          }
        } else {
          int R0 = m0 + lrow;                 // mult of 4; M mult of 4 -> whole quad valid
          if (R0 < M){
            int seq_ = R0 / oTs, t0 = R0 - seq_ * oTs;   // t0 mult of 4, quad in-seq
            u16x4 pk;
            #pragma unroll
            for (int r = 0; r < 4; r++) pk[r] = f2bf(vv[r]);
            *(u16x4*)((u16*)aux2 +
              ((size_t)(seq_ * 12 + (c0 >> 6)) * 64 + (c0 & 63)) * ldo + t0) = pk;
          }
        }
      } else if constexpr (MODE == 9){
        int mat = Cg / 768, c0 = Cg - mat * 768;
        if (mat < 2){
          #pragma unroll
          for (int r = 0; r < 4; r++){
            int R = m0 + lrow + r;
            if (R < M)
              ((u16*)out)[(size_t)mat * ot0 * 768 + (size_t)R * 768 + c0] = f2bf(vv[r]);
          }
        } else {
          int R0 = m0 + lrow;
          if (R0 < M){
            int s_ = R0 / 197, j0 = R0 - s_ * 197;
            if (j0 <= 193){                   // whole quad in one seq; p0 = j0 + s%4 mult of 4
              u16x4 pk;
              #pragma unroll
              for (int r = 0; r < 4; r++) pk[r] = f2bf(vv[r]);
              *(u16x4*)((u16*)aux2 +
                ((size_t)(s_ * 12 + (c0 >> 6)) * 64 + (c0 & 63)) * 224 + j0 + (s_ & 3)) = pk;
            } else {                          // seq-boundary quad: scalar fallback
              #pragma unroll
              for (int r = 0; r < 4; r++){
                int R = R0 + r;
                if (R < M){
                  int s2 = R / 197, j2 = R - s2 * 197;
                  ((u16*)aux2)[((size_t)(s2 * 12 + (c0 >> 6)) * 64 + (c0 & 63)) * 224
                               + j2 + (s2 & 3)] = f2bf(vv[r]);
                }
              }
            }
          }
        }
      } else {
        #pragma unroll
        for (int r = 0; r < 4; r++){
          const int R = m0 + lrow + r;
          if (R >= M) continue;
          float val = vv[r];
          if constexpr (MODE == 0){
            ((u16*)out)[(size_t)R * ldo + Cg] = f2bf(val);
          } else if constexpr (MODE == 1){
            int Ro = (R / oTs) * oTf + ot0 + (R % oTs);
            u16* po = (u16*)out + (size_t)Ro * ldo + Cg;
            *po = f2bf(0.5f * val + 0.5f * bf2f(*po));
          } else if constexpr (MODE == 2){
            int b_ = R / 3136, m_ = R - b_ * 3136;
            ((u16*)out)[(size_t)R * 768 + Cg] =
                f2bf(val + ((const float*)aux1)[((size_t)b_ * 3137 + 1 + m_) * 768 + Cg]);
          } else if constexpr (MODE == 3){
            int s_ = R / 197, j_ = R - s_ * 197;
            if (j_ == 0){
              ((float*)aux2)[(size_t)s_ * 768 + Cg] = val;
            } else {
              int b_ = s_ >> 4, t_ = s_ & 15, m_ = (j_ - 1) * 16 + t_;
              ((float*)out)[((size_t)b_ * 3137 + 1 + m_) * 768 + Cg] =
                  val + bf2f(((const u16*)aux1)[((size_t)b_ * 3136 + m_) * 768 + Cg]);
            }
          } else if constexpr (MODE == 4){
            float c = val * (0.7978845608f + 0.0356774081f * val * val);
            float e2 = __expf(2.f * fabsf(c));
            float th = __builtin_copysignf(1.f - 2.f / (e2 + 1.f), c);
            ((u16*)out)[(size_t)R * ldo + Cg] = f2bf(0.5f * val * (1.f + th));
          } else if constexpr (MODE == 5){
            ((float*)out)[(size_t)R * 768 + Cg] = val + ((const float*)aux1)[(size_t)R * 768 + Cg];
          }
        }
      }
    }
  }
}

// ---------------- temporal attention via MFMA: one wave per (seq,head) ----------------
template<int TS, int TSPAD>
__global__ __launch_bounds__(256)
void tattn_k(const u16* __restrict__ q, const u16* __restrict__ k,
             const u16* __restrict__ vt, u16* __restrict__ o){
  const int lane = threadIdx.x & 63;
  const int g = lane >> 4, r16 = lane & 15;
  int p = blockIdx.x * 4 + (threadIdx.x >> 6);
  int seq = p / 12, h = p - seq * 12;

  int trow = (TS < 16 && r16 >= TS) ? TS - 1 : r16;
  size_t qko = (size_t)(seq * TS + trow) * 768 + h * 64 + g * 8;
  bf16x8 ak0 = *(const bf16x8*)(k + qko);
  bf16x8 ak1 = *(const bf16x8*)(k + qko + 32);
  bf16x8 bq0 = *(const bf16x8*)(q + qko);
  bf16x8 bq1 = *(const bf16x8*)(q + qko + 32);

  f32x4 s = {0.f, 0.f, 0.f, 0.f};
  s = __builtin_amdgcn_mfma_f32_16x16x32_bf16(ak0, bq0, s, 0, 0, 0);
  s = __builtin_amdgcn_mfma_f32_16x16x32_bf16(ak1, bq1, s, 0, 0, 0);

  const float C = 0.125f * 1.44269504089f;
  float pv[4]; float mx = -3e38f;
  #pragma unroll
  for (int r = 0; r < 4; r++){
    float x = (g * 4 + r < TS) ? s[r] : -3e38f;
    pv[r] = x; mx = fmaxf(mx, x);
  }
  mx = fmaxf(mx, __shfl_xor(mx, 16));
  mx = fmaxf(mx, __shfl_xor(mx, 32));
  float sum = 0.f;
  #pragma unroll
  for (int r = 0; r < 4; r++){ pv[r] = exp2f((pv[r] - mx) * C); sum += pv[r]; }
  sum += __shfl_xor(sum, 16);
  sum += __shfl_xor(sum, 32);
  float inv = 1.f / sum;
  #pragma unroll
  for (int r = 0; r < 4; r++) pv[r] *= inv;

  u32 w0 = (u32)f2bf(pv[0]) | ((u32)f2bf(pv[1]) << 16);
  u32 w1 = (u32)f2bf(pv[2]) | ((u32)f2bf(pv[3]) << 16);
  int a0 = ((g * 2) * 16 + r16) * 4;
  int a1 = ((g * 2 + 1) * 16 + r16) * 4;
  u32 msk = (g < 2) ? 0xFFFFFFFFu : 0u;
  union { u32 w[4]; bf16x8 v; } pa;
  pa.w[0] = msk & (u32)__builtin_amdgcn_ds_bpermute(a0, (int)w0);
  pa.w[1] = msk & (u32)__builtin_amdgcn_ds_bpermute(a0, (int)w1);
  pa.w[2] = msk & (u32)__builtin_amdgcn_ds_bpermute(a1, (int)w0);
  pa.w[3] = msk & (u32)__builtin_amdgcn_ds_bpermute(a1, (int)w1);

  const u16* vb = vt + ((size_t)(seq * 12 + h) * 64) * TSPAD;
  const f32x4 vz = {0.f, 0.f, 0.f, 0.f};
  f32x4 oc[4];
  #pragma unroll
  for (int dt = 0; dt < 4; ++dt){
    bf16x8 bv = *(const bf16x8*)(vb + (size_t)(dt * 16 + r16) * TSPAD + g * 8);
    oc[dt] = __builtin_amdgcn_mfma_f32_16x16x32_bf16(pa.v, bv, vz, 0, 0, 0);
  }
  #pragma unroll
  for (int rr = 0; rr < 4; ++rr){
    int qr = g * 4 + rr;
    if (qr < TS){
      size_t ob = (size_t)(seq * TS + qr) * 768 + h * 64 + r16;
      #pragma unroll
      for (int dt = 0; dt < 4; ++dt)
        o[ob + dt * 16] = f2bf(oc[dt][rr]);
    }
  }
}

// ---------------- spatial attention: 1 wave per (seq,head,16-row q-chunk) --------------
// vt columns are shifted by s&3 (see gemm MODE 9); P is written into LDS at the same
// shifted column so P.V stays index-consistent.
__global__ __launch_bounds__(64)
void sattn_k(const u16* __restrict__ qs, const u16* __restrict__ ks,
             const u16* __restrict__ vt, u16* __restrict__ o){
  __shared__ u16 Pl[16 * 224];
  const int lane = threadIdx.x & 63;
  const int g = lane >> 4, r16 = lane & 15;
  int bid = blockIdx.x;
  int chunk = bid % 13; int sh_ = bid / 13;
  int h = sh_ % 12, s = sh_ / 12;
  const int shft = s & 3;
  const float sc_l2e = 0.125f * 1.44269504089f;

  // zero pad cols: [208,224) and [0,4) (written region is [shft, 208+shft))
  #pragma unroll
  for (int i = 0; i < 4; i++){
    Pl[(i * 4 + g) * 224 + 208 + r16] = 0;
    if (r16 < 4) Pl[(i * 4 + g) * 224 + r16] = 0;
  }

  int q0 = chunk * 16;
  int qrow = q0 + r16; if (qrow > 196) qrow = 196;
  const u16* qp = qs + ((size_t)(s * 197 + qrow)) * 768 + h * 64 + g * 8;
  bf16x8 aq0 = *(const bf16x8*)qp;
  bf16x8 aq1 = *(const bf16x8*)(qp + 32);

  f32x4 scv[13];
  #pragma unroll
  for (int jt = 0; jt < 13; ++jt){
    int krow = jt * 16 + r16; if (krow > 196) krow = 196;
    const u16* kp = ks + ((size_t)(s * 197 + krow)) * 768 + h * 64 + g * 8;
    bf16x8 b0 = *(const bf16x8*)kp;
    bf16x8 b1 = *(const bf16x8*)(kp + 32);
    f32x4 z = {0.f, 0.f, 0.f, 0.f};
    z = __builtin_amdgcn_mfma_f32_16x16x32_bf16(aq0, b0, z, 0, 0, 0);
    z = __builtin_amdgcn_mfma_f32_16x16x32_bf16(aq1, b1, z, 0, 0, 0);
    scv[jt] = z;
  }
  float mrow[4] = {-3e38f, -3e38f, -3e38f, -3e38f};
  #pragma unroll
  for (int jt = 0; jt < 13; ++jt)
    #pragma unroll
    for (int r = 0; r < 4; r++){
      float x = (jt * 16 + r16 < 197) ? scv[jt][r] : -3e38f;
      scv[jt][r] = x;
      mrow[r] = fmaxf(mrow[r], x);
    }
  #pragma unroll
  for (int off = 1; off < 16; off <<= 1)
    #pragma unroll
    for (int r = 0; r < 4; r++) mrow[r] = fmaxf(mrow[r], __shfl_xor(mrow[r], off));
  float srow[4] = {0.f, 0.f, 0.f, 0.f};
  #pragma unroll
  for (int jt = 0; jt < 13; ++jt)
    #pragma unroll
    for (int r = 0; r < 4; r++){
      float e = exp2f((scv[jt][r] - mrow[r]) * sc_l2e);
      scv[jt][r] = e;
      srow[r] += e;
    }
  #pragma unroll
  for (int off = 1; off < 16; off <<= 1)
    #pragma unroll
    for (int r = 0; r < 4; r++) srow[r] += __shfl_xor(srow[r], off);
  float inv[4];
  #pragma unroll
  for (int r = 0; r < 4; r++) inv[r] = 1.f / srow[r];
  #pragma unroll
  for (int jt = 0; jt < 13; ++jt)
    #pragma unroll
    for (int r = 0; r < 4; r++)
      Pl[(g * 4 + r) * 224 + jt * 16 + r16 + shft] = f2bf(scv[jt][r] * inv[r]);
  __syncthreads();
  const u16* vbase = vt + ((size_t)(s * 12 + h) * 64) * 224;
  f32x4 oc[4]; const f32x4 vz = {0.f,0.f,0.f,0.f};
  #pragma unroll
  for (int dt = 0; dt < 4; dt++) oc[dt] = vz;
  #pragma unroll
  for (int ks2 = 0; ks2 < 7; ++ks2){
    bf16x8 ap = *(const bf16x8*)(Pl + r16 * 224 + ks2 * 32 + g * 8);
    #pragma unroll
    for (int dt = 0; dt < 4; ++dt){
      const u16* vp = vbase + ((size_t)(dt * 16 + r16)) * 224 + ks2 * 32 + g * 8;
      bf16x8 bv = *(const bf16x8*)vp;
      oc[dt] = __builtin_amdgcn_mfma_f32_16x16x32_bf16(ap, bv, oc[dt], 0, 0, 0);
    }
  }
  #pragma unroll
  for (int dt = 0; dt < 4; ++dt)
    #pragma unroll
    for (int r = 0; r < 4; r++){
      int qr2 = q0 + g * 4 + r;
      if (qr2 < 197)
        o[((size_t)(s * 197 + qr2)) * 768 + h * 64 + dt * 16 + r16] = f2bf(oc[dt][r]);
    }
}

// ---------------- cls row: xn[b,0] = x[b,0] + mean_t clsbuf[b*16+t] ----------------
__global__ __launch_bounds__(256)
void clsfin_k(const float* __restrict__ x, const float* __restrict__ cb, float* __restrict__ xn){
  int b = blockIdx.x;
  int c = blockIdx.y * 256 + threadIdx.x;
  float s = 0.f;
  #pragma unroll
  for (int t = 0; t < 16; t++) s += cb[((size_t)(b * 16 + t)) * 768 + c];
  xn[(size_t)b * 3137 * 768 + c] = x[(size_t)b * 3137 * 768 + c] + s * (1.f / 16.f);
}

// ======================================================================================
extern "C" void kernel_launch(void* const* d_in, const int* in_sizes, int n_in,
                              void* d_out, int out_size, void* d_ws, size_t ws_size,
                              hipStream_t stream){
  (void)in_sizes; (void)n_in; (void)out_size;
  const float* x    = (const float*)d_in[0];
  const float* ln1g = (const float*)d_in[1];
  const float* ln1b = (const float*)d_in[2];
  const float* tlng = (const float*)d_in[3];
  const float* tlnb = (const float*)d_in[4];
  const float* ln2g = (const float*)d_in[5];
  const float* ln2b = (const float*)d_in[6];
  const float* Ws   = (const float*)d_in[7];
  const float* bs   = (const float*)d_in[8];
  const float* Wt   = (const float*)d_in[9];
  const float* bt   = (const float*)d_in[10];
  const float* Wtp  = (const float*)d_in[11];
  const float* btp  = (const float*)d_in[12];
  const float* Wfc  = (const float*)d_in[13];
  const float* bfc  = (const float*)d_in[14];
  const float* W1   = (const float*)d_in[15];
  const float* b1   = (const float*)d_in[16];
  const float* W2   = (const float*)d_in[17];
  const float* b2   = (const float*)d_in[18];
  float* out = (float*)d_out;

  constexpr size_t MiB = 1048576;
  constexpr size_t C2  = 589824;
  constexpr size_t W_BYTES = (17 * C2 + 2 * 2359296) * 2;  // 29,491,200
  constexpr size_t NEED = W_BYTES + 143 * MiB;
  if (ws_size < NEED) return;

  char* wsb  = (char*)d_ws;
  u16*  wbuf = (u16*)wsb;
  u16*  W1T  = wbuf + 17 * C2;
  u16*  W2T  = W1T + (size_t)3072 * 768;
  char* A0   = wsb + W_BYTES;

  u16*  ht  = (u16*)(A0 + 0   * MiB);
  u16*  qk  = (u16*)(A0 + 20  * MiB);
  u16*  vtb = (u16*)(A0 + 58  * MiB);
  u16*  o16 = (u16*)(A0 + 86  * MiB);
  u16*  o8  = (u16*)(A0 + 105 * MiB);
  u16*  o4  = (u16*)(A0 + 115 * MiB);
  u16*  xt2 = (u16*)(A0 + 86  * MiB);
  float* xn = (float*)(A0 + 105 * MiB);
  float* clsb = (float*)(A0 + 142 * MiB);
  u16*  tp  = qk;
  u16*  hs  = ht;  u16* osb = ht; u16* h2 = ht;
  u16*  a1  = qk;

  // -- weights -> transposed bf16 (QKV triplets contiguous for fused GEMMs)
  twt17_k<<<dim3(24, 24, 17), 256, 0, stream>>>(Ws, Wt, Wtp, Wfc, wbuf);
  twt_k<<<dim3(96, 24), 256, 0, stream>>>(W1, W1T, 768, 3072);
  twt_k<<<dim3(24, 96), 256, 0, stream>>>(W2, W2T, 3072, 768);

  // -- temporal LN
  ln_k<0><<<3136, 256, 0, stream>>>(x, nullptr, tlng, tlnb, ht);

  // -- scale 16: fused QKV (N=2304; V -> transposed layout) + attn
  gemm_k<8><<<18*98, 256, 0, stream>>>(ht, wbuf + 10*C2, bt + 6*768, qk, nullptr, vtb, 18, 12544, 768, 768, 24, 1,1,0, 16,1,12544);
  tattn_k<16,24><<<2352, 256, 0, stream>>>(qk, qk + (size_t)12544*768, vtb, o16);

  // -- scale 8
  gemm_k<8><<<18*49, 256, 0, stream>>>(ht, wbuf +  7*C2, bt + 3*768, qk, nullptr, vtb, 18, 6272, 768, 768, 16, 8,16,8, 8,1,6272);
  tattn_k< 8,16><<<2352, 256, 0, stream>>>(qk, qk + (size_t)6272*768, vtb, o8);

  // -- scale 4
  gemm_k<8><<<18*25, 256, 0, stream>>>(ht, wbuf +  4*C2, bt + 0*768, qk, nullptr, vtb, 18, 3136, 768, 768, 16, 4,16,12, 4,1,3136);
  tattn_k< 4,16><<<2352, 256, 0, stream>>>(qk, qk + (size_t)3136*768, vtb, o4);

  // -- projection + blend chain; then tp, xt2
  gemm_k<1><<<6*25, 256, 0, stream>>>(o4,  wbuf + 13*C2, btp + 0,    o8,  nullptr, nullptr, 6, 3136, 768, 768, 768, 1,1,0, 4,8,4);
  gemm_k<1><<<6*49, 256, 0, stream>>>(o8,  wbuf + 14*C2, btp + 768,  o16, nullptr, nullptr, 6, 6272, 768, 768, 768, 1,1,0, 8,16,8);
  gemm_k<0><<<6*98, 256, 0, stream>>>(o16, wbuf + 15*C2, btp + 1536, tp,  nullptr, nullptr, 6, 12544, 768, 768, 768, 1,1,0, 1,1,0);
  gemm_k<2><<<6*98, 256, 0, stream>>>(tp,  wbuf + 16*C2, bfc,        xt2, x, nullptr,       6, 12544, 768, 768, 768, 1,1,0, 1,1,0);

  // -- spatial LN + fused QKV (shifted vT)
  ln_k<1><<<3152, 256, 0, stream>>>(x, xt2, ln1g, ln1b, hs);
  fillz_k<<<2048, 256, 0, stream>>>((u32*)vtb, 5505024);
  gemm_k<9><<<18*99, 256, 0, stream>>>(hs, wbuf + 0*C2, bs + 0, qk, nullptr, vtb, 18, 12608, 768, 768, 224, 1,1,0, 1,1,12608);

  // -- spatial attention
  sattn_k<<<9984, 64, 0, stream>>>(qk, qk + (size_t)12608*768, vtb, osb);

  // -- spatial proj + residual scatter into xn, cls rows
  gemm_k<3><<<6*99, 256, 0, stream>>>(osb, wbuf + 3*C2, bs + 2304, xn, xt2, clsb, 6, 12608, 768, 768, 768, 1,1,0, 1,1,0);
  clsfin_k<<<dim3(4, 3), 256, 0, stream>>>(x, clsb, xn);

  // -- final LN + MLP
  ln_k<2><<<3137, 256, 0, stream>>>(xn, nullptr, ln2g, ln2b, h2);
  gemm_k<4><<<24*99, 256, 0, stream>>>(h2, W1T, b1, a1,  nullptr, nullptr, 24, 12548, 768, 768, 3072, 1,1,0, 1,1,0);
  gemm_k<5><<<6*99, 256, 0, stream>>>(a1, W2T, b2, out, xn, nullptr,       6, 12548, 3072, 3072, 768, 1,1,0, 1,1,0);
}